// Round 6
// baseline (881.765 us; speedup 1.0000x reference)
//
#include <hip/hip_runtime.h>
#include <math.h>

// ---------------------------------------------------------------------------
// GAT pipeline: 3x (GEMM+alpha fused -> CSR segment-softmax aggregate) + FC
// R13: revert R12's XCD residue scheduling (FETCH went UP 13->19MB, flat
//      time -> blockIdx%8 locality assumption wrong) and 512-thr aggregate.
//      Back to R10 shapes (proven 850us). GEMM k-loop restructured:
//      - unroll-2 ROLE-SWAP buffers xa/xb: no xv=xn copies (was 32 v_mov
//        = 25% of VALU issue per iter), counted vmcnt(8) instead of drain.
//      - GROUP-level pipelining: last sub-iter of group g prefetches group
//        g+stride's head chunk; first group's head issued before the
//        W-staging barrier (cold ~900cy miss hidden under staging).
//      No launch_bounds cap, no full unroll (R8/R11 spill lessons).
// ---------------------------------------------------------------------------

// pass 1: cnt[dst]++ (atomic), remember each edge's arrival rank.
__global__ void count_rank_kernel(const int* __restrict__ ei, int E, int N,
                                  int* __restrict__ cnt, int* __restrict__ rank) {
    const int Etot = E + N;
    const int T = gridDim.x * blockDim.x;
    int e = blockIdx.x * blockDim.x + threadIdx.x;
#pragma unroll 4
    for (int u = 0; u < 4; ++u, e += T) {
        if (e < Etot) {
            int dst = (e < E) ? ei[E + e] : (e - E);   // self-loops appended
            rank[e] = atomicAdd(&cnt[dst], 1);
        }
    }
}

__global__ __launch_bounds__(1024) void scan_kernel(const int* __restrict__ cnt,
                                                    int N, int Etot,
                                                    int* __restrict__ row_ptr) {
    __shared__ int sums[1024];
    int tid = threadIdx.x;
    int chunk = (N + 1023) >> 10;
    int lo = tid * chunk;
    int hi = lo + chunk; if (hi > N) hi = N; if (lo > N) lo = N;
    int s = 0;
    for (int i = lo; i < hi; ++i) s += cnt[i];
    sums[tid] = s;
    __syncthreads();
    for (int off = 1; off < 1024; off <<= 1) {
        int t = (tid >= off) ? sums[tid - off] : 0;
        __syncthreads();
        sums[tid] += t;
        __syncthreads();
    }
    int run = sums[tid] - s;   // exclusive base for this thread's chunk
    for (int i = lo; i < hi; ++i) {
        row_ptr[i] = run;
        run += cnt[i];
    }
    if (tid == 0) row_ptr[N] = Etot;
}

// pass 3: pos = row_ptr[dst] + rank[e]; atomic-free scattered store.
__global__ void scatter_kernel(const int* __restrict__ ei, int E, int N,
                               const int* __restrict__ row_ptr,
                               const int* __restrict__ rank,
                               int* __restrict__ csr_src) {
    const int Etot = E + N;
    const int T = gridDim.x * blockDim.x;
    int e = blockIdx.x * blockDim.x + threadIdx.x;
#pragma unroll 4
    for (int u = 0; u < 4; ++u, e += T) {
        if (e < Etot) {
            int src, dst;
            if (e < E) { src = ei[e]; dst = ei[E + e]; }
            else       { src = e - E; dst = e - E; }
            csr_src[row_ptr[dst] + rank[e]] = src;
        }
    }
}

// ---------------------------------------------------------------------------
// GEMM: out[n, cb+m] = sum_k in[n,k]*W[k,cb+m].  256-thread blocks (4 waves),
// W chunk staged to LDS once (b128 conflict-free), grid-stride over row
// groups of RB=8 rows/wave. Role-swapped xa/xb double buffer (no copies,
// counted vmcnt); group-level head prefetch (next group's k4=0 chunk loaded
// during current group's last sub-iter; first group's under W staging).
// ALPHA: fused alpha_s/alpha_d via wave shfl reduction over the output row:
//   0=none  1=(H2,C32,PL1: segmented 32-lane)  2=(H2,C64,PL2)  3=(H1,C64,PL1)
// K*CHUNK <= 8192 (32 KB LDS).
// ---------------------------------------------------------------------------
template <int K, int CHUNK, int RB, int ALPHA>
__global__ __launch_bounds__(256) void gemm_kernel(
        const float* __restrict__ in,
        const float* __restrict__ W,
        const float* __restrict__ bias,
        float* __restrict__ out,
        const float* __restrict__ a_src,
        const float* __restrict__ a_dst,
        float* __restrict__ alpS,
        float* __restrict__ alpD,
        int N, int M, int relu) {
    constexpr int PL = CHUNK / 64;
    constexpr int K4 = K / 4;
    static_assert((K4 & 1) == 0, "K4 must be even for role-swap unroll-2");
    __shared__ float wlds[K * CHUNK];
    const int cb = blockIdx.y * CHUNK;

    const int wid  = threadIdx.x >> 6;
    const int lane = threadIdx.x & 63;
    const int gstep  = gridDim.x * 4;
    const int groups = (N + RB - 1) / RB;
    int g = blockIdx.x * 4 + wid;

    // ---- issue first group's head chunk BEFORE staging (hides cold miss)
    float4 xa[RB];
    if (g < groups && g * RB + RB <= N) {
        const float4* xp0 = (const float4*)(in + (size_t)(g * RB) * K);
#pragma unroll
        for (int r = 0; r < RB; ++r) xa[r] = xp0[r * K4];
    }

    // ---- stage W chunk to LDS (coalesced b128 writes)
    for (int idx = threadIdx.x; idx < K4 * CHUNK; idx += 256) {
        int k4 = idx / CHUNK, c = idx % CHUNK;
        const float* wp = W + (size_t)(4 * k4) * M + cb + c;
        float4 v;
        v.x = wp[0];
        v.y = wp[(size_t)M];
        v.z = wp[(size_t)2 * M];
        v.w = wp[(size_t)3 * M];
        ((float4*)wlds)[idx] = v;
    }
    __syncthreads();

    const float4* wlds4 = (const float4*)wlds;

    float b[PL], aSv[PL], aDv[PL];
#pragma unroll
    for (int j = 0; j < PL; ++j) {
        b[j] = bias ? bias[cb + lane + 64 * j] : 0.0f;
        if (ALPHA) { aSv[j] = a_src[lane + 64 * j]; aDv[j] = a_dst[lane + 64 * j]; }
    }

    for (; g < groups; g += gstep) {
        const int n0 = g * RB;
        const bool full = (n0 + RB <= N);

        // next group this wave will process; clamp to a known-full group (0)
        // when out-of-range or tail so the prefetch reads are always safe.
        int gn = g + gstep;
        if (gn >= groups || gn * RB + RB > N) gn = 0;
        const float4* xq = (const float4*)(in + (size_t)(gn * RB) * K);

        float acc[RB][PL];
#pragma unroll
        for (int r = 0; r < RB; ++r)
#pragma unroll
            for (int j = 0; j < PL; ++j) acc[r][j] = 0.0f;

        const float4* xp = (const float4*)(in + (size_t)n0 * K);

        if (full) {
            // xa already holds this group's k4=0 chunk.
            float4 xb[RB];
#pragma unroll 1
            for (int k4 = 0; k4 < K4; k4 += 2) {
                // -- sub-iter A: prefetch k4+1 into xb, consume xa
#pragma unroll
                for (int r = 0; r < RB; ++r) xb[r] = xp[r * K4 + k4 + 1];
#pragma unroll
                for (int j = 0; j < PL; ++j) {
                    float4 wv = wlds4[k4 * CHUNK + lane + 64 * j];
#pragma unroll
                    for (int r = 0; r < RB; ++r) {
                        acc[r][j] += xa[r].x * wv.x;
                        acc[r][j] += xa[r].y * wv.y;
                        acc[r][j] += xa[r].z * wv.z;
                        acc[r][j] += xa[r].w * wv.w;
                    }
                }
                // -- sub-iter B: prefetch k4+2 (or next group's head) into xa,
                //    consume xb
                if (k4 + 2 < K4) {
#pragma unroll
                    for (int r = 0; r < RB; ++r) xa[r] = xp[r * K4 + k4 + 2];
                } else {
#pragma unroll
                    for (int r = 0; r < RB; ++r) xa[r] = xq[r * K4];
                }
#pragma unroll
                for (int j = 0; j < PL; ++j) {
                    float4 wv = wlds4[(k4 + 1) * CHUNK + lane + 64 * j];
#pragma unroll
                    for (int r = 0; r < RB; ++r) {
                        acc[r][j] += xb[r].x * wv.x;
                        acc[r][j] += xb[r].y * wv.y;
                        acc[r][j] += xb[r].z * wv.z;
                        acc[r][j] += xb[r].w * wv.w;
                    }
                }
            }
            // xa now holds group gn's head chunk (or group 0 garbage if last).
        } else {
            // ---- tail path (never taken when N % RB == 0): simple, guarded.
#pragma unroll 1
            for (int k4 = 0; k4 < K4; ++k4) {
#pragma unroll 1
                for (int r = 0; r < RB; ++r) {
                    if (n0 + r >= N) break;
                    float4 xr = xp[(size_t)r * K4 + k4];
#pragma unroll
                    for (int j = 0; j < PL; ++j) {
                        float4 wv = wlds4[k4 * CHUNK + lane + 64 * j];
                        acc[r][j] += xr.x * wv.x;
                        acc[r][j] += xr.y * wv.y;
                        acc[r][j] += xr.z * wv.z;
                        acc[r][j] += xr.w * wv.w;
                    }
                }
            }
        }

#pragma unroll
        for (int r = 0; r < RB; ++r) {
            if (!full && n0 + r >= N) break;
            const int n = n0 + r;
            float v[PL];
#pragma unroll
            for (int j = 0; j < PL; ++j) {
                v[j] = acc[r][j] + b[j];
                if (relu) v[j] = fmaxf(v[j], 0.0f);
                out[(size_t)n * M + cb + lane + 64 * j] = v[j];
            }
            if (ALPHA) {
                float ps[PL], pd[PL];
#pragma unroll
                for (int j = 0; j < PL; ++j) { ps[j] = v[j] * aSv[j]; pd[j] = v[j] * aDv[j]; }
                const int m0 = (ALPHA == 1) ? 16 : 32;
                for (int mm = m0; mm >= 1; mm >>= 1) {
#pragma unroll
                    for (int j = 0; j < PL; ++j) {
                        ps[j] += __shfl_xor(ps[j], mm, 64);
                        pd[j] += __shfl_xor(pd[j], mm, 64);
                    }
                }
                if (ALPHA == 1) {
                    if ((lane & 31) == 0) {
                        int idx = n * 2 + (lane >> 5);
                        alpS[idx] = ps[0]; alpD[idx] = pd[0];
                    }
                } else if (ALPHA == 2) {
                    if (lane == 0) {
#pragma unroll
                        for (int j = 0; j < PL; ++j) {
                            alpS[n * 2 + j] = ps[j]; alpD[n * 2 + j] = pd[j];
                        }
                    }
                } else {
                    if (lane == 0) { alpS[n] = ps[0]; alpD[n] = pd[0]; }
                }
            }
        }
    }
}

// ---------------------------------------------------------------------------
// Aggregate R10 (proven): one wave per dst node, 64-edge chunks.
//   Phase A (lane = edge): coalesced csr_src, float2 alpha_s, leaky, wave
//     butterfly max -> chunk-level rescale of (m,den,acc), lane-parallel
//     p=exp(lg-m), butterfly den sum. 1 exp per 64 edges (per head).
//   Phase B (broadcast): (src,p) staged in per-wave LDS slice (wave-sync,
//     no barrier needed); per edge: uniform LDS read + readfirstlane scalar
//     base + PL loads + PL FMA.
// Template: (H,C,PL) in {(2,32,1), (2,64,2), (1,64,1)}; M=H*C.
// ---------------------------------------------------------------------------
template <int H, int C, int PL>
__global__ __launch_bounds__(256) void aggregate_kernel(
        const float* __restrict__ h,
        const float* __restrict__ alpha_s,
        const float* __restrict__ alpha_d,
        const int* __restrict__ row_ptr,
        const int* __restrict__ csr_src,
        const float* __restrict__ bias,
        float* __restrict__ out, int N) {
    constexpr int M = H * C;
    __shared__ int   ss[4][64];
    __shared__ float sp[4][128];
    const int wid  = threadIdx.x >> 6;
    const int lane = threadIdx.x & 63;
    const int n = blockIdx.x * 4 + wid;
    if (n >= N) return;

    const int lo = row_ptr[n], hi = row_ptr[n + 1];
    const int myhead = (PL == 1 && H == 2) ? (lane / C) : 0;

    float adv[H];
#pragma unroll
    for (int t = 0; t < H; ++t) adv[t] = alpha_d[n * H + t];

    float m[H], den[H], acc[PL];
#pragma unroll
    for (int t = 0; t < H; ++t) { m[t] = -INFINITY; den[t] = 0.0f; }
#pragma unroll
    for (int j = 0; j < PL; ++j) acc[j] = 0.0f;

    for (int e0 = lo; e0 < hi; e0 += 64) {
        const int idx = e0 + lane;
        const bool valid = idx < hi;
        const int src_l = csr_src[valid ? idx : hi - 1];

        // ---- phase A: lane-parallel logits ----
        float lg[H];
        if (H == 2) {
            float2 as = ((const float2*)alpha_s)[src_l];
            lg[0] = as.x + adv[0];
            lg[1] = as.y + adv[1];
        } else {
            lg[0] = alpha_s[src_l] + adv[0];
        }
#pragma unroll
        for (int t = 0; t < H; ++t) {
            float v = lg[t];
            v = v > 0.0f ? v : 0.2f * v;
            lg[t] = valid ? v : -INFINITY;
        }
        // chunk max (butterfly, result uniform)
        float cm[H];
#pragma unroll
        for (int t = 0; t < H; ++t) cm[t] = lg[t];
        for (int mm = 32; mm >= 1; mm >>= 1) {
#pragma unroll
            for (int t = 0; t < H; ++t)
                cm[t] = fmaxf(cm[t], __shfl_xor(cm[t], mm, 64));
        }
        // chunk-level rescale (exp(0)=1 when max unchanged; exp(-inf)=0 first chunk)
        float sc[H];
#pragma unroll
        for (int t = 0; t < H; ++t) {
            float mnew = fmaxf(m[t], cm[t]);
            sc[t] = __expf(m[t] - mnew);
            den[t] *= sc[t];
            m[t] = mnew;
        }
        if (PL == 2) {
#pragma unroll
            for (int j = 0; j < PL; ++j) acc[j] *= sc[j];
        } else {
            float smine = (H == 1) ? sc[0] : (myhead == 0 ? sc[0] : sc[1]);
            acc[0] *= smine;
        }
        // lane-parallel p and den sum
        float p[H], dsum[H];
#pragma unroll
        for (int t = 0; t < H; ++t) { p[t] = __expf(lg[t] - m[t]); dsum[t] = p[t]; }
        for (int mm = 32; mm >= 1; mm >>= 1) {
#pragma unroll
            for (int t = 0; t < H; ++t)
                dsum[t] += __shfl_xor(dsum[t], mm, 64);
        }
#pragma unroll
        for (int t = 0; t < H; ++t) den[t] += dsum[t];

        // stage (src, p) in this wave's LDS slice (wave-synchronous)
        ss[wid][lane] = src_l;
        if (H == 2) ((float2*)sp[wid])[lane] = make_float2(p[0], p[1]);
        else        sp[wid][lane] = p[0];

        // ---- phase B: per-edge broadcast accumulate ----
        int nu = hi - e0; if (nu > 64) nu = 64;
        int u = 0;
#pragma unroll 1
        for (; u + 4 <= nu; u += 4) {
            int su0 = __builtin_amdgcn_readfirstlane(ss[wid][u + 0]);
            int su1 = __builtin_amdgcn_readfirstlane(ss[wid][u + 1]);
            int su2 = __builtin_amdgcn_readfirstlane(ss[wid][u + 2]);
            int su3 = __builtin_amdgcn_readfirstlane(ss[wid][u + 3]);
            const float* hp0 = h + (size_t)su0 * M;
            const float* hp1 = h + (size_t)su1 * M;
            const float* hp2 = h + (size_t)su2 * M;
            const float* hp3 = h + (size_t)su3 * M;
            if (H == 2) {
                const float2* pb = (const float2*)sp[wid];
                float2 q0 = pb[u + 0], q1 = pb[u + 1], q2 = pb[u + 2], q3 = pb[u + 3];
                if (PL == 2) {
                    float a0 = hp0[lane], b0 = hp0[lane + C];
                    float a1 = hp1[lane], b1 = hp1[lane + C];
                    float a2 = hp2[lane], b2 = hp2[lane + C];
                    float a3 = hp3[lane], b3 = hp3[lane + C];
                    acc[0] += q0.x * a0; acc[PL - 1] += q0.y * b0;
                    acc[0] += q1.x * a1; acc[PL - 1] += q1.y * b1;
                    acc[0] += q2.x * a2; acc[PL - 1] += q2.y * b2;
                    acc[0] += q3.x * a3; acc[PL - 1] += q3.y * b3;
                } else {
                    float a0 = hp0[lane], a1 = hp1[lane], a2 = hp2[lane], a3 = hp3[lane];
                    float p0 = myhead == 0 ? q0.x : q0.y;
                    float p1 = myhead == 0 ? q1.x : q1.y;
                    float p2 = myhead == 0 ? q2.x : q2.y;
                    float p3 = myhead == 0 ? q3.x : q3.y;
                    acc[0] += p0 * a0; acc[0] += p1 * a1;
                    acc[0] += p2 * a2; acc[0] += p3 * a3;
                }
            } else {
                float q0 = sp[wid][u + 0], q1 = sp[wid][u + 1];
                float q2 = sp[wid][u + 2], q3 = sp[wid][u + 3];
                float a0 = hp0[lane], a1 = hp1[lane], a2 = hp2[lane], a3 = hp3[lane];
                acc[0] += q0 * a0; acc[0] += q1 * a1;
                acc[0] += q2 * a2; acc[0] += q3 * a3;
            }
        }
#pragma unroll 1
        for (; u < nu; ++u) {
            int su = __builtin_amdgcn_readfirstlane(ss[wid][u]);
            const float* hp = h + (size_t)su * M;
            if (H == 2) {
                float2 q = ((const float2*)sp[wid])[u];
                if (PL == 2) {
                    acc[0] += q.x * hp[lane];
                    acc[PL - 1] += q.y * hp[lane + C];
                } else {
                    float pv = myhead == 0 ? q.x : q.y;
                    acc[0] += pv * hp[lane];
                }
            } else {
                acc[0] += sp[wid][u] * hp[lane];
            }
        }
    }

    if (PL == 2) {
#pragma unroll
        for (int j = 0; j < PL; ++j) {
            float v = acc[j] / den[j] + bias[j * C + lane];
            out[(size_t)n * M + j * C + lane] = fmaxf(v, 0.0f);
        }
    } else {
        float dv = (H == 1) ? den[0] : (myhead == 0 ? den[0] : den[1]);
        float v = acc[0] / dv + bias[lane];
        out[(size_t)n * M + lane] = fmaxf(v, 0.0f);
    }
}

// ---------------------------------------------------------------------------

extern "C" void kernel_launch(void* const* d_in, const int* in_sizes, int n_in,
                              void* d_out, int out_size, void* d_ws, size_t ws_size,
                              hipStream_t stream) {
    const float* x   = (const float*)d_in[0];
    const int*   ei  = (const int*)  d_in[1];
    const float* w1  = (const float*)d_in[2];
    const float* as1 = (const float*)d_in[3];
    const float* ad1 = (const float*)d_in[4];
    const float* b1  = (const float*)d_in[5];
    const float* w2  = (const float*)d_in[6];
    const float* as2 = (const float*)d_in[7];
    const float* ad2 = (const float*)d_in[8];
    const float* b2  = (const float*)d_in[9];
    const float* w3  = (const float*)d_in[10];
    const float* as3 = (const float*)d_in[11];
    const float* ad3 = (const float*)d_in[12];
    const float* b3  = (const float*)d_in[13];
    const float* fcw = (const float*)d_in[14];
    const float* fcb = (const float*)d_in[15];
    float* out = (float*)d_out;

    const int N = in_sizes[0] / 128;
    const int E = in_sizes[1] / 2;
    const int Etot = E + N;

    // workspace carve-up (256B aligned regions)
    char* p = (char*)d_ws;
    auto alloc = [&](size_t bytes) {
        char* r = p;
        p += (bytes + 255) & ~(size_t)255;
        return r;
    };
    int*   cnt     = (int*)  alloc((size_t)N * 4);
    int*   row_ptr = (int*)  alloc((size_t)(N + 1) * 4);
    int*   rank    = (int*)  alloc((size_t)Etot * 4);
    int*   csr_src = (int*)  alloc((size_t)Etot * 4);
    float* bufA    = (float*)alloc((size_t)N * 128 * 4);
    float* bufB    = (float*)alloc((size_t)N * 128 * 4);
    float* alpS    = (float*)alloc((size_t)N * 2 * 4);
    float* alpD    = (float*)alloc((size_t)N * 2 * 4);
    (void)ws_size; (void)n_in; (void)out_size;

    // ---- build CSR by dst (atomics only in pass 1) ----
    hipMemsetAsync(cnt, 0, (size_t)N * 4, stream);
    int eb4 = (Etot / 4 + 255) / 256 + 1;   // 4 edges/thread
    count_rank_kernel<<<eb4, 256, 0, stream>>>(ei, E, N, cnt, rank);
    scan_kernel<<<1, 1024, 0, stream>>>(cnt, N, Etot, row_ptr);
    scatter_kernel<<<eb4, 256, 0, stream>>>(ei, E, N, row_ptr, rank, csr_src);

    int gb = (N + 3) / 4;         // aggregate: 4 waves/block, 1 node/wave
    const int GB = 1024;          // gemm persistent blocks: 4/CU

    // ---- layer 1: 128 -> H2 x C32, concat ----
    gemm_kernel<128, 64, 8, 1><<<dim3(GB, 1), 256, 0, stream>>>(
        x, w1, nullptr, bufA, as1, ad1, alpS, alpD, N, 64, 0);
    aggregate_kernel<2, 32, 1><<<gb, 256, 0, stream>>>(bufA, alpS, alpD, row_ptr, csr_src, b1, bufB, N);

    // ---- layer 2: 64 -> H2 x C64, concat ----
    gemm_kernel<64, 128, 8, 2><<<dim3(GB, 1), 256, 0, stream>>>(
        bufB, w2, nullptr, bufA, as2, ad2, alpS, alpD, N, 128, 0);
    aggregate_kernel<2, 64, 2><<<gb, 256, 0, stream>>>(bufA, alpS, alpD, row_ptr, csr_src, b2, bufB, N);

    // ---- layer 3: 128 -> H1 x C64, mean (=identity for 1 head) ----
    gemm_kernel<128, 64, 8, 3><<<dim3(GB, 1), 256, 0, stream>>>(
        bufB, w3, nullptr, bufA, as3, ad3, alpS, alpD, N, 64, 0);
    aggregate_kernel<1, 64, 1><<<gb, 256, 0, stream>>>(bufA, alpS, alpD, row_ptr, csr_src, b3, bufB, N);

    // ---- FC: 64 -> 512 + relu ----
    gemm_kernel<64, 128, 8, 0><<<dim3(GB / 4, 4), 256, 0, stream>>>(
        bufB, fcw, fcb, out, nullptr, nullptr, nullptr, nullptr, N, 512, 1);
}

// Round 7
// 857.023 us; speedup vs baseline: 1.0289x; 1.0289x over previous
//
#include <hip/hip_runtime.h>
#include <math.h>

// ---------------------------------------------------------------------------
// GAT pipeline: 3x (GEMM+alpha fused -> CSR segment-softmax aggregate) + FC
// R14: revert R13's role-swap GEMM (VGPR 88->136, occupancy halved, FC
//      130->148). GEMM = exact R10 shape (RB=8 ping-pong, unroll 2).
//      Changes: (1) aggregate phase B unroll 4->8 LOAD-BATCHED: all 8/16
//      h-row loads issued before any FMA (2x memory-level parallelism;
//      R9 showed aggs gather-latency-bound at 2.9 TB/s, not BW-bound).
//      (2) FC grid 256x4 -> 320x4: 6250 groups/1280 waves = 4.88 -> tail
//      2.4% instead of 15%. 1280 blocks = exact 5-blocks/CU LDS cap.
// ---------------------------------------------------------------------------

// pass 1: cnt[dst]++ (atomic), remember each edge's arrival rank.
__global__ void count_rank_kernel(const int* __restrict__ ei, int E, int N,
                                  int* __restrict__ cnt, int* __restrict__ rank) {
    const int Etot = E + N;
    const int T = gridDim.x * blockDim.x;
    int e = blockIdx.x * blockDim.x + threadIdx.x;
#pragma unroll 4
    for (int u = 0; u < 4; ++u, e += T) {
        if (e < Etot) {
            int dst = (e < E) ? ei[E + e] : (e - E);   // self-loops appended
            rank[e] = atomicAdd(&cnt[dst], 1);
        }
    }
}

__global__ __launch_bounds__(1024) void scan_kernel(const int* __restrict__ cnt,
                                                    int N, int Etot,
                                                    int* __restrict__ row_ptr) {
    __shared__ int sums[1024];
    int tid = threadIdx.x;
    int chunk = (N + 1023) >> 10;
    int lo = tid * chunk;
    int hi = lo + chunk; if (hi > N) hi = N; if (lo > N) lo = N;
    int s = 0;
    for (int i = lo; i < hi; ++i) s += cnt[i];
    sums[tid] = s;
    __syncthreads();
    for (int off = 1; off < 1024; off <<= 1) {
        int t = (tid >= off) ? sums[tid - off] : 0;
        __syncthreads();
        sums[tid] += t;
        __syncthreads();
    }
    int run = sums[tid] - s;   // exclusive base for this thread's chunk
    for (int i = lo; i < hi; ++i) {
        row_ptr[i] = run;
        run += cnt[i];
    }
    if (tid == 0) row_ptr[N] = Etot;
}

// pass 3: pos = row_ptr[dst] + rank[e]; atomic-free scattered store.
__global__ void scatter_kernel(const int* __restrict__ ei, int E, int N,
                               const int* __restrict__ row_ptr,
                               const int* __restrict__ rank,
                               int* __restrict__ csr_src) {
    const int Etot = E + N;
    const int T = gridDim.x * blockDim.x;
    int e = blockIdx.x * blockDim.x + threadIdx.x;
#pragma unroll 4
    for (int u = 0; u < 4; ++u, e += T) {
        if (e < Etot) {
            int src, dst;
            if (e < E) { src = ei[e]; dst = ei[E + e]; }
            else       { src = e - E; dst = e - E; }
            csr_src[row_ptr[dst] + rank[e]] = src;
        }
    }
}

// ---------------------------------------------------------------------------
// GEMM (R10-proven): out[n, cb+m] = sum_k in[n,k]*W[k,cb+m].  256-thread
// blocks (4 waves), W chunk staged to LDS once (b128 conflict-free),
// grid-stride over row groups of RB=8 rows/wave, distance-1 x ping-pong
// prefetch, partial unroll 2 (full unroll / role-swap / reg caps all spilled
// or killed occupancy: R8/R11/R13).
// ALPHA: fused alpha_s/alpha_d via wave shfl reduction over the output row:
//   0=none  1=(H2,C32,PL1: segmented 32-lane)  2=(H2,C64,PL2)  3=(H1,C64,PL1)
// K*CHUNK <= 8192 (32 KB LDS).
// ---------------------------------------------------------------------------
template <int K, int CHUNK, int RB, int ALPHA>
__global__ __launch_bounds__(256) void gemm_kernel(
        const float* __restrict__ in,
        const float* __restrict__ W,
        const float* __restrict__ bias,
        float* __restrict__ out,
        const float* __restrict__ a_src,
        const float* __restrict__ a_dst,
        float* __restrict__ alpS,
        float* __restrict__ alpD,
        int N, int M, int relu) {
    constexpr int PL = CHUNK / 64;
    constexpr int K4 = K / 4;
    __shared__ float wlds[K * CHUNK];
    const int cb = blockIdx.y * CHUNK;
    for (int idx = threadIdx.x; idx < K4 * CHUNK; idx += 256) {
        int k4 = idx / CHUNK, c = idx % CHUNK;
        const float* wp = W + (size_t)(4 * k4) * M + cb + c;
        float4 v;
        v.x = wp[0];
        v.y = wp[(size_t)M];
        v.z = wp[(size_t)2 * M];
        v.w = wp[(size_t)3 * M];
        ((float4*)wlds)[idx] = v;
    }
    __syncthreads();

    const int wid  = threadIdx.x >> 6;
    const int lane = threadIdx.x & 63;
    const float4* wlds4 = (const float4*)wlds;

    float b[PL], aSv[PL], aDv[PL];
#pragma unroll
    for (int j = 0; j < PL; ++j) {
        b[j] = bias ? bias[cb + lane + 64 * j] : 0.0f;
        if (ALPHA) { aSv[j] = a_src[lane + 64 * j]; aDv[j] = a_dst[lane + 64 * j]; }
    }

    const int groups = (N + RB - 1) / RB;
    for (int g = blockIdx.x * 4 + wid; g < groups; g += gridDim.x * 4) {
        const int n0 = g * RB;
        const bool full = (n0 + RB <= N);

        float acc[RB][PL];
#pragma unroll
        for (int r = 0; r < RB; ++r)
#pragma unroll
            for (int j = 0; j < PL; ++j) acc[r][j] = 0.0f;

        const float4* xp = (const float4*)(in + (size_t)n0 * K);

        if (full) {
            float4 xv[RB], xn[RB];
#pragma unroll
            for (int r = 0; r < RB; ++r) xv[r] = xp[r * K4];
#pragma unroll 2
            for (int k4 = 0; k4 < K4; ++k4) {
                if (k4 + 1 < K4) {
#pragma unroll
                    for (int r = 0; r < RB; ++r)
                        xn[r] = xp[r * K4 + k4 + 1];
                }
#pragma unroll
                for (int j = 0; j < PL; ++j) {
                    float4 wv = wlds4[k4 * CHUNK + lane + 64 * j];
#pragma unroll
                    for (int r = 0; r < RB; ++r) {
                        acc[r][j] += xv[r].x * wv.x;
                        acc[r][j] += xv[r].y * wv.y;
                        acc[r][j] += xv[r].z * wv.z;
                        acc[r][j] += xv[r].w * wv.w;
                    }
                }
                if (k4 + 1 < K4) {
#pragma unroll
                    for (int r = 0; r < RB; ++r) xv[r] = xn[r];
                }
            }
        } else {
#pragma unroll 1
            for (int k4 = 0; k4 < K4; ++k4) {
#pragma unroll 1
                for (int r = 0; r < RB; ++r) {
                    if (n0 + r >= N) break;
                    float4 xr = xp[(size_t)r * K4 + k4];
#pragma unroll
                    for (int j = 0; j < PL; ++j) {
                        float4 wv = wlds4[k4 * CHUNK + lane + 64 * j];
                        acc[r][j] += xr.x * wv.x;
                        acc[r][j] += xr.y * wv.y;
                        acc[r][j] += xr.z * wv.z;
                        acc[r][j] += xr.w * wv.w;
                    }
                }
            }
        }

#pragma unroll
        for (int r = 0; r < RB; ++r) {
            if (!full && n0 + r >= N) break;
            const int n = n0 + r;
            float v[PL];
#pragma unroll
            for (int j = 0; j < PL; ++j) {
                v[j] = acc[r][j] + b[j];
                if (relu) v[j] = fmaxf(v[j], 0.0f);
                out[(size_t)n * M + cb + lane + 64 * j] = v[j];
            }
            if (ALPHA) {
                float ps[PL], pd[PL];
#pragma unroll
                for (int j = 0; j < PL; ++j) { ps[j] = v[j] * aSv[j]; pd[j] = v[j] * aDv[j]; }
                const int m0 = (ALPHA == 1) ? 16 : 32;
                for (int mm = m0; mm >= 1; mm >>= 1) {
#pragma unroll
                    for (int j = 0; j < PL; ++j) {
                        ps[j] += __shfl_xor(ps[j], mm, 64);
                        pd[j] += __shfl_xor(pd[j], mm, 64);
                    }
                }
                if (ALPHA == 1) {
                    if ((lane & 31) == 0) {
                        int idx = n * 2 + (lane >> 5);
                        alpS[idx] = ps[0]; alpD[idx] = pd[0];
                    }
                } else if (ALPHA == 2) {
                    if (lane == 0) {
#pragma unroll
                        for (int j = 0; j < PL; ++j) {
                            alpS[n * 2 + j] = ps[j]; alpD[n * 2 + j] = pd[j];
                        }
                    }
                } else {
                    if (lane == 0) { alpS[n] = ps[0]; alpD[n] = pd[0]; }
                }
            }
        }
    }
}

// ---------------------------------------------------------------------------
// Aggregate R14: R10 two-phase, phase B now unroll-8 LOAD-BATCHED (all 8/16
// h-row gathers issued before any FMA -> 2x in-flight loads; R9 counters
// showed gather-latency-bound, 2.9 TB/s << any BW ceiling).
//   Phase A (lane = edge): coalesced csr_src, float2 alpha_s, leaky, wave
//     butterfly max -> chunk-level rescale of (m,den,acc), lane-parallel
//     p=exp(lg-m), butterfly den sum. 1 exp per 64 edges (per head).
//   Phase B (broadcast): (src,p) staged in per-wave LDS slice (wave-sync).
// Template: (H,C,PL) in {(2,32,1), (2,64,2), (1,64,1)}; M=H*C.
// ---------------------------------------------------------------------------
template <int H, int C, int PL>
__global__ __launch_bounds__(256) void aggregate_kernel(
        const float* __restrict__ h,
        const float* __restrict__ alpha_s,
        const float* __restrict__ alpha_d,
        const int* __restrict__ row_ptr,
        const int* __restrict__ csr_src,
        const float* __restrict__ bias,
        float* __restrict__ out, int N) {
    constexpr int M = H * C;
    __shared__ int   ss[4][64];
    __shared__ float sp[4][128];
    const int wid  = threadIdx.x >> 6;
    const int lane = threadIdx.x & 63;
    const int n = blockIdx.x * 4 + wid;
    if (n >= N) return;

    const int lo = row_ptr[n], hi = row_ptr[n + 1];
    const int myhead = (PL == 1 && H == 2) ? (lane / C) : 0;
    const int col1 = (PL == 2) ? (lane + C) : lane;   // second column (PL2)

    float adv[H];
#pragma unroll
    for (int t = 0; t < H; ++t) adv[t] = alpha_d[n * H + t];

    float m[H], den[H], acc[PL];
#pragma unroll
    for (int t = 0; t < H; ++t) { m[t] = -INFINITY; den[t] = 0.0f; }
#pragma unroll
    for (int j = 0; j < PL; ++j) acc[j] = 0.0f;

    for (int e0 = lo; e0 < hi; e0 += 64) {
        const int idx = e0 + lane;
        const bool valid = idx < hi;
        const int src_l = csr_src[valid ? idx : hi - 1];

        // ---- phase A: lane-parallel logits ----
        float lg[H];
        if (H == 2) {
            float2 as = ((const float2*)alpha_s)[src_l];
            lg[0] = as.x + adv[0];
            lg[1] = as.y + adv[1];
        } else {
            lg[0] = alpha_s[src_l] + adv[0];
        }
#pragma unroll
        for (int t = 0; t < H; ++t) {
            float v = lg[t];
            v = v > 0.0f ? v : 0.2f * v;
            lg[t] = valid ? v : -INFINITY;
        }
        // chunk max (butterfly, result uniform)
        float cm[H];
#pragma unroll
        for (int t = 0; t < H; ++t) cm[t] = lg[t];
        for (int mm = 32; mm >= 1; mm >>= 1) {
#pragma unroll
            for (int t = 0; t < H; ++t)
                cm[t] = fmaxf(cm[t], __shfl_xor(cm[t], mm, 64));
        }
        // chunk-level rescale (exp(0)=1 when max unchanged; exp(-inf)=0 first chunk)
        float sc[H];
#pragma unroll
        for (int t = 0; t < H; ++t) {
            float mnew = fmaxf(m[t], cm[t]);
            sc[t] = __expf(m[t] - mnew);
            den[t] *= sc[t];
            m[t] = mnew;
        }
        if (PL == 2) {
#pragma unroll
            for (int j = 0; j < PL; ++j) acc[j] *= sc[j];
        } else {
            float smine = (H == 1) ? sc[0] : (myhead == 0 ? sc[0] : sc[1]);
            acc[0] *= smine;
        }
        // lane-parallel p and den sum
        float p[H], dsum[H];
#pragma unroll
        for (int t = 0; t < H; ++t) { p[t] = __expf(lg[t] - m[t]); dsum[t] = p[t]; }
        for (int mm = 32; mm >= 1; mm >>= 1) {
#pragma unroll
            for (int t = 0; t < H; ++t)
                dsum[t] += __shfl_xor(dsum[t], mm, 64);
        }
#pragma unroll
        for (int t = 0; t < H; ++t) den[t] += dsum[t];

        // stage (src, p) in this wave's LDS slice (wave-synchronous)
        ss[wid][lane] = src_l;
        if (H == 2) ((float2*)sp[wid])[lane] = make_float2(p[0], p[1]);
        else        sp[wid][lane] = p[0];

        // ---- phase B: per-edge broadcast accumulate, 8-wide load batch ----
        int nu = hi - e0; if (nu > 64) nu = 64;
        int u = 0;
#pragma unroll 1
        for (; u + 8 <= nu; u += 8) {
            int su[8];
#pragma unroll
            for (int t = 0; t < 8; ++t)
                su[t] = __builtin_amdgcn_readfirstlane(ss[wid][u + t]);
            // batch-issue all gathers (8 or 16 loads in flight)
            float hv0[8], hv1[8];
#pragma unroll
            for (int t = 0; t < 8; ++t) {
                const float* hp = h + (size_t)su[t] * M;
                hv0[t] = hp[lane];
                if (PL == 2) hv1[t] = hp[col1];
            }
            // FMA pass
            if (H == 2) {
                const float2* pb = (const float2*)sp[wid];
#pragma unroll
                for (int t = 0; t < 8; ++t) {
                    float2 q = pb[u + t];
                    if (PL == 2) {
                        acc[0] += q.x * hv0[t];
                        acc[PL - 1] += q.y * hv1[t];
                    } else {
                        float pv = myhead == 0 ? q.x : q.y;
                        acc[0] += pv * hv0[t];
                    }
                }
            } else {
#pragma unroll
                for (int t = 0; t < 8; ++t)
                    acc[0] += sp[wid][u + t] * hv0[t];
            }
        }
#pragma unroll 1
        for (; u < nu; ++u) {
            int su = __builtin_amdgcn_readfirstlane(ss[wid][u]);
            const float* hp = h + (size_t)su * M;
            if (H == 2) {
                float2 q = ((const float2*)sp[wid])[u];
                if (PL == 2) {
                    acc[0] += q.x * hp[lane];
                    acc[PL - 1] += q.y * hp[col1];
                } else {
                    float pv = myhead == 0 ? q.x : q.y;
                    acc[0] += pv * hp[lane];
                }
            } else {
                acc[0] += sp[wid][u] * hp[lane];
            }
        }
    }

    if (PL == 2) {
#pragma unroll
        for (int j = 0; j < PL; ++j) {
            float v = acc[j] / den[j] + bias[j * C + lane];
            out[(size_t)n * M + j * C + lane] = fmaxf(v, 0.0f);
        }
    } else {
        float dv = (H == 1) ? den[0] : (myhead == 0 ? den[0] : den[1]);
        float v = acc[0] / dv + bias[lane];
        out[(size_t)n * M + lane] = fmaxf(v, 0.0f);
    }
}

// ---------------------------------------------------------------------------

extern "C" void kernel_launch(void* const* d_in, const int* in_sizes, int n_in,
                              void* d_out, int out_size, void* d_ws, size_t ws_size,
                              hipStream_t stream) {
    const float* x   = (const float*)d_in[0];
    const int*   ei  = (const int*)  d_in[1];
    const float* w1  = (const float*)d_in[2];
    const float* as1 = (const float*)d_in[3];
    const float* ad1 = (const float*)d_in[4];
    const float* b1  = (const float*)d_in[5];
    const float* w2  = (const float*)d_in[6];
    const float* as2 = (const float*)d_in[7];
    const float* ad2 = (const float*)d_in[8];
    const float* b2  = (const float*)d_in[9];
    const float* w3  = (const float*)d_in[10];
    const float* as3 = (const float*)d_in[11];
    const float* ad3 = (const float*)d_in[12];
    const float* b3  = (const float*)d_in[13];
    const float* fcw = (const float*)d_in[14];
    const float* fcb = (const float*)d_in[15];
    float* out = (float*)d_out;

    const int N = in_sizes[0] / 128;
    const int E = in_sizes[1] / 2;
    const int Etot = E + N;

    // workspace carve-up (256B aligned regions)
    char* p = (char*)d_ws;
    auto alloc = [&](size_t bytes) {
        char* r = p;
        p += (bytes + 255) & ~(size_t)255;
        return r;
    };
    int*   cnt     = (int*)  alloc((size_t)N * 4);
    int*   row_ptr = (int*)  alloc((size_t)(N + 1) * 4);
    int*   rank    = (int*)  alloc((size_t)Etot * 4);
    int*   csr_src = (int*)  alloc((size_t)Etot * 4);
    float* bufA    = (float*)alloc((size_t)N * 128 * 4);
    float* bufB    = (float*)alloc((size_t)N * 128 * 4);
    float* alpS    = (float*)alloc((size_t)N * 2 * 4);
    float* alpD    = (float*)alloc((size_t)N * 2 * 4);
    (void)ws_size; (void)n_in; (void)out_size;

    // ---- build CSR by dst (atomics only in pass 1) ----
    hipMemsetAsync(cnt, 0, (size_t)N * 4, stream);
    int eb4 = (Etot / 4 + 255) / 256 + 1;   // 4 edges/thread
    count_rank_kernel<<<eb4, 256, 0, stream>>>(ei, E, N, cnt, rank);
    scan_kernel<<<1, 1024, 0, stream>>>(cnt, N, Etot, row_ptr);
    scatter_kernel<<<eb4, 256, 0, stream>>>(ei, E, N, row_ptr, rank, csr_src);

    int gb = (N + 3) / 4;         // aggregate: 4 waves/block, 1 node/wave
    const int GB = 1024;          // gemm persistent blocks: 4/CU

    // ---- layer 1: 128 -> H2 x C32, concat ----
    gemm_kernel<128, 64, 8, 1><<<dim3(GB, 1), 256, 0, stream>>>(
        x, w1, nullptr, bufA, as1, ad1, alpS, alpD, N, 64, 0);
    aggregate_kernel<2, 32, 1><<<gb, 256, 0, stream>>>(bufA, alpS, alpD, row_ptr, csr_src, b1, bufB, N);

    // ---- layer 2: 64 -> H2 x C64, concat ----
    gemm_kernel<64, 128, 8, 2><<<dim3(GB, 1), 256, 0, stream>>>(
        bufB, w2, nullptr, bufA, as2, ad2, alpS, alpD, N, 128, 0);
    aggregate_kernel<2, 64, 2><<<gb, 256, 0, stream>>>(bufA, alpS, alpD, row_ptr, csr_src, b2, bufB, N);

    // ---- layer 3: 128 -> H1 x C64, mean (=identity for 1 head) ----
    gemm_kernel<128, 64, 8, 3><<<dim3(GB, 1), 256, 0, stream>>>(
        bufB, w3, nullptr, bufA, as3, ad3, alpS, alpD, N, 64, 0);
    aggregate_kernel<1, 64, 1><<<gb, 256, 0, stream>>>(bufA, alpS, alpD, row_ptr, csr_src, b3, bufB, N);

    // ---- FC: 64 -> 512 + relu: 320x4 blocks = 5/CU, tail 2.4% ----
    gemm_kernel<64, 128, 8, 0><<<dim3(320, 4), 256, 0, stream>>>(
        bufB, fcw, fcb, out, nullptr, nullptr, nullptr, nullptr, N, 512, 1);
}

// Round 8
// 850.984 us; speedup vs baseline: 1.0362x; 1.0071x over previous
//
#include <hip/hip_runtime.h>
#include <math.h>

// ---------------------------------------------------------------------------
// GAT pipeline: 3x (GEMM+alpha fused -> CSR segment-softmax aggregate) + FC
// R15: (a) revert FC grid to 256x4 (R14's 320x4 was +8us: per-slice critical
//      path is ceil(6250/4096)=2 groups either way, extra blocks only re-
//      staged W: FETCH 13->17MB). (b) layer-2 aggregate HEAD-SPLIT: 2 waves
//      per node, each owning one 64-ch head (256B/edge instead of 512B).
//      Theory: aggs are L2-fill-rate bound (R9: FETCH 372MB @2.9TB/s =
//      measured 128us; h=25.6MB >> 4MB/XCD L2 -> constant misses); doubling
//      wave count doubles outstanding-line concurrency. GEMM = R10 exact
//      (RB=8 ping-pong; R8/R11/R13 proved its register budget saturated).
// ---------------------------------------------------------------------------

// pass 1: cnt[dst]++ (atomic), remember each edge's arrival rank.
__global__ void count_rank_kernel(const int* __restrict__ ei, int E, int N,
                                  int* __restrict__ cnt, int* __restrict__ rank) {
    const int Etot = E + N;
    const int T = gridDim.x * blockDim.x;
    int e = blockIdx.x * blockDim.x + threadIdx.x;
#pragma unroll 4
    for (int u = 0; u < 4; ++u, e += T) {
        if (e < Etot) {
            int dst = (e < E) ? ei[E + e] : (e - E);   // self-loops appended
            rank[e] = atomicAdd(&cnt[dst], 1);
        }
    }
}

__global__ __launch_bounds__(1024) void scan_kernel(const int* __restrict__ cnt,
                                                    int N, int Etot,
                                                    int* __restrict__ row_ptr) {
    __shared__ int sums[1024];
    int tid = threadIdx.x;
    int chunk = (N + 1023) >> 10;
    int lo = tid * chunk;
    int hi = lo + chunk; if (hi > N) hi = N; if (lo > N) lo = N;
    int s = 0;
    for (int i = lo; i < hi; ++i) s += cnt[i];
    sums[tid] = s;
    __syncthreads();
    for (int off = 1; off < 1024; off <<= 1) {
        int t = (tid >= off) ? sums[tid - off] : 0;
        __syncthreads();
        sums[tid] += t;
        __syncthreads();
    }
    int run = sums[tid] - s;   // exclusive base for this thread's chunk
    for (int i = lo; i < hi; ++i) {
        row_ptr[i] = run;
        run += cnt[i];
    }
    if (tid == 0) row_ptr[N] = Etot;
}

// pass 3: pos = row_ptr[dst] + rank[e]; atomic-free scattered store.
__global__ void scatter_kernel(const int* __restrict__ ei, int E, int N,
                               const int* __restrict__ row_ptr,
                               const int* __restrict__ rank,
                               int* __restrict__ csr_src) {
    const int Etot = E + N;
    const int T = gridDim.x * blockDim.x;
    int e = blockIdx.x * blockDim.x + threadIdx.x;
#pragma unroll 4
    for (int u = 0; u < 4; ++u, e += T) {
        if (e < Etot) {
            int src, dst;
            if (e < E) { src = ei[e]; dst = ei[E + e]; }
            else       { src = e - E; dst = e - E; }
            csr_src[row_ptr[dst] + rank[e]] = src;
        }
    }
}

// ---------------------------------------------------------------------------
// GEMM (R10-proven): out[n, cb+m] = sum_k in[n,k]*W[k,cb+m].  256-thread
// blocks (4 waves), W chunk staged to LDS once (b128 conflict-free),
// grid-stride over row groups of RB=8 rows/wave, distance-1 x ping-pong
// prefetch, partial unroll 2.
// ALPHA: fused alpha_s/alpha_d via wave shfl reduction over the output row:
//   0=none  1=(H2,C32,PL1: segmented 32-lane)  2=(H2,C64,PL2)  3=(H1,C64,PL1)
// K*CHUNK <= 8192 (32 KB LDS).
// ---------------------------------------------------------------------------
template <int K, int CHUNK, int RB, int ALPHA>
__global__ __launch_bounds__(256) void gemm_kernel(
        const float* __restrict__ in,
        const float* __restrict__ W,
        const float* __restrict__ bias,
        float* __restrict__ out,
        const float* __restrict__ a_src,
        const float* __restrict__ a_dst,
        float* __restrict__ alpS,
        float* __restrict__ alpD,
        int N, int M, int relu) {
    constexpr int PL = CHUNK / 64;
    constexpr int K4 = K / 4;
    __shared__ float wlds[K * CHUNK];
    const int cb = blockIdx.y * CHUNK;
    for (int idx = threadIdx.x; idx < K4 * CHUNK; idx += 256) {
        int k4 = idx / CHUNK, c = idx % CHUNK;
        const float* wp = W + (size_t)(4 * k4) * M + cb + c;
        float4 v;
        v.x = wp[0];
        v.y = wp[(size_t)M];
        v.z = wp[(size_t)2 * M];
        v.w = wp[(size_t)3 * M];
        ((float4*)wlds)[idx] = v;
    }
    __syncthreads();

    const int wid  = threadIdx.x >> 6;
    const int lane = threadIdx.x & 63;
    const float4* wlds4 = (const float4*)wlds;

    float b[PL], aSv[PL], aDv[PL];
#pragma unroll
    for (int j = 0; j < PL; ++j) {
        b[j] = bias ? bias[cb + lane + 64 * j] : 0.0f;
        if (ALPHA) { aSv[j] = a_src[lane + 64 * j]; aDv[j] = a_dst[lane + 64 * j]; }
    }

    const int groups = (N + RB - 1) / RB;
    for (int g = blockIdx.x * 4 + wid; g < groups; g += gridDim.x * 4) {
        const int n0 = g * RB;
        const bool full = (n0 + RB <= N);

        float acc[RB][PL];
#pragma unroll
        for (int r = 0; r < RB; ++r)
#pragma unroll
            for (int j = 0; j < PL; ++j) acc[r][j] = 0.0f;

        const float4* xp = (const float4*)(in + (size_t)n0 * K);

        if (full) {
            float4 xv[RB], xn[RB];
#pragma unroll
            for (int r = 0; r < RB; ++r) xv[r] = xp[r * K4];
#pragma unroll 2
            for (int k4 = 0; k4 < K4; ++k4) {
                if (k4 + 1 < K4) {
#pragma unroll
                    for (int r = 0; r < RB; ++r)
                        xn[r] = xp[r * K4 + k4 + 1];
                }
#pragma unroll
                for (int j = 0; j < PL; ++j) {
                    float4 wv = wlds4[k4 * CHUNK + lane + 64 * j];
#pragma unroll
                    for (int r = 0; r < RB; ++r) {
                        acc[r][j] += xv[r].x * wv.x;
                        acc[r][j] += xv[r].y * wv.y;
                        acc[r][j] += xv[r].z * wv.z;
                        acc[r][j] += xv[r].w * wv.w;
                    }
                }
                if (k4 + 1 < K4) {
#pragma unroll
                    for (int r = 0; r < RB; ++r) xv[r] = xn[r];
                }
            }
        } else {
#pragma unroll 1
            for (int k4 = 0; k4 < K4; ++k4) {
#pragma unroll 1
                for (int r = 0; r < RB; ++r) {
                    if (n0 + r >= N) break;
                    float4 xr = xp[(size_t)r * K4 + k4];
#pragma unroll
                    for (int j = 0; j < PL; ++j) {
                        float4 wv = wlds4[k4 * CHUNK + lane + 64 * j];
                        acc[r][j] += xr.x * wv.x;
                        acc[r][j] += xr.y * wv.y;
                        acc[r][j] += xr.z * wv.z;
                        acc[r][j] += xr.w * wv.w;
                    }
                }
            }
        }

#pragma unroll
        for (int r = 0; r < RB; ++r) {
            if (!full && n0 + r >= N) break;
            const int n = n0 + r;
            float v[PL];
#pragma unroll
            for (int j = 0; j < PL; ++j) {
                v[j] = acc[r][j] + b[j];
                if (relu) v[j] = fmaxf(v[j], 0.0f);
                out[(size_t)n * M + cb + lane + 64 * j] = v[j];
            }
            if (ALPHA) {
                float ps[PL], pd[PL];
#pragma unroll
                for (int j = 0; j < PL; ++j) { ps[j] = v[j] * aSv[j]; pd[j] = v[j] * aDv[j]; }
                const int m0 = (ALPHA == 1) ? 16 : 32;
                for (int mm = m0; mm >= 1; mm >>= 1) {
#pragma unroll
                    for (int j = 0; j < PL; ++j) {
                        ps[j] += __shfl_xor(ps[j], mm, 64);
                        pd[j] += __shfl_xor(pd[j], mm, 64);
                    }
                }
                if (ALPHA == 1) {
                    if ((lane & 31) == 0) {
                        int idx = n * 2 + (lane >> 5);
                        alpS[idx] = ps[0]; alpD[idx] = pd[0];
                    }
                } else if (ALPHA == 2) {
                    if (lane == 0) {
#pragma unroll
                        for (int j = 0; j < PL; ++j) {
                            alpS[n * 2 + j] = ps[j]; alpD[n * 2 + j] = pd[j];
                        }
                    }
                } else {
                    if (lane == 0) { alpS[n] = ps[0]; alpD[n] = pd[0]; }
                }
            }
        }
    }
}

// ---------------------------------------------------------------------------
// Aggregate (PL1 variants, layers 1+3): one wave per dst node, 64-edge
// chunks, two-phase (lane-parallel logits; broadcast accumulate, 8-wide
// load batch). Template: (H,C) in {(2,32), (1,64)}; M=H*C=64.
// ---------------------------------------------------------------------------
template <int H, int C>
__global__ __launch_bounds__(256) void aggregate_kernel(
        const float* __restrict__ h,
        const float* __restrict__ alpha_s,
        const float* __restrict__ alpha_d,
        const int* __restrict__ row_ptr,
        const int* __restrict__ csr_src,
        const float* __restrict__ bias,
        float* __restrict__ out, int N) {
    constexpr int M = H * C;
    __shared__ int   ss[4][64];
    __shared__ float sp[4][128];
    const int wid  = threadIdx.x >> 6;
    const int lane = threadIdx.x & 63;
    const int n = blockIdx.x * 4 + wid;
    if (n >= N) return;

    const int lo = row_ptr[n], hi = row_ptr[n + 1];
    const int myhead = (H == 2) ? (lane / C) : 0;

    float adv[H];
#pragma unroll
    for (int t = 0; t < H; ++t) adv[t] = alpha_d[n * H + t];

    float m[H], den[H], acc = 0.0f;
#pragma unroll
    for (int t = 0; t < H; ++t) { m[t] = -INFINITY; den[t] = 0.0f; }

    for (int e0 = lo; e0 < hi; e0 += 64) {
        const int idx = e0 + lane;
        const bool valid = idx < hi;
        const int src_l = csr_src[valid ? idx : hi - 1];

        // ---- phase A: lane-parallel logits ----
        float lg[H];
        if (H == 2) {
            float2 as = ((const float2*)alpha_s)[src_l];
            lg[0] = as.x + adv[0];
            lg[1] = as.y + adv[1];
        } else {
            lg[0] = alpha_s[src_l] + adv[0];
        }
#pragma unroll
        for (int t = 0; t < H; ++t) {
            float v = lg[t];
            v = v > 0.0f ? v : 0.2f * v;
            lg[t] = valid ? v : -INFINITY;
        }
        float cm[H];
#pragma unroll
        for (int t = 0; t < H; ++t) cm[t] = lg[t];
        for (int mm = 32; mm >= 1; mm >>= 1) {
#pragma unroll
            for (int t = 0; t < H; ++t)
                cm[t] = fmaxf(cm[t], __shfl_xor(cm[t], mm, 64));
        }
        float sc[H];
#pragma unroll
        for (int t = 0; t < H; ++t) {
            float mnew = fmaxf(m[t], cm[t]);
            sc[t] = __expf(m[t] - mnew);
            den[t] *= sc[t];
            m[t] = mnew;
        }
        acc *= (H == 1) ? sc[0] : (myhead == 0 ? sc[0] : sc[1]);

        float p[H], dsum[H];
#pragma unroll
        for (int t = 0; t < H; ++t) { p[t] = __expf(lg[t] - m[t]); dsum[t] = p[t]; }
        for (int mm = 32; mm >= 1; mm >>= 1) {
#pragma unroll
            for (int t = 0; t < H; ++t)
                dsum[t] += __shfl_xor(dsum[t], mm, 64);
        }
#pragma unroll
        for (int t = 0; t < H; ++t) den[t] += dsum[t];

        ss[wid][lane] = src_l;
        if (H == 2) ((float2*)sp[wid])[lane] = make_float2(p[0], p[1]);
        else        sp[wid][lane] = p[0];

        // ---- phase B: per-edge broadcast accumulate, 8-wide batch ----
        int nu = hi - e0; if (nu > 64) nu = 64;
        int u = 0;
#pragma unroll 1
        for (; u + 8 <= nu; u += 8) {
            int su[8];
#pragma unroll
            for (int t = 0; t < 8; ++t)
                su[t] = __builtin_amdgcn_readfirstlane(ss[wid][u + t]);
            float hv[8];
#pragma unroll
            for (int t = 0; t < 8; ++t)
                hv[t] = h[(size_t)su[t] * M + lane];
            if (H == 2) {
                const float2* pb = (const float2*)sp[wid];
#pragma unroll
                for (int t = 0; t < 8; ++t) {
                    float2 q = pb[u + t];
                    acc += (myhead == 0 ? q.x : q.y) * hv[t];
                }
            } else {
#pragma unroll
                for (int t = 0; t < 8; ++t)
                    acc += sp[wid][u + t] * hv[t];
            }
        }
#pragma unroll 1
        for (; u < nu; ++u) {
            int su = __builtin_amdgcn_readfirstlane(ss[wid][u]);
            float hv = h[(size_t)su * M + lane];
            if (H == 2) {
                float2 q = ((const float2*)sp[wid])[u];
                acc += (myhead == 0 ? q.x : q.y) * hv;
            } else {
                acc += sp[wid][u] * hv;
            }
        }
    }

    float dv = (H == 1) ? den[0] : (myhead == 0 ? den[0] : den[1]);
    float v = acc / dv + bias[lane];
    out[(size_t)n * M + lane] = fmaxf(v, 0.0f);
}

// ---------------------------------------------------------------------------
// Layer-2 aggregate, HEAD-SPLIT: 2 waves per node; wave (n, hd) owns head
// hd's 64 channels (256B/edge gather). Doubles wave count -> doubles
// outstanding gather lines (fill-concurrency theory); halves per-wave state.
// ---------------------------------------------------------------------------
__global__ __launch_bounds__(256) void aggregate2_kernel(
        const float* __restrict__ h,        // [N][128]
        const float* __restrict__ alpha_s,  // [N][2]
        const float* __restrict__ alpha_d,  // [N][2]
        const int* __restrict__ row_ptr,
        const int* __restrict__ csr_src,
        const float* __restrict__ bias,     // [128]
        float* __restrict__ out, int N) {
    __shared__ int   ss[4][64];
    __shared__ float sp[4][64];
    const int wid  = threadIdx.x >> 6;
    const int lane = threadIdx.x & 63;
    const int gw   = blockIdx.x * 4 + wid;
    const int n    = gw >> 1;
    const int hd   = gw & 1;
    if (n >= N) return;

    const int lo = row_ptr[n], hi = row_ptr[n + 1];
    const float adv = alpha_d[n * 2 + hd];

    float m = -INFINITY, den = 0.0f, acc = 0.0f;

    for (int e0 = lo; e0 < hi; e0 += 64) {
        const int idx = e0 + lane;
        const bool valid = idx < hi;
        const int src_l = csr_src[valid ? idx : hi - 1];

        // phase A: lane-parallel logits (single head)
        float lg = alpha_s[src_l * 2 + hd] + adv;
        lg = lg > 0.0f ? lg : 0.2f * lg;
        if (!valid) lg = -INFINITY;

        float cm = lg;
        for (int mm = 32; mm >= 1; mm >>= 1)
            cm = fmaxf(cm, __shfl_xor(cm, mm, 64));

        float mnew = fmaxf(m, cm);
        float sc = __expf(m - mnew);
        den *= sc; acc *= sc; m = mnew;

        float p = __expf(lg - m), ds = p;
        for (int mm = 32; mm >= 1; mm >>= 1)
            ds += __shfl_xor(ds, mm, 64);
        den += ds;

        ss[wid][lane] = src_l;
        sp[wid][lane] = p;

        // phase B: broadcast accumulate over this head's 64 channels
        int nu = hi - e0; if (nu > 64) nu = 64;
        int u = 0;
#pragma unroll 1
        for (; u + 8 <= nu; u += 8) {
            int su[8];
#pragma unroll
            for (int t = 0; t < 8; ++t)
                su[t] = __builtin_amdgcn_readfirstlane(ss[wid][u + t]);
            float hv[8];
#pragma unroll
            for (int t = 0; t < 8; ++t)
                hv[t] = h[(size_t)su[t] * 128 + hd * 64 + lane];
#pragma unroll
            for (int t = 0; t < 8; ++t)
                acc += sp[wid][u + t] * hv[t];
        }
#pragma unroll 1
        for (; u < nu; ++u) {
            int su = __builtin_amdgcn_readfirstlane(ss[wid][u]);
            acc += sp[wid][u] * h[(size_t)su * 128 + hd * 64 + lane];
        }
    }

    float v = acc / den + bias[hd * 64 + lane];
    out[(size_t)n * 128 + hd * 64 + lane] = fmaxf(v, 0.0f);
}

// ---------------------------------------------------------------------------

extern "C" void kernel_launch(void* const* d_in, const int* in_sizes, int n_in,
                              void* d_out, int out_size, void* d_ws, size_t ws_size,
                              hipStream_t stream) {
    const float* x   = (const float*)d_in[0];
    const int*   ei  = (const int*)  d_in[1];
    const float* w1  = (const float*)d_in[2];
    const float* as1 = (const float*)d_in[3];
    const float* ad1 = (const float*)d_in[4];
    const float* b1  = (const float*)d_in[5];
    const float* w2  = (const float*)d_in[6];
    const float* as2 = (const float*)d_in[7];
    const float* ad2 = (const float*)d_in[8];
    const float* b2  = (const float*)d_in[9];
    const float* w3  = (const float*)d_in[10];
    const float* as3 = (const float*)d_in[11];
    const float* ad3 = (const float*)d_in[12];
    const float* b3  = (const float*)d_in[13];
    const float* fcw = (const float*)d_in[14];
    const float* fcb = (const float*)d_in[15];
    float* out = (float*)d_out;

    const int N = in_sizes[0] / 128;
    const int E = in_sizes[1] / 2;
    const int Etot = E + N;

    // workspace carve-up (256B aligned regions)
    char* p = (char*)d_ws;
    auto alloc = [&](size_t bytes) {
        char* r = p;
        p += (bytes + 255) & ~(size_t)255;
        return r;
    };
    int*   cnt     = (int*)  alloc((size_t)N * 4);
    int*   row_ptr = (int*)  alloc((size_t)(N + 1) * 4);
    int*   rank    = (int*)  alloc((size_t)Etot * 4);
    int*   csr_src = (int*)  alloc((size_t)Etot * 4);
    float* bufA    = (float*)alloc((size_t)N * 128 * 4);
    float* bufB    = (float*)alloc((size_t)N * 128 * 4);
    float* alpS    = (float*)alloc((size_t)N * 2 * 4);
    float* alpD    = (float*)alloc((size_t)N * 2 * 4);
    (void)ws_size; (void)n_in; (void)out_size;

    // ---- build CSR by dst (atomics only in pass 1) ----
    hipMemsetAsync(cnt, 0, (size_t)N * 4, stream);
    int eb4 = (Etot / 4 + 255) / 256 + 1;   // 4 edges/thread
    count_rank_kernel<<<eb4, 256, 0, stream>>>(ei, E, N, cnt, rank);
    scan_kernel<<<1, 1024, 0, stream>>>(cnt, N, Etot, row_ptr);
    scatter_kernel<<<eb4, 256, 0, stream>>>(ei, E, N, row_ptr, rank, csr_src);

    int gb  = (N + 3) / 4;        // aggregate (PL1): 4 waves/block, 1 node/wave
    int gb2 = (2 * N + 3) / 4;    // aggregate2: 2 waves/node
    const int GB = 1024;          // gemm persistent blocks: 4/CU

    // ---- layer 1: 128 -> H2 x C32, concat ----
    gemm_kernel<128, 64, 8, 1><<<dim3(GB, 1), 256, 0, stream>>>(
        x, w1, nullptr, bufA, as1, ad1, alpS, alpD, N, 64, 0);
    aggregate_kernel<2, 32><<<gb, 256, 0, stream>>>(bufA, alpS, alpD, row_ptr, csr_src, b1, bufB, N);

    // ---- layer 2: 64 -> H2 x C64, concat (head-split aggregate) ----
    gemm_kernel<64, 128, 8, 2><<<dim3(GB, 1), 256, 0, stream>>>(
        bufB, w2, nullptr, bufA, as2, ad2, alpS, alpD, N, 128, 0);
    aggregate2_kernel<<<gb2, 256, 0, stream>>>(bufA, alpS, alpD, row_ptr, csr_src, b2, bufB, N);

    // ---- layer 3: 128 -> H1 x C64, mean (=identity for 1 head) ----
    gemm_kernel<128, 64, 8, 3><<<dim3(GB, 1), 256, 0, stream>>>(
        bufB, w3, nullptr, bufA, as3, ad3, alpS, alpD, N, 64, 0);
    aggregate_kernel<1, 64><<<gb, 256, 0, stream>>>(bufA, alpS, alpD, row_ptr, csr_src, b3, bufB, N);

    // ---- FC: 64 -> 512 + relu ----
    gemm_kernel<64, 128, 8, 0><<<dim3(GB / 4, 4), 256, 0, stream>>>(
        bufB, fcw, fcb, out, nullptr, nullptr, nullptr, nullptr, N, 512, 1);
}

// Round 9
// 790.078 us; speedup vs baseline: 1.1160x; 1.0771x over previous
//
#include <hip/hip_runtime.h>
#include <hip/hip_fp16.h>
#include <math.h>

// ---------------------------------------------------------------------------
// GAT pipeline: 3x (GEMM+alpha fused -> CSR segment-softmax aggregate) + FC
// R16: fp16 h for the gather path. Evidence: R14 (2x per-wave MLP) and R15
//      (2x wave concurrency) both NEUTRAL on aggregates -> they sit at a
//      fill/transaction-rate wall (~3.1 TB/s random row-gather), not a
//      latency wall. Lever: bytes/edge. bufA (GEMM->aggregate h) is now
//      fp16: gather bytes and cache-lines halve, L2 footprint halves.
//      Numerically sensitive state stays fp32: alpha_s/d computed from fp32
//      acc BEFORE conversion; softmax state fp32; accumulate fp32; bufB
//      (aggregate->next GEMM) fp32. GEMM/agg structures = R15 (proven).
//      Tripwire: absmax blowup -> revert to fp32 next round.
// ---------------------------------------------------------------------------

// pass 1: cnt[dst]++ (atomic), remember each edge's arrival rank.
__global__ void count_rank_kernel(const int* __restrict__ ei, int E, int N,
                                  int* __restrict__ cnt, int* __restrict__ rank) {
    const int Etot = E + N;
    const int T = gridDim.x * blockDim.x;
    int e = blockIdx.x * blockDim.x + threadIdx.x;
#pragma unroll 4
    for (int u = 0; u < 4; ++u, e += T) {
        if (e < Etot) {
            int dst = (e < E) ? ei[E + e] : (e - E);   // self-loops appended
            rank[e] = atomicAdd(&cnt[dst], 1);
        }
    }
}

__global__ __launch_bounds__(1024) void scan_kernel(const int* __restrict__ cnt,
                                                    int N, int Etot,
                                                    int* __restrict__ row_ptr) {
    __shared__ int sums[1024];
    int tid = threadIdx.x;
    int chunk = (N + 1023) >> 10;
    int lo = tid * chunk;
    int hi = lo + chunk; if (hi > N) hi = N; if (lo > N) lo = N;
    int s = 0;
    for (int i = lo; i < hi; ++i) s += cnt[i];
    sums[tid] = s;
    __syncthreads();
    for (int off = 1; off < 1024; off <<= 1) {
        int t = (tid >= off) ? sums[tid - off] : 0;
        __syncthreads();
        sums[tid] += t;
        __syncthreads();
    }
    int run = sums[tid] - s;   // exclusive base for this thread's chunk
    for (int i = lo; i < hi; ++i) {
        row_ptr[i] = run;
        run += cnt[i];
    }
    if (tid == 0) row_ptr[N] = Etot;
}

// pass 3: pos = row_ptr[dst] + rank[e]; atomic-free scattered store.
__global__ void scatter_kernel(const int* __restrict__ ei, int E, int N,
                               const int* __restrict__ row_ptr,
                               const int* __restrict__ rank,
                               int* __restrict__ csr_src) {
    const int Etot = E + N;
    const int T = gridDim.x * blockDim.x;
    int e = blockIdx.x * blockDim.x + threadIdx.x;
#pragma unroll 4
    for (int u = 0; u < 4; ++u, e += T) {
        if (e < Etot) {
            int src, dst;
            if (e < E) { src = ei[e]; dst = ei[E + e]; }
            else       { src = e - E; dst = e - E; }
            csr_src[row_ptr[dst] + rank[e]] = src;
        }
    }
}

// ---------------------------------------------------------------------------
// GEMM (R10-proven loop): out[n, cb+m] = sum_k in[n,k]*W[k,cb+m]. 256-thread
// blocks (4 waves), W chunk staged to LDS once (b128 conflict-free),
// grid-stride over row groups of RB=8 rows/wave, distance-1 x ping-pong
// prefetch, partial unroll 2. OT = output element type (fp16 for h buffers
// feeding aggregates, fp32 for FC). alpha computed from fp32 acc (full
// precision) BEFORE the OT conversion.
// ALPHA: 0=none  1=(H2,C32: segmented 32-lane)  2=(H2,C64,PL2)  3=(H1,C64)
// K*CHUNK <= 8192 (32 KB LDS).
// ---------------------------------------------------------------------------
template <int K, int CHUNK, int RB, int ALPHA, typename OT>
__global__ __launch_bounds__(256) void gemm_kernel(
        const float* __restrict__ in,
        const float* __restrict__ W,
        const float* __restrict__ bias,
        OT* __restrict__ out,
        const float* __restrict__ a_src,
        const float* __restrict__ a_dst,
        float* __restrict__ alpS,
        float* __restrict__ alpD,
        int N, int M, int relu) {
    constexpr int PL = CHUNK / 64;
    constexpr int K4 = K / 4;
    __shared__ float wlds[K * CHUNK];
    const int cb = blockIdx.y * CHUNK;
    for (int idx = threadIdx.x; idx < K4 * CHUNK; idx += 256) {
        int k4 = idx / CHUNK, c = idx % CHUNK;
        const float* wp = W + (size_t)(4 * k4) * M + cb + c;
        float4 v;
        v.x = wp[0];
        v.y = wp[(size_t)M];
        v.z = wp[(size_t)2 * M];
        v.w = wp[(size_t)3 * M];
        ((float4*)wlds)[idx] = v;
    }
    __syncthreads();

    const int wid  = threadIdx.x >> 6;
    const int lane = threadIdx.x & 63;
    const float4* wlds4 = (const float4*)wlds;

    float b[PL], aSv[PL], aDv[PL];
#pragma unroll
    for (int j = 0; j < PL; ++j) {
        b[j] = bias ? bias[cb + lane + 64 * j] : 0.0f;
        if (ALPHA) { aSv[j] = a_src[lane + 64 * j]; aDv[j] = a_dst[lane + 64 * j]; }
    }

    const int groups = (N + RB - 1) / RB;
    for (int g = blockIdx.x * 4 + wid; g < groups; g += gridDim.x * 4) {
        const int n0 = g * RB;
        const bool full = (n0 + RB <= N);

        float acc[RB][PL];
#pragma unroll
        for (int r = 0; r < RB; ++r)
#pragma unroll
            for (int j = 0; j < PL; ++j) acc[r][j] = 0.0f;

        const float4* xp = (const float4*)(in + (size_t)n0 * K);

        if (full) {
            float4 xv[RB], xn[RB];
#pragma unroll
            for (int r = 0; r < RB; ++r) xv[r] = xp[r * K4];
#pragma unroll 2
            for (int k4 = 0; k4 < K4; ++k4) {
                if (k4 + 1 < K4) {
#pragma unroll
                    for (int r = 0; r < RB; ++r)
                        xn[r] = xp[r * K4 + k4 + 1];
                }
#pragma unroll
                for (int j = 0; j < PL; ++j) {
                    float4 wv = wlds4[k4 * CHUNK + lane + 64 * j];
#pragma unroll
                    for (int r = 0; r < RB; ++r) {
                        acc[r][j] += xv[r].x * wv.x;
                        acc[r][j] += xv[r].y * wv.y;
                        acc[r][j] += xv[r].z * wv.z;
                        acc[r][j] += xv[r].w * wv.w;
                    }
                }
                if (k4 + 1 < K4) {
#pragma unroll
                    for (int r = 0; r < RB; ++r) xv[r] = xn[r];
                }
            }
        } else {
#pragma unroll 1
            for (int k4 = 0; k4 < K4; ++k4) {
#pragma unroll 1
                for (int r = 0; r < RB; ++r) {
                    if (n0 + r >= N) break;
                    float4 xr = xp[(size_t)r * K4 + k4];
#pragma unroll
                    for (int j = 0; j < PL; ++j) {
                        float4 wv = wlds4[k4 * CHUNK + lane + 64 * j];
                        acc[r][j] += xr.x * wv.x;
                        acc[r][j] += xr.y * wv.y;
                        acc[r][j] += xr.z * wv.z;
                        acc[r][j] += xr.w * wv.w;
                    }
                }
            }
        }

#pragma unroll
        for (int r = 0; r < RB; ++r) {
            if (!full && n0 + r >= N) break;
            const int n = n0 + r;
            float v[PL];
#pragma unroll
            for (int j = 0; j < PL; ++j) {
                v[j] = acc[r][j] + b[j];
                if (relu) v[j] = fmaxf(v[j], 0.0f);
                out[(size_t)n * M + cb + lane + 64 * j] = (OT)v[j];
            }
            if (ALPHA) {
                float ps[PL], pd[PL];
#pragma unroll
                for (int j = 0; j < PL; ++j) { ps[j] = v[j] * aSv[j]; pd[j] = v[j] * aDv[j]; }
                const int m0 = (ALPHA == 1) ? 16 : 32;
                for (int mm = m0; mm >= 1; mm >>= 1) {
#pragma unroll
                    for (int j = 0; j < PL; ++j) {
                        ps[j] += __shfl_xor(ps[j], mm, 64);
                        pd[j] += __shfl_xor(pd[j], mm, 64);
                    }
                }
                if (ALPHA == 1) {
                    if ((lane & 31) == 0) {
                        int idx = n * 2 + (lane >> 5);
                        alpS[idx] = ps[0]; alpD[idx] = pd[0];
                    }
                } else if (ALPHA == 2) {
                    if (lane == 0) {
#pragma unroll
                        for (int j = 0; j < PL; ++j) {
                            alpS[n * 2 + j] = ps[j]; alpD[n * 2 + j] = pd[j];
                        }
                    }
                } else {
                    if (lane == 0) { alpS[n] = ps[0]; alpD[n] = pd[0]; }
                }
            }
        }
    }
}

// ---------------------------------------------------------------------------
// Aggregate (PL1 variants, layers 1+3): one wave per dst node, 64-edge
// chunks, two-phase; h gathered as FP16 (half the bytes/lines of fp32),
// converted to fp32 at use; softmax state and accumulation fp32.
// Template: (H,C) in {(2,32), (1,64)}; M=H*C=64.
// ---------------------------------------------------------------------------
template <int H, int C>
__global__ __launch_bounds__(256) void aggregate_kernel(
        const __half* __restrict__ h,
        const float* __restrict__ alpha_s,
        const float* __restrict__ alpha_d,
        const int* __restrict__ row_ptr,
        const int* __restrict__ csr_src,
        const float* __restrict__ bias,
        float* __restrict__ out, int N) {
    constexpr int M = H * C;
    __shared__ int   ss[4][64];
    __shared__ float sp[4][128];
    const int wid  = threadIdx.x >> 6;
    const int lane = threadIdx.x & 63;
    const int n = blockIdx.x * 4 + wid;
    if (n >= N) return;

    const int lo = row_ptr[n], hi = row_ptr[n + 1];
    const int myhead = (H == 2) ? (lane / C) : 0;

    float adv[H];
#pragma unroll
    for (int t = 0; t < H; ++t) adv[t] = alpha_d[n * H + t];

    float m[H], den[H], acc = 0.0f;
#pragma unroll
    for (int t = 0; t < H; ++t) { m[t] = -INFINITY; den[t] = 0.0f; }

    for (int e0 = lo; e0 < hi; e0 += 64) {
        const int idx = e0 + lane;
        const bool valid = idx < hi;
        const int src_l = csr_src[valid ? idx : hi - 1];

        // ---- phase A: lane-parallel logits ----
        float lg[H];
        if (H == 2) {
            float2 as = ((const float2*)alpha_s)[src_l];
            lg[0] = as.x + adv[0];
            lg[1] = as.y + adv[1];
        } else {
            lg[0] = alpha_s[src_l] + adv[0];
        }
#pragma unroll
        for (int t = 0; t < H; ++t) {
            float v = lg[t];
            v = v > 0.0f ? v : 0.2f * v;
            lg[t] = valid ? v : -INFINITY;
        }
        float cm[H];
#pragma unroll
        for (int t = 0; t < H; ++t) cm[t] = lg[t];
        for (int mm = 32; mm >= 1; mm >>= 1) {
#pragma unroll
            for (int t = 0; t < H; ++t)
                cm[t] = fmaxf(cm[t], __shfl_xor(cm[t], mm, 64));
        }
        float sc[H];
#pragma unroll
        for (int t = 0; t < H; ++t) {
            float mnew = fmaxf(m[t], cm[t]);
            sc[t] = __expf(m[t] - mnew);
            den[t] *= sc[t];
            m[t] = mnew;
        }
        acc *= (H == 1) ? sc[0] : (myhead == 0 ? sc[0] : sc[1]);

        float p[H], dsum[H];
#pragma unroll
        for (int t = 0; t < H; ++t) { p[t] = __expf(lg[t] - m[t]); dsum[t] = p[t]; }
        for (int mm = 32; mm >= 1; mm >>= 1) {
#pragma unroll
            for (int t = 0; t < H; ++t)
                dsum[t] += __shfl_xor(dsum[t], mm, 64);
        }
#pragma unroll
        for (int t = 0; t < H; ++t) den[t] += dsum[t];

        ss[wid][lane] = src_l;
        if (H == 2) ((float2*)sp[wid])[lane] = make_float2(p[0], p[1]);
        else        sp[wid][lane] = p[0];

        // ---- phase B: per-edge broadcast accumulate, 8-wide batch ----
        int nu = hi - e0; if (nu > 64) nu = 64;
        int u = 0;
#pragma unroll 1
        for (; u + 8 <= nu; u += 8) {
            int su[8];
#pragma unroll
            for (int t = 0; t < 8; ++t)
                su[t] = __builtin_amdgcn_readfirstlane(ss[wid][u + t]);
            float hv[8];
#pragma unroll
            for (int t = 0; t < 8; ++t)
                hv[t] = __half2float(h[(size_t)su[t] * M + lane]);
            if (H == 2) {
                const float2* pb = (const float2*)sp[wid];
#pragma unroll
                for (int t = 0; t < 8; ++t) {
                    float2 q = pb[u + t];
                    acc += (myhead == 0 ? q.x : q.y) * hv[t];
                }
            } else {
#pragma unroll
                for (int t = 0; t < 8; ++t)
                    acc += sp[wid][u + t] * hv[t];
            }
        }
#pragma unroll 1
        for (; u < nu; ++u) {
            int su = __builtin_amdgcn_readfirstlane(ss[wid][u]);
            float hv = __half2float(h[(size_t)su * M + lane]);
            if (H == 2) {
                float2 q = ((const float2*)sp[wid])[u];
                acc += (myhead == 0 ? q.x : q.y) * hv;
            } else {
                acc += sp[wid][u] * hv;
            }
        }
    }

    float dv = (H == 1) ? den[0] : (myhead == 0 ? den[0] : den[1]);
    float v = acc / dv + bias[lane];
    out[(size_t)n * M + lane] = fmaxf(v, 0.0f);
}

// ---------------------------------------------------------------------------
// Layer-2 aggregate, HEAD-SPLIT (R15): 2 waves per node; wave (n, hd) owns
// head hd's 64 channels. h gathered as FP16 (128B/edge instead of 256B).
// ---------------------------------------------------------------------------
__global__ __launch_bounds__(256) void aggregate2_kernel(
        const __half* __restrict__ h,       // [N][128] fp16
        const float* __restrict__ alpha_s,  // [N][2]
        const float* __restrict__ alpha_d,  // [N][2]
        const int* __restrict__ row_ptr,
        const int* __restrict__ csr_src,
        const float* __restrict__ bias,     // [128]
        float* __restrict__ out, int N) {
    __shared__ int   ss[4][64];
    __shared__ float sp[4][64];
    const int wid  = threadIdx.x >> 6;
    const int lane = threadIdx.x & 63;
    const int gw   = blockIdx.x * 4 + wid;
    const int n    = gw >> 1;
    const int hd   = gw & 1;
    if (n >= N) return;

    const int lo = row_ptr[n], hi = row_ptr[n + 1];
    const float adv = alpha_d[n * 2 + hd];

    float m = -INFINITY, den = 0.0f, acc = 0.0f;

    for (int e0 = lo; e0 < hi; e0 += 64) {
        const int idx = e0 + lane;
        const bool valid = idx < hi;
        const int src_l = csr_src[valid ? idx : hi - 1];

        float lg = alpha_s[src_l * 2 + hd] + adv;
        lg = lg > 0.0f ? lg : 0.2f * lg;
        if (!valid) lg = -INFINITY;

        float cm = lg;
        for (int mm = 32; mm >= 1; mm >>= 1)
            cm = fmaxf(cm, __shfl_xor(cm, mm, 64));

        float mnew = fmaxf(m, cm);
        float sc = __expf(m - mnew);
        den *= sc; acc *= sc; m = mnew;

        float p = __expf(lg - m), ds = p;
        for (int mm = 32; mm >= 1; mm >>= 1)
            ds += __shfl_xor(ds, mm, 64);
        den += ds;

        ss[wid][lane] = src_l;
        sp[wid][lane] = p;

        int nu = hi - e0; if (nu > 64) nu = 64;
        int u = 0;
#pragma unroll 1
        for (; u + 8 <= nu; u += 8) {
            int su[8];
#pragma unroll
            for (int t = 0; t < 8; ++t)
                su[t] = __builtin_amdgcn_readfirstlane(ss[wid][u + t]);
            float hv[8];
#pragma unroll
            for (int t = 0; t < 8; ++t)
                hv[t] = __half2float(h[(size_t)su[t] * 128 + hd * 64 + lane]);
#pragma unroll
            for (int t = 0; t < 8; ++t)
                acc += sp[wid][u + t] * hv[t];
        }
#pragma unroll 1
        for (; u < nu; ++u) {
            int su = __builtin_amdgcn_readfirstlane(ss[wid][u]);
            acc += sp[wid][u] * __half2float(h[(size_t)su * 128 + hd * 64 + lane]);
        }
    }

    float v = acc / den + bias[hd * 64 + lane];
    out[(size_t)n * 128 + hd * 64 + lane] = fmaxf(v, 0.0f);
}

// ---------------------------------------------------------------------------

extern "C" void kernel_launch(void* const* d_in, const int* in_sizes, int n_in,
                              void* d_out, int out_size, void* d_ws, size_t ws_size,
                              hipStream_t stream) {
    const float* x   = (const float*)d_in[0];
    const int*   ei  = (const int*)  d_in[1];
    const float* w1  = (const float*)d_in[2];
    const float* as1 = (const float*)d_in[3];
    const float* ad1 = (const float*)d_in[4];
    const float* b1  = (const float*)d_in[5];
    const float* w2  = (const float*)d_in[6];
    const float* as2 = (const float*)d_in[7];
    const float* ad2 = (const float*)d_in[8];
    const float* b2  = (const float*)d_in[9];
    const float* w3  = (const float*)d_in[10];
    const float* as3 = (const float*)d_in[11];
    const float* ad3 = (const float*)d_in[12];
    const float* b3  = (const float*)d_in[13];
    const float* fcw = (const float*)d_in[14];
    const float* fcb = (const float*)d_in[15];
    float* out = (float*)d_out;

    const int N = in_sizes[0] / 128;
    const int E = in_sizes[1] / 2;
    const int Etot = E + N;

    // workspace carve-up (256B aligned regions)
    char* p = (char*)d_ws;
    auto alloc = [&](size_t bytes) {
        char* r = p;
        p += (bytes + 255) & ~(size_t)255;
        return r;
    };
    int*    cnt     = (int*)   alloc((size_t)N * 4);
    int*    row_ptr = (int*)   alloc((size_t)(N + 1) * 4);
    int*    rank    = (int*)   alloc((size_t)Etot * 4);
    int*    csr_src = (int*)   alloc((size_t)Etot * 4);
    __half* bufA    = (__half*)alloc((size_t)N * 128 * 4);   // fp16 h (alloc fp32-sized)
    float*  bufB    = (float*) alloc((size_t)N * 128 * 4);   // fp32 agg output
    float*  alpS    = (float*) alloc((size_t)N * 2 * 4);
    float*  alpD    = (float*) alloc((size_t)N * 2 * 4);
    (void)ws_size; (void)n_in; (void)out_size;

    // ---- build CSR by dst (atomics only in pass 1) ----
    hipMemsetAsync(cnt, 0, (size_t)N * 4, stream);
    int eb4 = (Etot / 4 + 255) / 256 + 1;   // 4 edges/thread
    count_rank_kernel<<<eb4, 256, 0, stream>>>(ei, E, N, cnt, rank);
    scan_kernel<<<1, 1024, 0, stream>>>(cnt, N, Etot, row_ptr);
    scatter_kernel<<<eb4, 256, 0, stream>>>(ei, E, N, row_ptr, rank, csr_src);

    int gb  = (N + 3) / 4;        // aggregate (PL1): 4 waves/block, 1 node/wave
    int gb2 = (2 * N + 3) / 4;    // aggregate2: 2 waves/node
    const int GB = 1024;          // gemm persistent blocks: 4/CU

    // ---- layer 1: 128 -> H2 x C32, concat ----
    gemm_kernel<128, 64, 8, 1, __half><<<dim3(GB, 1), 256, 0, stream>>>(
        x, w1, nullptr, bufA, as1, ad1, alpS, alpD, N, 64, 0);
    aggregate_kernel<2, 32><<<gb, 256, 0, stream>>>(bufA, alpS, alpD, row_ptr, csr_src, b1, bufB, N);

    // ---- layer 2: 64 -> H2 x C64, concat (head-split aggregate) ----
    gemm_kernel<64, 128, 8, 2, __half><<<dim3(GB, 1), 256, 0, stream>>>(
        bufB, w2, nullptr, bufA, as2, ad2, alpS, alpD, N, 128, 0);
    aggregate2_kernel<<<gb2, 256, 0, stream>>>(bufA, alpS, alpD, row_ptr, csr_src, b2, bufB, N);

    // ---- layer 3: 128 -> H1 x C64, mean (=identity for 1 head) ----
    gemm_kernel<128, 64, 8, 3, __half><<<dim3(GB, 1), 256, 0, stream>>>(
        bufB, w3, nullptr, bufA, as3, ad3, alpS, alpD, N, 64, 0);
    aggregate_kernel<1, 64><<<gb, 256, 0, stream>>>(bufA, alpS, alpD, row_ptr, csr_src, b3, bufB, N);

    // ---- FC: 64 -> 512 + relu (fp32 path, unchanged) ----
    gemm_kernel<64, 128, 8, 0, float><<<dim3(GB / 4, 4), 256, 0, stream>>>(
        bufB, fcw, fcb, out, nullptr, nullptr, nullptr, nullptr, N, 512, 1);
}

// Round 10
// 786.550 us; speedup vs baseline: 1.1211x; 1.0045x over previous
//
#include <hip/hip_runtime.h>
#include <hip/hip_fp16.h>
#include <math.h>

// ---------------------------------------------------------------------------
// GAT pipeline: 3x (GEMM+alpha fused -> CSR segment-softmax aggregate) + FC
// R17: fp16 FC via v_dot2_f32_f16. R16 proved (a) fp16 halving of gather
//      bytes works (-61us) and (b) absmax is NOT dominated by our h
//      quantization (unchanged at 2^-10) -> precision headroom. FC was
//      re-established as top dispatch (132us, VALU-issue/latency mixed,
//      register budget saturated per R8/R11/R13). New lever: halve work
//      per element -- x (agg3 out) and fcw in fp16, inner product via
//      fdot2 (fp32 accumulate): VALU issue, x bytes, W LDS, LDS read
//      width all halve. Layers 1-3 untouched (proven R16 config).
//      Tripwire: absmax blowup -> revert fp16 FC.
// ---------------------------------------------------------------------------

typedef _Float16 h2_t __attribute__((ext_vector_type(2)));

__device__ __forceinline__ h2_t as_h2(unsigned int u) {
    union { unsigned int u; h2_t h; } x; x.u = u; return x.h;
}

__device__ __forceinline__ float fdot2(h2_t a, h2_t b, float c) {
#if __has_builtin(__builtin_amdgcn_fdot2)
    return __builtin_amdgcn_fdot2(a, b, c, false);
#else
    return c + (float)a[0] * (float)b[0] + (float)a[1] * (float)b[1];
#endif
}

// fcw fp32 -> fp16 (64KB, off critical path, launched first)
__global__ void cvt_kernel(const float* __restrict__ w, __half* __restrict__ wh, int n) {
    int i = blockIdx.x * blockDim.x + threadIdx.x;
    if (i < n) wh[i] = (__half)w[i];
}

// pass 1: cnt[dst]++ (atomic), remember each edge's arrival rank.
__global__ void count_rank_kernel(const int* __restrict__ ei, int E, int N,
                                  int* __restrict__ cnt, int* __restrict__ rank) {
    const int Etot = E + N;
    const int T = gridDim.x * blockDim.x;
    int e = blockIdx.x * blockDim.x + threadIdx.x;
#pragma unroll 4
    for (int u = 0; u < 4; ++u, e += T) {
        if (e < Etot) {
            int dst = (e < E) ? ei[E + e] : (e - E);   // self-loops appended
            rank[e] = atomicAdd(&cnt[dst], 1);
        }
    }
}

__global__ __launch_bounds__(1024) void scan_kernel(const int* __restrict__ cnt,
                                                    int N, int Etot,
                                                    int* __restrict__ row_ptr) {
    __shared__ int sums[1024];
    int tid = threadIdx.x;
    int chunk = (N + 1023) >> 10;
    int lo = tid * chunk;
    int hi = lo + chunk; if (hi > N) hi = N; if (lo > N) lo = N;
    int s = 0;
    for (int i = lo; i < hi; ++i) s += cnt[i];
    sums[tid] = s;
    __syncthreads();
    for (int off = 1; off < 1024; off <<= 1) {
        int t = (tid >= off) ? sums[tid - off] : 0;
        __syncthreads();
        sums[tid] += t;
        __syncthreads();
    }
    int run = sums[tid] - s;   // exclusive base for this thread's chunk
    for (int i = lo; i < hi; ++i) {
        row_ptr[i] = run;
        run += cnt[i];
    }
    if (tid == 0) row_ptr[N] = Etot;
}

// pass 3: pos = row_ptr[dst] + rank[e]; atomic-free scattered store.
__global__ void scatter_kernel(const int* __restrict__ ei, int E, int N,
                               const int* __restrict__ row_ptr,
                               const int* __restrict__ rank,
                               int* __restrict__ csr_src) {
    const int Etot = E + N;
    const int T = gridDim.x * blockDim.x;
    int e = blockIdx.x * blockDim.x + threadIdx.x;
#pragma unroll 4
    for (int u = 0; u < 4; ++u, e += T) {
        if (e < Etot) {
            int src, dst;
            if (e < E) { src = ei[e]; dst = ei[E + e]; }
            else       { src = e - E; dst = e - E; }
            csr_src[row_ptr[dst] + rank[e]] = src;
        }
    }
}

// ---------------------------------------------------------------------------
// GEMM (R10-proven loop): fp32 in, OT out (fp16 h buffers). 256-thread
// blocks (4 waves), W chunk in LDS, RB=8 rows/wave, distance-1 ping-pong,
// partial unroll 2. alpha from fp32 acc BEFORE conversion.
// ALPHA: 0=none  1=(H2,C32: segmented 32-lane)  2=(H2,C64,PL2)  3=(H1,C64)
// ---------------------------------------------------------------------------
template <int K, int CHUNK, int RB, int ALPHA, typename OT>
__global__ __launch_bounds__(256) void gemm_kernel(
        const float* __restrict__ in,
        const float* __restrict__ W,
        const float* __restrict__ bias,
        OT* __restrict__ out,
        const float* __restrict__ a_src,
        const float* __restrict__ a_dst,
        float* __restrict__ alpS,
        float* __restrict__ alpD,
        int N, int M, int relu) {
    constexpr int PL = CHUNK / 64;
    constexpr int K4 = K / 4;
    __shared__ float wlds[K * CHUNK];
    const int cb = blockIdx.y * CHUNK;
    for (int idx = threadIdx.x; idx < K4 * CHUNK; idx += 256) {
        int k4 = idx / CHUNK, c = idx % CHUNK;
        const float* wp = W + (size_t)(4 * k4) * M + cb + c;
        float4 v;
        v.x = wp[0];
        v.y = wp[(size_t)M];
        v.z = wp[(size_t)2 * M];
        v.w = wp[(size_t)3 * M];
        ((float4*)wlds)[idx] = v;
    }
    __syncthreads();

    const int wid  = threadIdx.x >> 6;
    const int lane = threadIdx.x & 63;
    const float4* wlds4 = (const float4*)wlds;

    float b[PL], aSv[PL], aDv[PL];
#pragma unroll
    for (int j = 0; j < PL; ++j) {
        b[j] = bias ? bias[cb + lane + 64 * j] : 0.0f;
        if (ALPHA) { aSv[j] = a_src[lane + 64 * j]; aDv[j] = a_dst[lane + 64 * j]; }
    }

    const int groups = (N + RB - 1) / RB;
    for (int g = blockIdx.x * 4 + wid; g < groups; g += gridDim.x * 4) {
        const int n0 = g * RB;
        const bool full = (n0 + RB <= N);

        float acc[RB][PL];
#pragma unroll
        for (int r = 0; r < RB; ++r)
#pragma unroll
            for (int j = 0; j < PL; ++j) acc[r][j] = 0.0f;

        const float4* xp = (const float4*)(in + (size_t)n0 * K);

        if (full) {
            float4 xv[RB], xn[RB];
#pragma unroll
            for (int r = 0; r < RB; ++r) xv[r] = xp[r * K4];
#pragma unroll 2
            for (int k4 = 0; k4 < K4; ++k4) {
                if (k4 + 1 < K4) {
#pragma unroll
                    for (int r = 0; r < RB; ++r)
                        xn[r] = xp[r * K4 + k4 + 1];
                }
#pragma unroll
                for (int j = 0; j < PL; ++j) {
                    float4 wv = wlds4[k4 * CHUNK + lane + 64 * j];
#pragma unroll
                    for (int r = 0; r < RB; ++r) {
                        acc[r][j] += xv[r].x * wv.x;
                        acc[r][j] += xv[r].y * wv.y;
                        acc[r][j] += xv[r].z * wv.z;
                        acc[r][j] += xv[r].w * wv.w;
                    }
                }
                if (k4 + 1 < K4) {
#pragma unroll
                    for (int r = 0; r < RB; ++r) xv[r] = xn[r];
                }
            }
        } else {
#pragma unroll 1
            for (int k4 = 0; k4 < K4; ++k4) {
#pragma unroll 1
                for (int r = 0; r < RB; ++r) {
                    if (n0 + r >= N) break;
                    float4 xr = xp[(size_t)r * K4 + k4];
#pragma unroll
                    for (int j = 0; j < PL; ++j) {
                        float4 wv = wlds4[k4 * CHUNK + lane + 64 * j];
                        acc[r][j] += xr.x * wv.x;
                        acc[r][j] += xr.y * wv.y;
                        acc[r][j] += xr.z * wv.z;
                        acc[r][j] += xr.w * wv.w;
                    }
                }
            }
        }

#pragma unroll
        for (int r = 0; r < RB; ++r) {
            if (!full && n0 + r >= N) break;
            const int n = n0 + r;
            float v[PL];
#pragma unroll
            for (int j = 0; j < PL; ++j) {
                v[j] = acc[r][j] + b[j];
                if (relu) v[j] = fmaxf(v[j], 0.0f);
                out[(size_t)n * M + cb + lane + 64 * j] = (OT)v[j];
            }
            if (ALPHA) {
                float ps[PL], pd[PL];
#pragma unroll
                for (int j = 0; j < PL; ++j) { ps[j] = v[j] * aSv[j]; pd[j] = v[j] * aDv[j]; }
                const int m0 = (ALPHA == 1) ? 16 : 32;
                for (int mm = m0; mm >= 1; mm >>= 1) {
#pragma unroll
                    for (int j = 0; j < PL; ++j) {
                        ps[j] += __shfl_xor(ps[j], mm, 64);
                        pd[j] += __shfl_xor(pd[j], mm, 64);
                    }
                }
                if (ALPHA == 1) {
                    if ((lane & 31) == 0) {
                        int idx = n * 2 + (lane >> 5);
                        alpS[idx] = ps[0]; alpD[idx] = pd[0];
                    }
                } else if (ALPHA == 2) {
                    if (lane == 0) {
#pragma unroll
                        for (int j = 0; j < PL; ++j) {
                            alpS[n * 2 + j] = ps[j]; alpD[n * 2 + j] = pd[j];
                        }
                    }
                } else {
                    if (lane == 0) { alpS[n] = ps[0]; alpD[n] = pd[0]; }
                }
            }
        }
    }
}

// ---------------------------------------------------------------------------
// FC GEMM, fp16 inputs / fp32 accumulate via fdot2. Same proven loop shape:
// 256 thr, 4 waves, RB=8, ping-pong, unroll 2. W tile (64x128 fp16 = 16KB
// LDS) packed as uint2 (4 halves per k4); x loads 8B/lane.
// Per iter: 32 fdot2 (vs 64 FMA) -- issue, LDS width, x bytes all halved.
// ---------------------------------------------------------------------------
template <int RB>
__global__ __launch_bounds__(256) void fc16_kernel(
        const __half* __restrict__ in,    // [N][64] fp16
        const __half* __restrict__ Wh,    // [64][512] fp16
        const float* __restrict__ bias,   // [512]
        float* __restrict__ out,          // [N][512]
        int N) {
    constexpr int K4 = 16, CHUNK = 128, M = 512;
    __shared__ uint2 wlds[K4 * CHUNK];    // 16 KB
    const int cb = blockIdx.y * CHUNK;
    const unsigned short* wsrc = (const unsigned short*)Wh;
    for (int idx = threadIdx.x; idx < K4 * CHUNK; idx += 256) {
        int k4 = idx / CHUNK, c = idx % CHUNK;
        const unsigned short* wp = wsrc + (size_t)(4 * k4) * M + cb + c;
        uint2 v;
        v.x = (unsigned int)wp[0]     | ((unsigned int)wp[M] << 16);
        v.y = (unsigned int)wp[2 * M] | ((unsigned int)wp[3 * M] << 16);
        wlds[idx] = v;
    }
    __syncthreads();

    const int wid  = threadIdx.x >> 6;
    const int lane = threadIdx.x & 63;
    const float b0 = bias[cb + lane];
    const float b1 = bias[cb + lane + 64];

    const int groups = (N + RB - 1) / RB;
    for (int g = blockIdx.x * 4 + wid; g < groups; g += gridDim.x * 4) {
        const int n0 = g * RB;
        const bool full = (n0 + RB <= N);

        float acc[RB][2];
#pragma unroll
        for (int r = 0; r < RB; ++r) { acc[r][0] = 0.0f; acc[r][1] = 0.0f; }

        const uint2* xp = (const uint2*)(in + (size_t)n0 * 64);

        if (full) {
            uint2 xv[RB], xn[RB];
#pragma unroll
            for (int r = 0; r < RB; ++r) xv[r] = xp[r * K4];
#pragma unroll 2
            for (int k4 = 0; k4 < K4; ++k4) {
                if (k4 + 1 < K4) {
#pragma unroll
                    for (int r = 0; r < RB; ++r)
                        xn[r] = xp[r * K4 + k4 + 1];
                }
#pragma unroll
                for (int j = 0; j < 2; ++j) {
                    uint2 wv = wlds[k4 * CHUNK + lane + 64 * j];
#pragma unroll
                    for (int r = 0; r < RB; ++r) {
                        acc[r][j] = fdot2(as_h2(xv[r].x), as_h2(wv.x), acc[r][j]);
                        acc[r][j] = fdot2(as_h2(xv[r].y), as_h2(wv.y), acc[r][j]);
                    }
                }
                if (k4 + 1 < K4) {
#pragma unroll
                    for (int r = 0; r < RB; ++r) xv[r] = xn[r];
                }
            }
        } else {
#pragma unroll 1
            for (int k4 = 0; k4 < K4; ++k4) {
#pragma unroll 1
                for (int r = 0; r < RB; ++r) {
                    if (n0 + r >= N) break;
                    uint2 xr = xp[(size_t)r * K4 + k4];
#pragma unroll
                    for (int j = 0; j < 2; ++j) {
                        uint2 wv = wlds[k4 * CHUNK + lane + 64 * j];
                        acc[r][j] = fdot2(as_h2(xr.x), as_h2(wv.x), acc[r][j]);
                        acc[r][j] = fdot2(as_h2(xr.y), as_h2(wv.y), acc[r][j]);
                    }
                }
            }
        }

#pragma unroll
        for (int r = 0; r < RB; ++r) {
            if (!full && n0 + r >= N) break;
            const int n = n0 + r;
            out[(size_t)n * M + cb + lane]      = fmaxf(acc[r][0] + b0, 0.0f);
            out[(size_t)n * M + cb + lane + 64] = fmaxf(acc[r][1] + b1, 0.0f);
        }
    }
}

// ---------------------------------------------------------------------------
// Aggregate (PL1 variants, layers 1+3): one wave per dst node, 64-edge
// chunks, two-phase; h gathered as FP16; softmax/accumulate fp32; OT out
// (float for layer 1, fp16 for layer 3 -> FC input).
// ---------------------------------------------------------------------------
template <int H, int C, typename OT>
__global__ __launch_bounds__(256) void aggregate_kernel(
        const __half* __restrict__ h,
        const float* __restrict__ alpha_s,
        const float* __restrict__ alpha_d,
        const int* __restrict__ row_ptr,
        const int* __restrict__ csr_src,
        const float* __restrict__ bias,
        OT* __restrict__ out, int N) {
    constexpr int M = H * C;
    __shared__ int   ss[4][64];
    __shared__ float sp[4][128];
    const int wid  = threadIdx.x >> 6;
    const int lane = threadIdx.x & 63;
    const int n = blockIdx.x * 4 + wid;
    if (n >= N) return;

    const int lo = row_ptr[n], hi = row_ptr[n + 1];
    const int myhead = (H == 2) ? (lane / C) : 0;

    float adv[H];
#pragma unroll
    for (int t = 0; t < H; ++t) adv[t] = alpha_d[n * H + t];

    float m[H], den[H], acc = 0.0f;
#pragma unroll
    for (int t = 0; t < H; ++t) { m[t] = -INFINITY; den[t] = 0.0f; }

    for (int e0 = lo; e0 < hi; e0 += 64) {
        const int idx = e0 + lane;
        const bool valid = idx < hi;
        const int src_l = csr_src[valid ? idx : hi - 1];

        // ---- phase A: lane-parallel logits ----
        float lg[H];
        if (H == 2) {
            float2 as = ((const float2*)alpha_s)[src_l];
            lg[0] = as.x + adv[0];
            lg[1] = as.y + adv[1];
        } else {
            lg[0] = alpha_s[src_l] + adv[0];
        }
#pragma unroll
        for (int t = 0; t < H; ++t) {
            float v = lg[t];
            v = v > 0.0f ? v : 0.2f * v;
            lg[t] = valid ? v : -INFINITY;
        }
        float cm[H];
#pragma unroll
        for (int t = 0; t < H; ++t) cm[t] = lg[t];
        for (int mm = 32; mm >= 1; mm >>= 1) {
#pragma unroll
            for (int t = 0; t < H; ++t)
                cm[t] = fmaxf(cm[t], __shfl_xor(cm[t], mm, 64));
        }
        float sc[H];
#pragma unroll
        for (int t = 0; t < H; ++t) {
            float mnew = fmaxf(m[t], cm[t]);
            sc[t] = __expf(m[t] - mnew);
            den[t] *= sc[t];
            m[t] = mnew;
        }
        acc *= (H == 1) ? sc[0] : (myhead == 0 ? sc[0] : sc[1]);

        float p[H], dsum[H];
#pragma unroll
        for (int t = 0; t < H; ++t) { p[t] = __expf(lg[t] - m[t]); dsum[t] = p[t]; }
        for (int mm = 32; mm >= 1; mm >>= 1) {
#pragma unroll
            for (int t = 0; t < H; ++t)
                dsum[t] += __shfl_xor(dsum[t], mm, 64);
        }
#pragma unroll
        for (int t = 0; t < H; ++t) den[t] += dsum[t];

        ss[wid][lane] = src_l;
        if (H == 2) ((float2*)sp[wid])[lane] = make_float2(p[0], p[1]);
        else        sp[wid][lane] = p[0];

        // ---- phase B: per-edge broadcast accumulate, 8-wide batch ----
        int nu = hi - e0; if (nu > 64) nu = 64;
        int u = 0;
#pragma unroll 1
        for (; u + 8 <= nu; u += 8) {
            int su[8];
#pragma unroll
            for (int t = 0; t < 8; ++t)
                su[t] = __builtin_amdgcn_readfirstlane(ss[wid][u + t]);
            float hv[8];
#pragma unroll
            for (int t = 0; t < 8; ++t)
                hv[t] = __half2float(h[(size_t)su[t] * M + lane]);
            if (H == 2) {
                const float2* pb = (const float2*)sp[wid];
#pragma unroll
                for (int t = 0; t < 8; ++t) {
                    float2 q = pb[u + t];
                    acc += (myhead == 0 ? q.x : q.y) * hv[t];
                }
            } else {
#pragma unroll
                for (int t = 0; t < 8; ++t)
                    acc += sp[wid][u + t] * hv[t];
            }
        }
#pragma unroll 1
        for (; u < nu; ++u) {
            int su = __builtin_amdgcn_readfirstlane(ss[wid][u]);
            float hv = __half2float(h[(size_t)su * M + lane]);
            if (H == 2) {
                float2 q = ((const float2*)sp[wid])[u];
                acc += (myhead == 0 ? q.x : q.y) * hv;
            } else {
                acc += sp[wid][u] * hv;
            }
        }
    }

    float dv = (H == 1) ? den[0] : (myhead == 0 ? den[0] : den[1]);
    float v = acc / dv + bias[lane];
    out[(size_t)n * M + lane] = (OT)fmaxf(v, 0.0f);
}

// ---------------------------------------------------------------------------
// Layer-2 aggregate, HEAD-SPLIT: 2 waves per node; h gathered as FP16.
// ---------------------------------------------------------------------------
__global__ __launch_bounds__(256) void aggregate2_kernel(
        const __half* __restrict__ h,       // [N][128] fp16
        const float* __restrict__ alpha_s,  // [N][2]
        const float* __restrict__ alpha_d,  // [N][2]
        const int* __restrict__ row_ptr,
        const int* __restrict__ csr_src,
        const float* __restrict__ bias,     // [128]
        float* __restrict__ out, int N) {
    __shared__ int   ss[4][64];
    __shared__ float sp[4][64];
    const int wid  = threadIdx.x >> 6;
    const int lane = threadIdx.x & 63;
    const int gw   = blockIdx.x * 4 + wid;
    const int n    = gw >> 1;
    const int hd   = gw & 1;
    if (n >= N) return;

    const int lo = row_ptr[n], hi = row_ptr[n + 1];
    const float adv = alpha_d[n * 2 + hd];

    float m = -INFINITY, den = 0.0f, acc = 0.0f;

    for (int e0 = lo; e0 < hi; e0 += 64) {
        const int idx = e0 + lane;
        const bool valid = idx < hi;
        const int src_l = csr_src[valid ? idx : hi - 1];

        float lg = alpha_s[src_l * 2 + hd] + adv;
        lg = lg > 0.0f ? lg : 0.2f * lg;
        if (!valid) lg = -INFINITY;

        float cm = lg;
        for (int mm = 32; mm >= 1; mm >>= 1)
            cm = fmaxf(cm, __shfl_xor(cm, mm, 64));

        float mnew = fmaxf(m, cm);
        float sc = __expf(m - mnew);
        den *= sc; acc *= sc; m = mnew;

        float p = __expf(lg - m), ds = p;
        for (int mm = 32; mm >= 1; mm >>= 1)
            ds += __shfl_xor(ds, mm, 64);
        den += ds;

        ss[wid][lane] = src_l;
        sp[wid][lane] = p;

        int nu = hi - e0; if (nu > 64) nu = 64;
        int u = 0;
#pragma unroll 1
        for (; u + 8 <= nu; u += 8) {
            int su[8];
#pragma unroll
            for (int t = 0; t < 8; ++t)
                su[t] = __builtin_amdgcn_readfirstlane(ss[wid][u + t]);
            float hv[8];
#pragma unroll
            for (int t = 0; t < 8; ++t)
                hv[t] = __half2float(h[(size_t)su[t] * 128 + hd * 64 + lane]);
#pragma unroll
            for (int t = 0; t < 8; ++t)
                acc += sp[wid][u + t] * hv[t];
        }
#pragma unroll 1
        for (; u < nu; ++u) {
            int su = __builtin_amdgcn_readfirstlane(ss[wid][u]);
            acc += sp[wid][u] * __half2float(h[(size_t)su * 128 + hd * 64 + lane]);
        }
    }

    float v = acc / den + bias[hd * 64 + lane];
    out[(size_t)n * 128 + hd * 64 + lane] = fmaxf(v, 0.0f);
}

// ---------------------------------------------------------------------------

extern "C" void kernel_launch(void* const* d_in, const int* in_sizes, int n_in,
                              void* d_out, int out_size, void* d_ws, size_t ws_size,
                              hipStream_t stream) {
    const float* x   = (const float*)d_in[0];
    const int*   ei  = (const int*)  d_in[1];
    const float* w1  = (const float*)d_in[2];
    const float* as1 = (const float*)d_in[3];
    const float* ad1 = (const float*)d_in[4];
    const float* b1  = (const float*)d_in[5];
    const float* w2  = (const float*)d_in[6];
    const float* as2 = (const float*)d_in[7];
    const float* ad2 = (const float*)d_in[8];
    const float* b2  = (const float*)d_in[9];
    const float* w3  = (const float*)d_in[10];
    const float* as3 = (const float*)d_in[11];
    const float* ad3 = (const float*)d_in[12];
    const float* b3  = (const float*)d_in[13];
    const float* fcw = (const float*)d_in[14];
    const float* fcb = (const float*)d_in[15];
    float* out = (float*)d_out;

    const int N = in_sizes[0] / 128;
    const int E = in_sizes[1] / 2;
    const int Etot = E + N;

    // workspace carve-up (256B aligned regions)
    char* p = (char*)d_ws;
    auto alloc = [&](size_t bytes) {
        char* r = p;
        p += (bytes + 255) & ~(size_t)255;
        return r;
    };
    int*    cnt     = (int*)   alloc((size_t)N * 4);
    int*    row_ptr = (int*)   alloc((size_t)(N + 1) * 4);
    int*    rank    = (int*)   alloc((size_t)Etot * 4);
    int*    csr_src = (int*)   alloc((size_t)Etot * 4);
    __half* bufA    = (__half*)alloc((size_t)N * 128 * 2);   // fp16 h
    float*  bufB    = (float*) alloc((size_t)N * 128 * 4);   // fp32 agg out (l1,l2)
    __half* bufC    = (__half*)alloc((size_t)N * 64 * 2);    // fp16 agg3 out (FC in)
    __half* fcwh    = (__half*)alloc((size_t)64 * 512 * 2);  // fp16 fcw
    float*  alpS    = (float*) alloc((size_t)N * 2 * 4);
    float*  alpD    = (float*) alloc((size_t)N * 2 * 4);
    (void)ws_size; (void)n_in; (void)out_size;

    // fcw -> fp16 (independent, off critical path)
    cvt_kernel<<<128, 256, 0, stream>>>(fcw, fcwh, 64 * 512);

    // ---- build CSR by dst (atomics only in pass 1) ----
    hipMemsetAsync(cnt, 0, (size_t)N * 4, stream);
    int eb4 = (Etot / 4 + 255) / 256 + 1;   // 4 edges/thread
    count_rank_kernel<<<eb4, 256, 0, stream>>>(ei, E, N, cnt, rank);
    scan_kernel<<<1, 1024, 0, stream>>>(cnt, N, Etot, row_ptr);
    scatter_kernel<<<eb4, 256, 0, stream>>>(ei, E, N, row_ptr, rank, csr_src);

    int gb  = (N + 3) / 4;        // aggregate (PL1): 4 waves/block, 1 node/wave
    int gb2 = (2 * N + 3) / 4;    // aggregate2: 2 waves/node
    const int GB = 1024;          // gemm persistent blocks: 4/CU

    // ---- layer 1: 128 -> H2 x C32, concat ----
    gemm_kernel<128, 64, 8, 1, __half><<<dim3(GB, 1), 256, 0, stream>>>(
        x, w1, nullptr, bufA, as1, ad1, alpS, alpD, N, 64, 0);
    aggregate_kernel<2, 32, float><<<gb, 256, 0, stream>>>(bufA, alpS, alpD, row_ptr, csr_src, b1, bufB, N);

    // ---- layer 2: 64 -> H2 x C64, concat (head-split aggregate) ----
    gemm_kernel<64, 128, 8, 2, __half><<<dim3(GB, 1), 256, 0, stream>>>(
        bufB, w2, nullptr, bufA, as2, ad2, alpS, alpD, N, 128, 0);
    aggregate2_kernel<<<gb2, 256, 0, stream>>>(bufA, alpS, alpD, row_ptr, csr_src, b2, bufB, N);

    // ---- layer 3: 128 -> H1 x C64, mean; output fp16 for FC ----
    gemm_kernel<128, 64, 8, 3, __half><<<dim3(GB, 1), 256, 0, stream>>>(
        bufB, w3, nullptr, bufA, as3, ad3, alpS, alpD, N, 64, 0);
    aggregate_kernel<1, 64, __half><<<gb, 256, 0, stream>>>(bufA, alpS, alpD, row_ptr, csr_src, b3, bufC, N);

    // ---- FC: 64 -> 512 + relu, fp16 inputs via fdot2 ----
    fc16_kernel<8><<<dim3(GB / 4, 4), 256, 0, stream>>>(
        bufC, fcwh, fcb, out, N);
}

// Round 11
// 759.023 us; speedup vs baseline: 1.1617x; 1.0363x over previous
//
#include <hip/hip_runtime.h>
#include <hip/hip_fp16.h>
#include <math.h>

// ---------------------------------------------------------------------------
// GAT pipeline: 3x (GEMM16+alpha fused -> CSR segment-softmax aggregate) + FC
// R18: occupancy harvest. R17's fp16 FC dropped VGPR to 52 / LDS to 16KB but
//      grid stayed 1024 = 4 blocks/CU -> still latency-bound at 32% occ.
//      (1) fc16 grid -> (512,4) = 2048 blocks = 8/CU = 8 waves/SIMD.
//      (2) layer GEMMs ported to the same fdot2 pattern (gemm16_kernel):
//          fp16 x/W, fp32 acc, alpha from fp32 acc, fp16 h out. VGPR ~55,
//          LDS 16KB, grid 2048, <=1 group/wave.
//      (3) aggregates write fp16 (all h/x intermediates now fp16).
//      (4) cvt kernels: weights (off-path) + x (one 6us pass).
//      absmax frozen at 2^-10 through R16/R17 fp16 changes -> headroom.
// ---------------------------------------------------------------------------

typedef _Float16 h2_t __attribute__((ext_vector_type(2)));

__device__ __forceinline__ h2_t as_h2(unsigned int u) {
    union { unsigned int u; h2_t h; } x; x.u = u; return x.h;
}

__device__ __forceinline__ float fdot2(h2_t a, h2_t b, float c) {
#if __has_builtin(__builtin_amdgcn_fdot2)
    return __builtin_amdgcn_fdot2(a, b, c, false);
#else
    return c + (float)a[0] * (float)b[0] + (float)a[1] * (float)b[1];
#endif
}

// all 4 weight matrices fp32 -> fp16 (57344 elems total, off critical path)
__global__ void cvtw_kernel(const float* __restrict__ w1, const float* __restrict__ w2,
                            const float* __restrict__ w3, const float* __restrict__ fcw,
                            __half* __restrict__ o1, __half* __restrict__ o2,
                            __half* __restrict__ o3, __half* __restrict__ o4) {
    int i = blockIdx.x * blockDim.x + threadIdx.x;
    if (i < 8192)       o1[i]         = (__half)w1[i];
    else if (i < 16384) o2[i - 8192]  = (__half)w2[i - 8192];
    else if (i < 24576) o3[i - 16384] = (__half)w3[i - 16384];
    else if (i < 57344) o4[i - 24576] = (__half)fcw[i - 24576];
}

// x fp32 -> fp16, vectorized (float4 -> 4 halves)
__global__ void cvtx_kernel(const float* __restrict__ x, __half* __restrict__ xh, int n4) {
    int i = blockIdx.x * blockDim.x + threadIdx.x;
    if (i < n4) {
        float4 v = ((const float4*)x)[i];
        __half2 a, b;
        a.x = (__half)v.x; a.y = (__half)v.y;
        b.x = (__half)v.z; b.y = (__half)v.w;
        ((__half2*)xh)[2 * i]     = a;
        ((__half2*)xh)[2 * i + 1] = b;
    }
}

// pass 1: cnt[dst]++ (atomic), remember each edge's arrival rank.
__global__ void count_rank_kernel(const int* __restrict__ ei, int E, int N,
                                  int* __restrict__ cnt, int* __restrict__ rank) {
    const int Etot = E + N;
    const int T = gridDim.x * blockDim.x;
    int e = blockIdx.x * blockDim.x + threadIdx.x;
#pragma unroll 4
    for (int u = 0; u < 4; ++u, e += T) {
        if (e < Etot) {
            int dst = (e < E) ? ei[E + e] : (e - E);   // self-loops appended
            rank[e] = atomicAdd(&cnt[dst], 1);
        }
    }
}

__global__ __launch_bounds__(1024) void scan_kernel(const int* __restrict__ cnt,
                                                    int N, int Etot,
                                                    int* __restrict__ row_ptr) {
    __shared__ int sums[1024];
    int tid = threadIdx.x;
    int chunk = (N + 1023) >> 10;
    int lo = tid * chunk;
    int hi = lo + chunk; if (hi > N) hi = N; if (lo > N) lo = N;
    int s = 0;
    for (int i = lo; i < hi; ++i) s += cnt[i];
    sums[tid] = s;
    __syncthreads();
    for (int off = 1; off < 1024; off <<= 1) {
        int t = (tid >= off) ? sums[tid - off] : 0;
        __syncthreads();
        sums[tid] += t;
        __syncthreads();
    }
    int run = sums[tid] - s;   // exclusive base for this thread's chunk
    for (int i = lo; i < hi; ++i) {
        row_ptr[i] = run;
        run += cnt[i];
    }
    if (tid == 0) row_ptr[N] = Etot;
}

// pass 3: pos = row_ptr[dst] + rank[e]; atomic-free scattered store.
__global__ void scatter_kernel(const int* __restrict__ ei, int E, int N,
                               const int* __restrict__ row_ptr,
                               const int* __restrict__ rank,
                               int* __restrict__ csr_src) {
    const int Etot = E + N;
    const int T = gridDim.x * blockDim.x;
    int e = blockIdx.x * blockDim.x + threadIdx.x;
#pragma unroll 4
    for (int u = 0; u < 4; ++u, e += T) {
        if (e < Etot) {
            int src, dst;
            if (e < E) { src = ei[e]; dst = ei[E + e]; }
            else       { src = e - E; dst = e - E; }
            csr_src[row_ptr[dst] + rank[e]] = src;
        }
    }
}

// ---------------------------------------------------------------------------
// Layer GEMM, fp16 in/W, fp32 acc via fdot2, fp16 out, fused alpha from the
// fp32 acc. Proven fc16 loop shape: 256 thr / 4 waves, W tile 16KB LDS
// (uint2-packed: 4 consecutive-k halves per entry), RB=8 rows/wave,
// distance-1 ping-pong, unroll 2. VGPR ~55 -> 8 waves/SIMD; grid 2048
// blocks -> <=1 group/wave, 8 blocks/CU.
// ALPHA: 1=(H2,C32: segmented 32-lane)  2=(H2,C64,PL2)  3=(H1,C64)
// ---------------------------------------------------------------------------
template <int K, int CHUNK, int RB, int ALPHA>
__global__ __launch_bounds__(256) void gemm16_kernel(
        const __half* __restrict__ in,
        const __half* __restrict__ Wh,
        __half* __restrict__ out,
        const float* __restrict__ a_src,
        const float* __restrict__ a_dst,
        float* __restrict__ alpS,
        float* __restrict__ alpD,
        int N, int M) {
    constexpr int PL = CHUNK / 64;
    constexpr int K4 = K / 4;
    __shared__ uint2 wlds[K4 * CHUNK];   // = K*CHUNK*2 B = 16 KB
    const unsigned short* wsrc = (const unsigned short*)Wh;
    for (int idx = threadIdx.x; idx < K4 * CHUNK; idx += 256) {
        int k4 = idx / CHUNK, c = idx % CHUNK;
        const unsigned short* wp = wsrc + (size_t)(4 * k4) * M + c;
        uint2 v;
        v.x = (unsigned int)wp[0]     | ((unsigned int)wp[M] << 16);
        v.y = (unsigned int)wp[2 * M] | ((unsigned int)wp[3 * M] << 16);
        wlds[idx] = v;
    }
    __syncthreads();

    const int wid  = threadIdx.x >> 6;
    const int lane = threadIdx.x & 63;

    float aSv[PL], aDv[PL];
#pragma unroll
    for (int j = 0; j < PL; ++j) {
        aSv[j] = a_src[lane + 64 * j];
        aDv[j] = a_dst[lane + 64 * j];
    }

    const int groups = (N + RB - 1) / RB;
    for (int g = blockIdx.x * 4 + wid; g < groups; g += gridDim.x * 4) {
        const int n0 = g * RB;
        const bool full = (n0 + RB <= N);

        float acc[RB][PL];
#pragma unroll
        for (int r = 0; r < RB; ++r)
#pragma unroll
            for (int j = 0; j < PL; ++j) acc[r][j] = 0.0f;

        const uint2* xp = (const uint2*)(in + (size_t)n0 * K);

        if (full) {
            uint2 xv[RB], xn[RB];
#pragma unroll
            for (int r = 0; r < RB; ++r) xv[r] = xp[r * K4];
#pragma unroll 2
            for (int k4 = 0; k4 < K4; ++k4) {
                if (k4 + 1 < K4) {
#pragma unroll
                    for (int r = 0; r < RB; ++r)
                        xn[r] = xp[r * K4 + k4 + 1];
                }
#pragma unroll
                for (int j = 0; j < PL; ++j) {
                    uint2 wv = wlds[k4 * CHUNK + lane + 64 * j];
#pragma unroll
                    for (int r = 0; r < RB; ++r) {
                        acc[r][j] = fdot2(as_h2(xv[r].x), as_h2(wv.x), acc[r][j]);
                        acc[r][j] = fdot2(as_h2(xv[r].y), as_h2(wv.y), acc[r][j]);
                    }
                }
                if (k4 + 1 < K4) {
#pragma unroll
                    for (int r = 0; r < RB; ++r) xv[r] = xn[r];
                }
            }
        } else {
#pragma unroll 1
            for (int k4 = 0; k4 < K4; ++k4) {
#pragma unroll 1
                for (int r = 0; r < RB; ++r) {
                    if (n0 + r >= N) break;
                    uint2 xr = xp[(size_t)r * K4 + k4];
#pragma unroll
                    for (int j = 0; j < PL; ++j) {
                        uint2 wv = wlds[k4 * CHUNK + lane + 64 * j];
                        acc[r][j] = fdot2(as_h2(xr.x), as_h2(wv.x), acc[r][j]);
                        acc[r][j] = fdot2(as_h2(xr.y), as_h2(wv.y), acc[r][j]);
                    }
                }
            }
        }

#pragma unroll
        for (int r = 0; r < RB; ++r) {
            if (!full && n0 + r >= N) break;
            const int n = n0 + r;
#pragma unroll
            for (int j = 0; j < PL; ++j)
                out[(size_t)n * M + lane + 64 * j] = (__half)acc[r][j];

            float ps[PL], pd[PL];
#pragma unroll
            for (int j = 0; j < PL; ++j) { ps[j] = acc[r][j] * aSv[j]; pd[j] = acc[r][j] * aDv[j]; }
            const int m0 = (ALPHA == 1) ? 16 : 32;
            for (int mm = m0; mm >= 1; mm >>= 1) {
#pragma unroll
                for (int j = 0; j < PL; ++j) {
                    ps[j] += __shfl_xor(ps[j], mm, 64);
                    pd[j] += __shfl_xor(pd[j], mm, 64);
                }
            }
            if (ALPHA == 1) {
                if ((lane & 31) == 0) {
                    int idx = n * 2 + (lane >> 5);
                    alpS[idx] = ps[0]; alpD[idx] = pd[0];
                }
            } else if (ALPHA == 2) {
                if (lane == 0) {
#pragma unroll
                    for (int j = 0; j < PL; ++j) {
                        alpS[n * 2 + j] = ps[j]; alpD[n * 2 + j] = pd[j];
                    }
                }
            } else {
                if (lane == 0) { alpS[n] = ps[0]; alpD[n] = pd[0]; }
            }
        }
    }
}

// ---------------------------------------------------------------------------
// FC GEMM, fp16 inputs / fp32 accumulate via fdot2 (R17-proven, VGPR 52).
// Grid now 2048 blocks = 8 blocks/CU = 8 waves/SIMD (occupancy harvest).
// ---------------------------------------------------------------------------
template <int RB>
__global__ __launch_bounds__(256) void fc16_kernel(
        const __half* __restrict__ in,    // [N][64] fp16
        const __half* __restrict__ Wh,    // [64][512] fp16
        const float* __restrict__ bias,   // [512]
        float* __restrict__ out,          // [N][512]
        int N) {
    constexpr int K4 = 16, CHUNK = 128, M = 512;
    __shared__ uint2 wlds[K4 * CHUNK];    // 16 KB
    const int cb = blockIdx.y * CHUNK;
    const unsigned short* wsrc = (const unsigned short*)Wh;
    for (int idx = threadIdx.x; idx < K4 * CHUNK; idx += 256) {
        int k4 = idx / CHUNK, c = idx % CHUNK;
        const unsigned short* wp = wsrc + (size_t)(4 * k4) * M + cb + c;
        uint2 v;
        v.x = (unsigned int)wp[0]     | ((unsigned int)wp[M] << 16);
        v.y = (unsigned int)wp[2 * M] | ((unsigned int)wp[3 * M] << 16);
        wlds[idx] = v;
    }
    __syncthreads();

    const int wid  = threadIdx.x >> 6;
    const int lane = threadIdx.x & 63;
    const float b0 = bias[cb + lane];
    const float b1 = bias[cb + lane + 64];

    const int groups = (N + RB - 1) / RB;
    for (int g = blockIdx.x * 4 + wid; g < groups; g += gridDim.x * 4) {
        const int n0 = g * RB;
        const bool full = (n0 + RB <= N);

        float acc[RB][2];
#pragma unroll
        for (int r = 0; r < RB; ++r) { acc[r][0] = 0.0f; acc[r][1] = 0.0f; }

        const uint2* xp = (const uint2*)(in + (size_t)n0 * 64);

        if (full) {
            uint2 xv[RB], xn[RB];
#pragma unroll
            for (int r = 0; r < RB; ++r) xv[r] = xp[r * K4];
#pragma unroll 2
            for (int k4 = 0; k4 < K4; ++k4) {
                if (k4 + 1 < K4) {
#pragma unroll
                    for (int r = 0; r < RB; ++r)
                        xn[r] = xp[r * K4 + k4 + 1];
                }
#pragma unroll
                for (int j = 0; j < 2; ++j) {
                    uint2 wv = wlds[k4 * CHUNK + lane + 64 * j];
#pragma unroll
                    for (int r = 0; r < RB; ++r) {
                        acc[r][j] = fdot2(as_h2(xv[r].x), as_h2(wv.x), acc[r][j]);
                        acc[r][j] = fdot2(as_h2(xv[r].y), as_h2(wv.y), acc[r][j]);
                    }
                }
                if (k4 + 1 < K4) {
#pragma unroll
                    for (int r = 0; r < RB; ++r) xv[r] = xn[r];
                }
            }
        } else {
#pragma unroll 1
            for (int k4 = 0; k4 < K4; ++k4) {
#pragma unroll 1
                for (int r = 0; r < RB; ++r) {
                    if (n0 + r >= N) break;
                    uint2 xr = xp[(size_t)r * K4 + k4];
#pragma unroll
                    for (int j = 0; j < 2; ++j) {
                        uint2 wv = wlds[k4 * CHUNK + lane + 64 * j];
                        acc[r][j] = fdot2(as_h2(xr.x), as_h2(wv.x), acc[r][j]);
                        acc[r][j] = fdot2(as_h2(xr.y), as_h2(wv.y), acc[r][j]);
                    }
                }
            }
        }

#pragma unroll
        for (int r = 0; r < RB; ++r) {
            if (!full && n0 + r >= N) break;
            const int n = n0 + r;
            out[(size_t)n * M + cb + lane]      = fmaxf(acc[r][0] + b0, 0.0f);
            out[(size_t)n * M + cb + lane + 64] = fmaxf(acc[r][1] + b1, 0.0f);
        }
    }
}

// ---------------------------------------------------------------------------
// Aggregate (PL1 variants, layers 1+3): one wave per dst node, 64-edge
// chunks, two-phase; h gathered as FP16; softmax/accumulate fp32; fp16 out.
// ---------------------------------------------------------------------------
template <int H, int C>
__global__ __launch_bounds__(256) void aggregate_kernel(
        const __half* __restrict__ h,
        const float* __restrict__ alpha_s,
        const float* __restrict__ alpha_d,
        const int* __restrict__ row_ptr,
        const int* __restrict__ csr_src,
        const float* __restrict__ bias,
        __half* __restrict__ out, int N) {
    constexpr int M = H * C;
    __shared__ int   ss[4][64];
    __shared__ float sp[4][128];
    const int wid  = threadIdx.x >> 6;
    const int lane = threadIdx.x & 63;
    const int n = blockIdx.x * 4 + wid;
    if (n >= N) return;

    const int lo = row_ptr[n], hi = row_ptr[n + 1];
    const int myhead = (H == 2) ? (lane / C) : 0;

    float adv[H];
#pragma unroll
    for (int t = 0; t < H; ++t) adv[t] = alpha_d[n * H + t];

    float m[H], den[H], acc = 0.0f;
#pragma unroll
    for (int t = 0; t < H; ++t) { m[t] = -INFINITY; den[t] = 0.0f; }

    for (int e0 = lo; e0 < hi; e0 += 64) {
        const int idx = e0 + lane;
        const bool valid = idx < hi;
        const int src_l = csr_src[valid ? idx : hi - 1];

        // ---- phase A: lane-parallel logits ----
        float lg[H];
        if (H == 2) {
            float2 as = ((const float2*)alpha_s)[src_l];
            lg[0] = as.x + adv[0];
            lg[1] = as.y + adv[1];
        } else {
            lg[0] = alpha_s[src_l] + adv[0];
        }
#pragma unroll
        for (int t = 0; t < H; ++t) {
            float v = lg[t];
            v = v > 0.0f ? v : 0.2f * v;
            lg[t] = valid ? v : -INFINITY;
        }
        float cm[H];
#pragma unroll
        for (int t = 0; t < H; ++t) cm[t] = lg[t];
        for (int mm = 32; mm >= 1; mm >>= 1) {
#pragma unroll
            for (int t = 0; t < H; ++t)
                cm[t] = fmaxf(cm[t], __shfl_xor(cm[t], mm, 64));
        }
        float sc[H];
#pragma unroll
        for (int t = 0; t < H; ++t) {
            float mnew = fmaxf(m[t], cm[t]);
            sc[t] = __expf(m[t] - mnew);
            den[t] *= sc[t];
            m[t] = mnew;
        }
        acc *= (H == 1) ? sc[0] : (myhead == 0 ? sc[0] : sc[1]);

        float p[H], dsum[H];
#pragma unroll
        for (int t = 0; t < H; ++t) { p[t] = __expf(lg[t] - m[t]); dsum[t] = p[t]; }
        for (int mm = 32; mm >= 1; mm >>= 1) {
#pragma unroll
            for (int t = 0; t < H; ++t)
                dsum[t] += __shfl_xor(dsum[t], mm, 64);
        }
#pragma unroll
        for (int t = 0; t < H; ++t) den[t] += dsum[t];

        ss[wid][lane] = src_l;
        if (H == 2) ((float2*)sp[wid])[lane] = make_float2(p[0], p[1]);
        else        sp[wid][lane] = p[0];

        // ---- phase B: per-edge broadcast accumulate, 8-wide batch ----
        int nu = hi - e0; if (nu > 64) nu = 64;
        int u = 0;
#pragma unroll 1
        for (; u + 8 <= nu; u += 8) {
            int su[8];
#pragma unroll
            for (int t = 0; t < 8; ++t)
                su[t] = __builtin_amdgcn_readfirstlane(ss[wid][u + t]);
            float hv[8];
#pragma unroll
            for (int t = 0; t < 8; ++t)
                hv[t] = __half2float(h[(size_t)su[t] * M + lane]);
            if (H == 2) {
                const float2* pb = (const float2*)sp[wid];
#pragma unroll
                for (int t = 0; t < 8; ++t) {
                    float2 q = pb[u + t];
                    acc += (myhead == 0 ? q.x : q.y) * hv[t];
                }
            } else {
#pragma unroll
                for (int t = 0; t < 8; ++t)
                    acc += sp[wid][u + t] * hv[t];
            }
        }
#pragma unroll 1
        for (; u < nu; ++u) {
            int su = __builtin_amdgcn_readfirstlane(ss[wid][u]);
            float hv = __half2float(h[(size_t)su * M + lane]);
            if (H == 2) {
                float2 q = ((const float2*)sp[wid])[u];
                acc += (myhead == 0 ? q.x : q.y) * hv;
            } else {
                acc += sp[wid][u] * hv;
            }
        }
    }

    float dv = (H == 1) ? den[0] : (myhead == 0 ? den[0] : den[1]);
    float v = acc / dv + bias[lane];
    out[(size_t)n * M + lane] = (__half)fmaxf(v, 0.0f);
}

// ---------------------------------------------------------------------------
// Layer-2 aggregate, HEAD-SPLIT: 2 waves per node; h fp16 in, fp16 out.
// ---------------------------------------------------------------------------
__global__ __launch_bounds__(256) void aggregate2_kernel(
        const __half* __restrict__ h,       // [N][128] fp16
        const float* __restrict__ alpha_s,  // [N][2]
        const float* __restrict__ alpha_d,  // [N][2]
        const int* __restrict__ row_ptr,
        const int* __restrict__ csr_src,
        const float* __restrict__ bias,     // [128]
        __half* __restrict__ out, int N) {
    __shared__ int   ss[4][64];
    __shared__ float sp[4][64];
    const int wid  = threadIdx.x >> 6;
    const int lane = threadIdx.x & 63;
    const int gw   = blockIdx.x * 4 + wid;
    const int n    = gw >> 1;
    const int hd   = gw & 1;
    if (n >= N) return;

    const int lo = row_ptr[n], hi = row_ptr[n + 1];
    const float adv = alpha_d[n * 2 + hd];

    float m = -INFINITY, den = 0.0f, acc = 0.0f;

    for (int e0 = lo; e0 < hi; e0 += 64) {
        const int idx = e0 + lane;
        const bool valid = idx < hi;
        const int src_l = csr_src[valid ? idx : hi - 1];

        float lg = alpha_s[src_l * 2 + hd] + adv;
        lg = lg > 0.0f ? lg : 0.2f * lg;
        if (!valid) lg = -INFINITY;

        float cm = lg;
        for (int mm = 32; mm >= 1; mm >>= 1)
            cm = fmaxf(cm, __shfl_xor(cm, mm, 64));

        float mnew = fmaxf(m, cm);
        float sc = __expf(m - mnew);
        den *= sc; acc *= sc; m = mnew;

        float p = __expf(lg - m), ds = p;
        for (int mm = 32; mm >= 1; mm >>= 1)
            ds += __shfl_xor(ds, mm, 64);
        den += ds;

        ss[wid][lane] = src_l;
        sp[wid][lane] = p;

        int nu = hi - e0; if (nu > 64) nu = 64;
        int u = 0;
#pragma unroll 1
        for (; u + 8 <= nu; u += 8) {
            int su[8];
#pragma unroll
            for (int t = 0; t < 8; ++t)
                su[t] = __builtin_amdgcn_readfirstlane(ss[wid][u + t]);
            float hv[8];
#pragma unroll
            for (int t = 0; t < 8; ++t)
                hv[t] = __half2float(h[(size_t)su[t] * 128 + hd * 64 + lane]);
#pragma unroll
            for (int t = 0; t < 8; ++t)
                acc += sp[wid][u + t] * hv[t];
        }
#pragma unroll 1
        for (; u < nu; ++u) {
            int su = __builtin_amdgcn_readfirstlane(ss[wid][u]);
            acc += sp[wid][u] * __half2float(h[(size_t)su * 128 + hd * 64 + lane]);
        }
    }

    float v = acc / den + bias[hd * 64 + lane];
    out[(size_t)n * 128 + hd * 64 + lane] = (__half)fmaxf(v, 0.0f);
}

// ---------------------------------------------------------------------------

extern "C" void kernel_launch(void* const* d_in, const int* in_sizes, int n_in,
                              void* d_out, int out_size, void* d_ws, size_t ws_size,
                              hipStream_t stream) {
    const float* x   = (const float*)d_in[0];
    const int*   ei  = (const int*)  d_in[1];
    const float* w1  = (const float*)d_in[2];
    const float* as1 = (const float*)d_in[3];
    const float* ad1 = (const float*)d_in[4];
    const float* b1  = (const float*)d_in[5];
    const float* w2  = (const float*)d_in[6];
    const float* as2 = (const float*)d_in[7];
    const float* ad2 = (const float*)d_in[8];
    const float* b2  = (const float*)d_in[9];
    const float* w3  = (const float*)d_in[10];
    const float* as3 = (const float*)d_in[11];
    const float* ad3 = (const float*)d_in[12];
    const float* b3  = (const float*)d_in[13];
    const float* fcw = (const float*)d_in[14];
    const float* fcb = (const float*)d_in[15];
    float* out = (float*)d_out;

    const int N = in_sizes[0] / 128;
    const int E = in_sizes[1] / 2;
    const int Etot = E + N;

    // workspace carve-up (256B aligned regions)
    char* p = (char*)d_ws;
    auto alloc = [&](size_t bytes) {
        char* r = p;
        p += (bytes + 255) & ~(size_t)255;
        return r;
    };
    int*    cnt     = (int*)   alloc((size_t)N * 4);
    int*    row_ptr = (int*)   alloc((size_t)(N + 1) * 4);
    int*    rank    = (int*)   alloc((size_t)Etot * 4);
    int*    csr_src = (int*)   alloc((size_t)Etot * 4);
    __half* x16     = (__half*)alloc((size_t)N * 128 * 2);   // fp16 input x
    __half* bufA    = (__half*)alloc((size_t)N * 128 * 2);   // fp16 gemm out h
    __half* bufB    = (__half*)alloc((size_t)N * 128 * 2);   // fp16 agg out
    __half* bufC    = (__half*)alloc((size_t)N * 64 * 2);    // fp16 agg3 out (FC in)
    __half* wh1     = (__half*)alloc((size_t)8192 * 2);
    __half* wh2     = (__half*)alloc((size_t)8192 * 2);
    __half* wh3     = (__half*)alloc((size_t)8192 * 2);
    __half* fcwh    = (__half*)alloc((size_t)32768 * 2);
    float*  alpS    = (float*) alloc((size_t)N * 2 * 4);
    float*  alpD    = (float*) alloc((size_t)N * 2 * 4);
    (void)ws_size; (void)n_in; (void)out_size;

    // weight + x conversions (weights independent of everything downstream)
    cvtw_kernel<<<224, 256, 0, stream>>>(w1, w2, w3, fcw, wh1, wh2, wh3, fcwh);
    cvtx_kernel<<<(N * 32 + 255) / 256, 256, 0, stream>>>(x, x16, N * 32);

    // ---- build CSR by dst (atomics only in pass 1) ----
    hipMemsetAsync(cnt, 0, (size_t)N * 4, stream);
    int eb4 = (Etot / 4 + 255) / 256 + 1;   // 4 edges/thread
    count_rank_kernel<<<eb4, 256, 0, stream>>>(ei, E, N, cnt, rank);
    scan_kernel<<<1, 1024, 0, stream>>>(cnt, N, Etot, row_ptr);
    scatter_kernel<<<eb4, 256, 0, stream>>>(ei, E, N, row_ptr, rank, csr_src);

    int gb  = (N + 3) / 4;        // aggregate (PL1): 4 waves/block, 1 node/wave
    int gb2 = (2 * N + 3) / 4;    // aggregate2: 2 waves/node
    const int GB16 = 2048;        // fp16 gemm grids: 8 blocks/CU (16KB LDS, VGPR<=64)

    // ---- layer 1: 128 -> H2 x C32, concat ----
    gemm16_kernel<128, 64, 8, 1><<<dim3(GB16, 1), 256, 0, stream>>>(
        x16, wh1, bufA, as1, ad1, alpS, alpD, N, 64);
    aggregate_kernel<2, 32><<<gb, 256, 0, stream>>>(bufA, alpS, alpD, row_ptr, csr_src, b1, bufB, N);

    // ---- layer 2: 64 -> H2 x C64, concat (head-split aggregate) ----
    gemm16_kernel<64, 128, 8, 2><<<dim3(GB16, 1), 256, 0, stream>>>(
        bufB, wh2, bufA, as2, ad2, alpS, alpD, N, 128);
    aggregate2_kernel<<<gb2, 256, 0, stream>>>(bufA, alpS, alpD, row_ptr, csr_src, b2, bufB, N);

    // ---- layer 3: 128 -> H1 x C64, mean; output fp16 for FC ----
    gemm16_kernel<128, 64, 8, 3><<<dim3(GB16, 1), 256, 0, stream>>>(
        bufB, wh3, bufA, as3, ad3, alpS, alpD, N, 64);
    aggregate_kernel<1, 64><<<gb, 256, 0, stream>>>(bufA, alpS, alpD, row_ptr, csr_src, b3, bufC, N);

    // ---- FC: 64 -> 512 + relu, fp16 inputs, 2048 blocks = 8/CU ----
    fc16_kernel<8><<<dim3(512, 4), 256, 0, stream>>>(
        bufC, fcwh, fcb, out, N);
}

// Round 12
// 754.220 us; speedup vs baseline: 1.1691x; 1.0064x over previous
//
#include <hip/hip_runtime.h>
#include <hip/hip_fp16.h>
#include <math.h>

// ---------------------------------------------------------------------------
// GAT pipeline: 3x (GEMM16+alpha fused -> CSR segment-softmax aggregate) + FC
// R19: (1) fc16 grid (512,4)->(521,4): 2084 waves/slice x 3 groups = 6252 >=
//      6250 -> tail-free (was ceil 4 vs avg 3.05 = 25% tail; R18's occupancy
//      counter at 35% despite 8 blocks/CU was the tail running at ~5% occ).
//      (2) fused_pre kernel: cvtx + cvtw + count_rank are independent but
//      were stream-serialized; block-range-partitioned single launch runs
//      them concurrently (~10us). All else = R18 (proven 759us).
// ---------------------------------------------------------------------------

typedef _Float16 h2_t __attribute__((ext_vector_type(2)));

__device__ __forceinline__ h2_t as_h2(unsigned int u) {
    union { unsigned int u; h2_t h; } x; x.u = u; return x.h;
}

__device__ __forceinline__ float fdot2(h2_t a, h2_t b, float c) {
#if __has_builtin(__builtin_amdgcn_fdot2)
    return __builtin_amdgcn_fdot2(a, b, c, false);
#else
    return c + (float)a[0] * (float)b[0] + (float)a[1] * (float)b[1];
#endif
}

// ---------------------------------------------------------------------------
// Fused prologue: blocks [0,XB) convert x fp32->fp16 (float4-wide);
// blocks [XB,XB+WB) convert the 4 weight mats; blocks [XB+WB,..) run
// count_rank (cnt[dst]++ + per-edge arrival rank). All three independent.
// ---------------------------------------------------------------------------
__global__ void fused_pre_kernel(
        const float* __restrict__ x, __half* __restrict__ xh, int n4,
        const float* __restrict__ w1, const float* __restrict__ w2,
        const float* __restrict__ w3, const float* __restrict__ fcw,
        __half* __restrict__ o1, __half* __restrict__ o2,
        __half* __restrict__ o3, __half* __restrict__ o4,
        const int* __restrict__ ei, int E, int N,
        int* __restrict__ cnt, int* __restrict__ rank,
        int XB, int WB) {
    const int b = blockIdx.x;
    if (b < XB) {
        int i = b * 256 + threadIdx.x;
        if (i < n4) {
            float4 v = ((const float4*)x)[i];
            __half2 a, c;
            a.x = (__half)v.x; a.y = (__half)v.y;
            c.x = (__half)v.z; c.y = (__half)v.w;
            ((__half2*)xh)[2 * i]     = a;
            ((__half2*)xh)[2 * i + 1] = c;
        }
    } else if (b < XB + WB) {
        int i = (b - XB) * 256 + threadIdx.x;
        if (i < 8192)       o1[i]         = (__half)w1[i];
        else if (i < 16384) o2[i - 8192]  = (__half)w2[i - 8192];
        else if (i < 24576) o3[i - 16384] = (__half)w3[i - 16384];
        else if (i < 57344) o4[i - 24576] = (__half)fcw[i - 24576];
    } else {
        const int base = XB + WB;
        const int Etot = E + N;
        const int T = (gridDim.x - base) * 256;
        int e = (b - base) * 256 + threadIdx.x;
#pragma unroll 4
        for (int u = 0; u < 4; ++u, e += T) {
            if (e < Etot) {
                int dst = (e < E) ? ei[E + e] : (e - E);   // self-loops appended
                rank[e] = atomicAdd(&cnt[dst], 1);
            }
        }
    }
}

__global__ __launch_bounds__(1024) void scan_kernel(const int* __restrict__ cnt,
                                                    int N, int Etot,
                                                    int* __restrict__ row_ptr) {
    __shared__ int sums[1024];
    int tid = threadIdx.x;
    int chunk = (N + 1023) >> 10;
    int lo = tid * chunk;
    int hi = lo + chunk; if (hi > N) hi = N; if (lo > N) lo = N;
    int s = 0;
    for (int i = lo; i < hi; ++i) s += cnt[i];
    sums[tid] = s;
    __syncthreads();
    for (int off = 1; off < 1024; off <<= 1) {
        int t = (tid >= off) ? sums[tid - off] : 0;
        __syncthreads();
        sums[tid] += t;
        __syncthreads();
    }
    int run = sums[tid] - s;   // exclusive base for this thread's chunk
    for (int i = lo; i < hi; ++i) {
        row_ptr[i] = run;
        run += cnt[i];
    }
    if (tid == 0) row_ptr[N] = Etot;
}

// pass 3: pos = row_ptr[dst] + rank[e]; atomic-free scattered store.
__global__ void scatter_kernel(const int* __restrict__ ei, int E, int N,
                               const int* __restrict__ row_ptr,
                               const int* __restrict__ rank,
                               int* __restrict__ csr_src) {
    const int Etot = E + N;
    const int T = gridDim.x * blockDim.x;
    int e = blockIdx.x * blockDim.x + threadIdx.x;
#pragma unroll 4
    for (int u = 0; u < 4; ++u, e += T) {
        if (e < Etot) {
            int src, dst;
            if (e < E) { src = ei[e]; dst = ei[E + e]; }
            else       { src = e - E; dst = e - E; }
            csr_src[row_ptr[dst] + rank[e]] = src;
        }
    }
}

// ---------------------------------------------------------------------------
// Layer GEMM, fp16 in/W, fp32 acc via fdot2, fp16 out, fused alpha from the
// fp32 acc (R18-proven). 256 thr / 4 waves, W tile 16KB LDS (uint2-packed),
// RB=8 rows/wave, distance-1 ping-pong, unroll 2, grid 2048 = 8 blocks/CU.
// ALPHA: 1=(H2,C32: segmented 32-lane)  2=(H2,C64,PL2)  3=(H1,C64)
// ---------------------------------------------------------------------------
template <int K, int CHUNK, int RB, int ALPHA>
__global__ __launch_bounds__(256) void gemm16_kernel(
        const __half* __restrict__ in,
        const __half* __restrict__ Wh,
        __half* __restrict__ out,
        const float* __restrict__ a_src,
        const float* __restrict__ a_dst,
        float* __restrict__ alpS,
        float* __restrict__ alpD,
        int N, int M) {
    constexpr int PL = CHUNK / 64;
    constexpr int K4 = K / 4;
    __shared__ uint2 wlds[K4 * CHUNK];   // = K*CHUNK*2 B = 16 KB
    const unsigned short* wsrc = (const unsigned short*)Wh;
    for (int idx = threadIdx.x; idx < K4 * CHUNK; idx += 256) {
        int k4 = idx / CHUNK, c = idx % CHUNK;
        const unsigned short* wp = wsrc + (size_t)(4 * k4) * M + c;
        uint2 v;
        v.x = (unsigned int)wp[0]     | ((unsigned int)wp[M] << 16);
        v.y = (unsigned int)wp[2 * M] | ((unsigned int)wp[3 * M] << 16);
        wlds[idx] = v;
    }
    __syncthreads();

    const int wid  = threadIdx.x >> 6;
    const int lane = threadIdx.x & 63;

    float aSv[PL], aDv[PL];
#pragma unroll
    for (int j = 0; j < PL; ++j) {
        aSv[j] = a_src[lane + 64 * j];
        aDv[j] = a_dst[lane + 64 * j];
    }

    const int groups = (N + RB - 1) / RB;
    for (int g = blockIdx.x * 4 + wid; g < groups; g += gridDim.x * 4) {
        const int n0 = g * RB;
        const bool full = (n0 + RB <= N);

        float acc[RB][PL];
#pragma unroll
        for (int r = 0; r < RB; ++r)
#pragma unroll
            for (int j = 0; j < PL; ++j) acc[r][j] = 0.0f;

        const uint2* xp = (const uint2*)(in + (size_t)n0 * K);

        if (full) {
            uint2 xv[RB], xn[RB];
#pragma unroll
            for (int r = 0; r < RB; ++r) xv[r] = xp[r * K4];
#pragma unroll 2
            for (int k4 = 0; k4 < K4; ++k4) {
                if (k4 + 1 < K4) {
#pragma unroll
                    for (int r = 0; r < RB; ++r)
                        xn[r] = xp[r * K4 + k4 + 1];
                }
#pragma unroll
                for (int j = 0; j < PL; ++j) {
                    uint2 wv = wlds[k4 * CHUNK + lane + 64 * j];
#pragma unroll
                    for (int r = 0; r < RB; ++r) {
                        acc[r][j] = fdot2(as_h2(xv[r].x), as_h2(wv.x), acc[r][j]);
                        acc[r][j] = fdot2(as_h2(xv[r].y), as_h2(wv.y), acc[r][j]);
                    }
                }
                if (k4 + 1 < K4) {
#pragma unroll
                    for (int r = 0; r < RB; ++r) xv[r] = xn[r];
                }
            }
        } else {
#pragma unroll 1
            for (int k4 = 0; k4 < K4; ++k4) {
#pragma unroll 1
                for (int r = 0; r < RB; ++r) {
                    if (n0 + r >= N) break;
                    uint2 xr = xp[(size_t)r * K4 + k4];
#pragma unroll
                    for (int j = 0; j < PL; ++j) {
                        uint2 wv = wlds[k4 * CHUNK + lane + 64 * j];
                        acc[r][j] = fdot2(as_h2(xr.x), as_h2(wv.x), acc[r][j]);
                        acc[r][j] = fdot2(as_h2(xr.y), as_h2(wv.y), acc[r][j]);
                    }
                }
            }
        }

#pragma unroll
        for (int r = 0; r < RB; ++r) {
            if (!full && n0 + r >= N) break;
            const int n = n0 + r;
#pragma unroll
            for (int j = 0; j < PL; ++j)
                out[(size_t)n * M + lane + 64 * j] = (__half)acc[r][j];

            float ps[PL], pd[PL];
#pragma unroll
            for (int j = 0; j < PL; ++j) { ps[j] = acc[r][j] * aSv[j]; pd[j] = acc[r][j] * aDv[j]; }
            const int m0 = (ALPHA == 1) ? 16 : 32;
            for (int mm = m0; mm >= 1; mm >>= 1) {
#pragma unroll
                for (int j = 0; j < PL; ++j) {
                    ps[j] += __shfl_xor(ps[j], mm, 64);
                    pd[j] += __shfl_xor(pd[j], mm, 64);
                }
            }
            if (ALPHA == 1) {
                if ((lane & 31) == 0) {
                    int idx = n * 2 + (lane >> 5);
                    alpS[idx] = ps[0]; alpD[idx] = pd[0];
                }
            } else if (ALPHA == 2) {
                if (lane == 0) {
#pragma unroll
                    for (int j = 0; j < PL; ++j) {
                        alpS[n * 2 + j] = ps[j]; alpD[n * 2 + j] = pd[j];
                    }
                }
            } else {
                if (lane == 0) { alpS[n] = ps[0]; alpD[n] = pd[0]; }
            }
        }
    }
}

// ---------------------------------------------------------------------------
// FC GEMM, fp16 inputs / fp32 accumulate via fdot2 (R17/R18-proven, VGPR 52).
// Grid (521,4): 2084 waves/slice x 3 groups >= 6250 -> tail-free.
// ---------------------------------------------------------------------------
template <int RB>
__global__ __launch_bounds__(256) void fc16_kernel(
        const __half* __restrict__ in,    // [N][64] fp16
        const __half* __restrict__ Wh,    // [64][512] fp16
        const float* __restrict__ bias,   // [512]
        float* __restrict__ out,          // [N][512]
        int N) {
    constexpr int K4 = 16, CHUNK = 128, M = 512;
    __shared__ uint2 wlds[K4 * CHUNK];    // 16 KB
    const int cb = blockIdx.y * CHUNK;
    const unsigned short* wsrc = (const unsigned short*)Wh;
    for (int idx = threadIdx.x; idx < K4 * CHUNK; idx += 256) {
        int k4 = idx / CHUNK, c = idx % CHUNK;
        const unsigned short* wp = wsrc + (size_t)(4 * k4) * M + cb + c;
        uint2 v;
        v.x = (unsigned int)wp[0]     | ((unsigned int)wp[M] << 16);
        v.y = (unsigned int)wp[2 * M] | ((unsigned int)wp[3 * M] << 16);
        wlds[idx] = v;
    }
    __syncthreads();

    const int wid  = threadIdx.x >> 6;
    const int lane = threadIdx.x & 63;
    const float b0 = bias[cb + lane];
    const float b1 = bias[cb + lane + 64];

    const int groups = (N + RB - 1) / RB;
    for (int g = blockIdx.x * 4 + wid; g < groups; g += gridDim.x * 4) {
        const int n0 = g * RB;
        const bool full = (n0 + RB <= N);

        float acc[RB][2];
#pragma unroll
        for (int r = 0; r < RB; ++r) { acc[r][0] = 0.0f; acc[r][1] = 0.0f; }

        const uint2* xp = (const uint2*)(in + (size_t)n0 * 64);

        if (full) {
            uint2 xv[RB], xn[RB];
#pragma unroll
            for (int r = 0; r < RB; ++r) xv[r] = xp[r * K4];
#pragma unroll 2
            for (int k4 = 0; k4 < K4; ++k4) {
                if (k4 + 1 < K4) {
#pragma unroll
                    for (int r = 0; r < RB; ++r)
                        xn[r] = xp[r * K4 + k4 + 1];
                }
#pragma unroll
                for (int j = 0; j < 2; ++j) {
                    uint2 wv = wlds[k4 * CHUNK + lane + 64 * j];
#pragma unroll
                    for (int r = 0; r < RB; ++r) {
                        acc[r][j] = fdot2(as_h2(xv[r].x), as_h2(wv.x), acc[r][j]);
                        acc[r][j] = fdot2(as_h2(xv[r].y), as_h2(wv.y), acc[r][j]);
                    }
                }
                if (k4 + 1 < K4) {
#pragma unroll
                    for (int r = 0; r < RB; ++r) xv[r] = xn[r];
                }
            }
        } else {
#pragma unroll 1
            for (int k4 = 0; k4 < K4; ++k4) {
#pragma unroll 1
                for (int r = 0; r < RB; ++r) {
                    if (n0 + r >= N) break;
                    uint2 xr = xp[(size_t)r * K4 + k4];
#pragma unroll
                    for (int j = 0; j < 2; ++j) {
                        uint2 wv = wlds[k4 * CHUNK + lane + 64 * j];
                        acc[r][j] = fdot2(as_h2(xr.x), as_h2(wv.x), acc[r][j]);
                        acc[r][j] = fdot2(as_h2(xr.y), as_h2(wv.y), acc[r][j]);
                    }
                }
            }
        }

#pragma unroll
        for (int r = 0; r < RB; ++r) {
            if (!full && n0 + r >= N) break;
            const int n = n0 + r;
            out[(size_t)n * M + cb + lane]      = fmaxf(acc[r][0] + b0, 0.0f);
            out[(size_t)n * M + cb + lane + 64] = fmaxf(acc[r][1] + b1, 0.0f);
        }
    }
}

// ---------------------------------------------------------------------------
// Aggregate (PL1 variants, layers 1+3): one wave per dst node, 64-edge
// chunks, two-phase; h gathered as FP16; softmax/accumulate fp32; fp16 out.
// ---------------------------------------------------------------------------
template <int H, int C>
__global__ __launch_bounds__(256) void aggregate_kernel(
        const __half* __restrict__ h,
        const float* __restrict__ alpha_s,
        const float* __restrict__ alpha_d,
        const int* __restrict__ row_ptr,
        const int* __restrict__ csr_src,
        const float* __restrict__ bias,
        __half* __restrict__ out, int N) {
    constexpr int M = H * C;
    __shared__ int   ss[4][64];
    __shared__ float sp[4][128];
    const int wid  = threadIdx.x >> 6;
    const int lane = threadIdx.x & 63;
    const int n = blockIdx.x * 4 + wid;
    if (n >= N) return;

    const int lo = row_ptr[n], hi = row_ptr[n + 1];
    const int myhead = (H == 2) ? (lane / C) : 0;

    float adv[H];
#pragma unroll
    for (int t = 0; t < H; ++t) adv[t] = alpha_d[n * H + t];

    float m[H], den[H], acc = 0.0f;
#pragma unroll
    for (int t = 0; t < H; ++t) { m[t] = -INFINITY; den[t] = 0.0f; }

    for (int e0 = lo; e0 < hi; e0 += 64) {
        const int idx = e0 + lane;
        const bool valid = idx < hi;
        const int src_l = csr_src[valid ? idx : hi - 1];

        // ---- phase A: lane-parallel logits ----
        float lg[H];
        if (H == 2) {
            float2 as = ((const float2*)alpha_s)[src_l];
            lg[0] = as.x + adv[0];
            lg[1] = as.y + adv[1];
        } else {
            lg[0] = alpha_s[src_l] + adv[0];
        }
#pragma unroll
        for (int t = 0; t < H; ++t) {
            float v = lg[t];
            v = v > 0.0f ? v : 0.2f * v;
            lg[t] = valid ? v : -INFINITY;
        }
        float cm[H];
#pragma unroll
        for (int t = 0; t < H; ++t) cm[t] = lg[t];
        for (int mm = 32; mm >= 1; mm >>= 1) {
#pragma unroll
            for (int t = 0; t < H; ++t)
                cm[t] = fmaxf(cm[t], __shfl_xor(cm[t], mm, 64));
        }
        float sc[H];
#pragma unroll
        for (int t = 0; t < H; ++t) {
            float mnew = fmaxf(m[t], cm[t]);
            sc[t] = __expf(m[t] - mnew);
            den[t] *= sc[t];
            m[t] = mnew;
        }
        acc *= (H == 1) ? sc[0] : (myhead == 0 ? sc[0] : sc[1]);

        float p[H], dsum[H];
#pragma unroll
        for (int t = 0; t < H; ++t) { p[t] = __expf(lg[t] - m[t]); dsum[t] = p[t]; }
        for (int mm = 32; mm >= 1; mm >>= 1) {
#pragma unroll
            for (int t = 0; t < H; ++t)
                dsum[t] += __shfl_xor(dsum[t], mm, 64);
        }
#pragma unroll
        for (int t = 0; t < H; ++t) den[t] += dsum[t];

        ss[wid][lane] = src_l;
        if (H == 2) ((float2*)sp[wid])[lane] = make_float2(p[0], p[1]);
        else        sp[wid][lane] = p[0];

        // ---- phase B: per-edge broadcast accumulate, 8-wide batch ----
        int nu = hi - e0; if (nu > 64) nu = 64;
        int u = 0;
#pragma unroll 1
        for (; u + 8 <= nu; u += 8) {
            int su[8];
#pragma unroll
            for (int t = 0; t < 8; ++t)
                su[t] = __builtin_amdgcn_readfirstlane(ss[wid][u + t]);
            float hv[8];
#pragma unroll
            for (int t = 0; t < 8; ++t)
                hv[t] = __half2float(h[(size_t)su[t] * M + lane]);
            if (H == 2) {
                const float2* pb = (const float2*)sp[wid];
#pragma unroll
                for (int t = 0; t < 8; ++t) {
                    float2 q = pb[u + t];
                    acc += (myhead == 0 ? q.x : q.y) * hv[t];
                }
            } else {
#pragma unroll
                for (int t = 0; t < 8; ++t)
                    acc += sp[wid][u + t] * hv[t];
            }
        }
#pragma unroll 1
        for (; u < nu; ++u) {
            int su = __builtin_amdgcn_readfirstlane(ss[wid][u]);
            float hv = __half2float(h[(size_t)su * M + lane]);
            if (H == 2) {
                float2 q = ((const float2*)sp[wid])[u];
                acc += (myhead == 0 ? q.x : q.y) * hv;
            } else {
                acc += sp[wid][u] * hv;
            }
        }
    }

    float dv = (H == 1) ? den[0] : (myhead == 0 ? den[0] : den[1]);
    float v = acc / dv + bias[lane];
    out[(size_t)n * M + lane] = (__half)fmaxf(v, 0.0f);
}

// ---------------------------------------------------------------------------
// Layer-2 aggregate, HEAD-SPLIT: 2 waves per node; h fp16 in, fp16 out.
// ---------------------------------------------------------------------------
__global__ __launch_bounds__(256) void aggregate2_kernel(
        const __half* __restrict__ h,       // [N][128] fp16
        const float* __restrict__ alpha_s,  // [N][2]
        const float* __restrict__ alpha_d,  // [N][2]
        const int* __restrict__ row_ptr,
        const int* __restrict__ csr_src,
        const float* __restrict__ bias,     // [128]
        __half* __restrict__ out, int N) {
    __shared__ int   ss[4][64];
    __shared__ float sp[4][64];
    const int wid  = threadIdx.x >> 6;
    const int lane = threadIdx.x & 63;
    const int gw   = blockIdx.x * 4 + wid;
    const int n    = gw >> 1;
    const int hd   = gw & 1;
    if (n >= N) return;

    const int lo = row_ptr[n], hi = row_ptr[n + 1];
    const float adv = alpha_d[n * 2 + hd];

    float m = -INFINITY, den = 0.0f, acc = 0.0f;

    for (int e0 = lo; e0 < hi; e0 += 64) {
        const int idx = e0 + lane;
        const bool valid = idx < hi;
        const int src_l = csr_src[valid ? idx : hi - 1];

        float lg = alpha_s[src_l * 2 + hd] + adv;
        lg = lg > 0.0f ? lg : 0.2f * lg;
        if (!valid) lg = -INFINITY;

        float cm = lg;
        for (int mm = 32; mm >= 1; mm >>= 1)
            cm = fmaxf(cm, __shfl_xor(cm, mm, 64));

        float mnew = fmaxf(m, cm);
        float sc = __expf(m - mnew);
        den *= sc; acc *= sc; m = mnew;

        float p = __expf(lg - m), ds = p;
        for (int mm = 32; mm >= 1; mm >>= 1)
            ds += __shfl_xor(ds, mm, 64);
        den += ds;

        ss[wid][lane] = src_l;
        sp[wid][lane] = p;

        int nu = hi - e0; if (nu > 64) nu = 64;
        int u = 0;
#pragma unroll 1
        for (; u + 8 <= nu; u += 8) {
            int su[8];
#pragma unroll
            for (int t = 0; t < 8; ++t)
                su[t] = __builtin_amdgcn_readfirstlane(ss[wid][u + t]);
            float hv[8];
#pragma unroll
            for (int t = 0; t < 8; ++t)
                hv[t] = __half2float(h[(size_t)su[t] * 128 + hd * 64 + lane]);
#pragma unroll
            for (int t = 0; t < 8; ++t)
                acc += sp[wid][u + t] * hv[t];
        }
#pragma unroll 1
        for (; u < nu; ++u) {
            int su = __builtin_amdgcn_readfirstlane(ss[wid][u]);
            acc += sp[wid][u] * __half2float(h[(size_t)su * 128 + hd * 64 + lane]);
        }
    }

    float v = acc / den + bias[hd * 64 + lane];
    out[(size_t)n * 128 + hd * 64 + lane] = (__half)fmaxf(v, 0.0f);
}

// ---------------------------------------------------------------------------

extern "C" void kernel_launch(void* const* d_in, const int* in_sizes, int n_in,
                              void* d_out, int out_size, void* d_ws, size_t ws_size,
                              hipStream_t stream) {
    const float* x   = (const float*)d_in[0];
    const int*   ei  = (const int*)  d_in[1];
    const float* w1  = (const float*)d_in[2];
    const float* as1 = (const float*)d_in[3];
    const float* ad1 = (const float*)d_in[4];
    const float* b1  = (const float*)d_in[5];
    const float* w2  = (const float*)d_in[6];
    const float* as2 = (const float*)d_in[7];
    const float* ad2 = (const float*)d_in[8];
    const float* b2  = (const float*)d_in[9];
    const float* w3  = (const float*)d_in[10];
    const float* as3 = (const float*)d_in[11];
    const float* ad3 = (const float*)d_in[12];
    const float* b3  = (const float*)d_in[13];
    const float* fcw = (const float*)d_in[14];
    const float* fcb = (const float*)d_in[15];
    float* out = (float*)d_out;

    const int N = in_sizes[0] / 128;
    const int E = in_sizes[1] / 2;
    const int Etot = E + N;

    // workspace carve-up (256B aligned regions)
    char* p = (char*)d_ws;
    auto alloc = [&](size_t bytes) {
        char* r = p;
        p += (bytes + 255) & ~(size_t)255;
        return r;
    };
    int*    cnt     = (int*)   alloc((size_t)N * 4);
    int*    row_ptr = (int*)   alloc((size_t)(N + 1) * 4);
    int*    rank    = (int*)   alloc((size_t)Etot * 4);
    int*    csr_src = (int*)   alloc((size_t)Etot * 4);
    __half* x16     = (__half*)alloc((size_t)N * 128 * 2);   // fp16 input x
    __half* bufA    = (__half*)alloc((size_t)N * 128 * 2);   // fp16 gemm out h
    __half* bufB    = (__half*)alloc((size_t)N * 128 * 2);   // fp16 agg out
    __half* bufC    = (__half*)alloc((size_t)N * 64 * 2);    // fp16 agg3 out (FC in)
    __half* wh1     = (__half*)alloc((size_t)8192 * 2);
    __half* wh2     = (__half*)alloc((size_t)8192 * 2);
    __half* wh3     = (__half*)alloc((size_t)8192 * 2);
    __half* fcwh    = (__half*)alloc((size_t)32768 * 2);
    float*  alpS    = (float*) alloc((size_t)N * 2 * 4);
    float*  alpD    = (float*) alloc((size_t)N * 2 * 4);
    (void)ws_size; (void)n_in; (void)out_size;

    // ---- fused prologue: cvtx + cvtw + count_rank in one launch ----
    hipMemsetAsync(cnt, 0, (size_t)N * 4, stream);
    const int n4 = N * 32;                      // float4 units in x
    const int XB = (n4 + 255) / 256;            // cvtx blocks (6250)
    const int WB = 224;                         // cvtw blocks
    const int CB = (Etot / 4 + 255) / 256 + 1;  // count_rank blocks
    fused_pre_kernel<<<XB + WB + CB, 256, 0, stream>>>(
        x, x16, n4, w1, w2, w3, fcw, wh1, wh2, wh3, fcwh,
        ei, E, N, cnt, rank, XB, WB);
    scan_kernel<<<1, 1024, 0, stream>>>(cnt, N, Etot, row_ptr);
    scatter_kernel<<<CB, 256, 0, stream>>>(ei, E, N, row_ptr, rank, csr_src);

    int gb  = (N + 3) / 4;        // aggregate (PL1): 4 waves/block, 1 node/wave
    int gb2 = (2 * N + 3) / 4;    // aggregate2: 2 waves/node
    const int GB16 = 2048;        // fp16 gemm grids: 8 blocks/CU (16KB LDS, VGPR<=64)

    // ---- layer 1: 128 -> H2 x C32, concat ----
    gemm16_kernel<128, 64, 8, 1><<<dim3(GB16, 1), 256, 0, stream>>>(
        x16, wh1, bufA, as1, ad1, alpS, alpD, N, 64);
    aggregate_kernel<2, 32><<<gb, 256, 0, stream>>>(bufA, alpS, alpD, row_ptr, csr_src, b1, bufB, N);

    // ---- layer 2: 64 -> H2 x C64, concat (head-split aggregate) ----
    gemm16_kernel<64, 128, 8, 2><<<dim3(GB16, 1), 256, 0, stream>>>(
        bufB, wh2, bufA, as2, ad2, alpS, alpD, N, 128);
    aggregate2_kernel<<<gb2, 256, 0, stream>>>(bufA, alpS, alpD, row_ptr, csr_src, b2, bufB, N);

    // ---- layer 3: 128 -> H1 x C64, mean; output fp16 for FC ----
    gemm16_kernel<128, 64, 8, 3><<<dim3(GB16, 1), 256, 0, stream>>>(
        bufB, wh3, bufA, as3, ad3, alpS, alpD, N, 64);
    aggregate_kernel<1, 64><<<gb, 256, 0, stream>>>(bufA, alpS, alpD, row_ptr, csr_src, b3, bufC, N);

    // ---- FC: 64 -> 512 + relu, fp16 inputs, tail-free grid (521,4) ----
    fc16_kernel<8><<<dim3(521, 4), 256, 0, stream>>>(
        bufC, fcwh, fcb, out, N);
}

// Round 13
// 688.210 us; speedup vs baseline: 1.2812x; 1.0959x over previous
//
#include <hip/hip_runtime.h>
#include <hip/hip_fp16.h>
#include <math.h>

// ---------------------------------------------------------------------------
// GAT pipeline: 3x (GEMM16+alpha fused -> CSR segment-softmax aggregate) + FC
// R20: (1) fc16 grid back to (512,4) (R19's 521 was -2us and doubled FETCH).
//      (2) fc16 column-pairing: lane owns cols (2l,2l+1) -> uint4 LDS read
//      (1 instead of 2) + float2 store (1 instead of 2). Same math.
//      (3) scan parallelized: 256-block partial sums -> 1-block scan of 256
//      -> 256-block emit (was 1 block x 1024 thr serializing ~20us).
//      Everything else = R19 (754us proven).
// ---------------------------------------------------------------------------

typedef _Float16 h2_t __attribute__((ext_vector_type(2)));

__device__ __forceinline__ h2_t as_h2(unsigned int u) {
    union { unsigned int u; h2_t h; } x; x.u = u; return x.h;
}

__device__ __forceinline__ float fdot2(h2_t a, h2_t b, float c) {
#if __has_builtin(__builtin_amdgcn_fdot2)
    return __builtin_amdgcn_fdot2(a, b, c, false);
#else
    return c + (float)a[0] * (float)b[0] + (float)a[1] * (float)b[1];
#endif
}

// ---------------------------------------------------------------------------
// Fused prologue: blocks [0,XB) convert x fp32->fp16 (float4-wide);
// blocks [XB,XB+WB) convert the 4 weight mats; blocks [XB+WB,..) run
// count_rank (cnt[dst]++ + per-edge arrival rank). All three independent.
// ---------------------------------------------------------------------------
__global__ void fused_pre_kernel(
        const float* __restrict__ x, __half* __restrict__ xh, int n4,
        const float* __restrict__ w1, const float* __restrict__ w2,
        const float* __restrict__ w3, const float* __restrict__ fcw,
        __half* __restrict__ o1, __half* __restrict__ o2,
        __half* __restrict__ o3, __half* __restrict__ o4,
        const int* __restrict__ ei, int E, int N,
        int* __restrict__ cnt, int* __restrict__ rank,
        int XB, int WB) {
    const int b = blockIdx.x;
    if (b < XB) {
        int i = b * 256 + threadIdx.x;
        if (i < n4) {
            float4 v = ((const float4*)x)[i];
            __half2 a, c;
            a.x = (__half)v.x; a.y = (__half)v.y;
            c.x = (__half)v.z; c.y = (__half)v.w;
            ((__half2*)xh)[2 * i]     = a;
            ((__half2*)xh)[2 * i + 1] = c;
        }
    } else if (b < XB + WB) {
        int i = (b - XB) * 256 + threadIdx.x;
        if (i < 8192)       o1[i]         = (__half)w1[i];
        else if (i < 16384) o2[i - 8192]  = (__half)w2[i - 8192];
        else if (i < 24576) o3[i - 16384] = (__half)w3[i - 16384];
        else if (i < 57344) o4[i - 24576] = (__half)fcw[i - 24576];
    } else {
        const int base = XB + WB;
        const int Etot = E + N;
        const int T = (gridDim.x - base) * 256;
        int e = (b - base) * 256 + threadIdx.x;
#pragma unroll 4
        for (int u = 0; u < 4; ++u, e += T) {
            if (e < Etot) {
                int dst = (e < E) ? ei[E + e] : (e - E);   // self-loops appended
                rank[e] = atomicAdd(&cnt[dst], 1);
            }
        }
    }
}

// ---------------------------------------------------------------------------
// Parallel scan, 3 phases. NB=256 blocks, chunk = ceil(N/NB) <= 256.
// ---------------------------------------------------------------------------
#define SCAN_NB 256

// phase A: per-block partial sum of its chunk
__global__ __launch_bounds__(256) void scanA_kernel(const int* __restrict__ cnt,
                                                    int N, int* __restrict__ bsum) {
    __shared__ int red[256];
    const int chunk = (N + SCAN_NB - 1) / SCAN_NB;
    const int lo = blockIdx.x * chunk;
    const int len = min(N - lo, chunk);
    int s = 0;
    for (int i = threadIdx.x; i < len; i += 256) s += cnt[lo + i];
    red[threadIdx.x] = s;
    __syncthreads();
    for (int off = 128; off >= 1; off >>= 1) {
        if (threadIdx.x < off) red[threadIdx.x] += red[threadIdx.x + off];
        __syncthreads();
    }
    if (threadIdx.x == 0) bsum[blockIdx.x] = red[0];
}

// phase B: single block exclusive-scans the 256 block sums
__global__ __launch_bounds__(256) void scanB_kernel(int* __restrict__ bsum,
                                                    int* __restrict__ bbase) {
    __shared__ int s[256];
    int v = bsum[threadIdx.x];
    s[threadIdx.x] = v;
    __syncthreads();
    for (int off = 1; off < 256; off <<= 1) {
        int t = (threadIdx.x >= off) ? s[threadIdx.x - off] : 0;
        __syncthreads();
        s[threadIdx.x] += t;
        __syncthreads();
    }
    bbase[threadIdx.x] = s[threadIdx.x] - v;   // exclusive
}

// phase C: per-block exclusive scan of its chunk (chunk <= 256 elems)
__global__ __launch_bounds__(256) void scanC_kernel(const int* __restrict__ cnt,
                                                    int N, int Etot,
                                                    const int* __restrict__ bbase,
                                                    int* __restrict__ row_ptr) {
    __shared__ int s[256];
    const int chunk = (N + SCAN_NB - 1) / SCAN_NB;
    const int lo = blockIdx.x * chunk;
    const int len = min(N - lo, chunk);
    const int t = threadIdx.x;
    int v = (t < len) ? cnt[lo + t] : 0;
    s[t] = v;
    __syncthreads();
    for (int off = 1; off < 256; off <<= 1) {
        int u = (t >= off) ? s[t - off] : 0;
        __syncthreads();
        s[t] += u;
        __syncthreads();
    }
    if (t < len) row_ptr[lo + t] = bbase[blockIdx.x] + s[t] - v;
    if (blockIdx.x == 0 && t == 0) row_ptr[N] = Etot;
}

// pass 3: pos = row_ptr[dst] + rank[e]; atomic-free scattered store.
__global__ void scatter_kernel(const int* __restrict__ ei, int E, int N,
                               const int* __restrict__ row_ptr,
                               const int* __restrict__ rank,
                               int* __restrict__ csr_src) {
    const int Etot = E + N;
    const int T = gridDim.x * blockDim.x;
    int e = blockIdx.x * blockDim.x + threadIdx.x;
#pragma unroll 4
    for (int u = 0; u < 4; ++u, e += T) {
        if (e < Etot) {
            int src, dst;
            if (e < E) { src = ei[e]; dst = ei[E + e]; }
            else       { src = e - E; dst = e - E; }
            csr_src[row_ptr[dst] + rank[e]] = src;
        }
    }
}

// ---------------------------------------------------------------------------
// Layer GEMM, fp16 in/W, fp32 acc via fdot2, fp16 out, fused alpha from the
// fp32 acc (R18-proven). 256 thr / 4 waves, W tile 16KB LDS (uint2-packed),
// RB=8 rows/wave, distance-1 ping-pong, unroll 2, grid 2048 = 8 blocks/CU.
// ALPHA: 1=(H2,C32: segmented 32-lane)  2=(H2,C64,PL2)  3=(H1,C64)
// ---------------------------------------------------------------------------
template <int K, int CHUNK, int RB, int ALPHA>
__global__ __launch_bounds__(256) void gemm16_kernel(
        const __half* __restrict__ in,
        const __half* __restrict__ Wh,
        __half* __restrict__ out,
        const float* __restrict__ a_src,
        const float* __restrict__ a_dst,
        float* __restrict__ alpS,
        float* __restrict__ alpD,
        int N, int M) {
    constexpr int PL = CHUNK / 64;
    constexpr int K4 = K / 4;
    __shared__ uint2 wlds[K4 * CHUNK];   // = K*CHUNK*2 B = 16 KB
    const unsigned short* wsrc = (const unsigned short*)Wh;
    for (int idx = threadIdx.x; idx < K4 * CHUNK; idx += 256) {
        int k4 = idx / CHUNK, c = idx % CHUNK;
        const unsigned short* wp = wsrc + (size_t)(4 * k4) * M + c;
        uint2 v;
        v.x = (unsigned int)wp[0]     | ((unsigned int)wp[M] << 16);
        v.y = (unsigned int)wp[2 * M] | ((unsigned int)wp[3 * M] << 16);
        wlds[idx] = v;
    }
    __syncthreads();

    const int wid  = threadIdx.x >> 6;
    const int lane = threadIdx.x & 63;

    float aSv[PL], aDv[PL];
#pragma unroll
    for (int j = 0; j < PL; ++j) {
        aSv[j] = a_src[lane + 64 * j];
        aDv[j] = a_dst[lane + 64 * j];
    }

    const int groups = (N + RB - 1) / RB;
    for (int g = blockIdx.x * 4 + wid; g < groups; g += gridDim.x * 4) {
        const int n0 = g * RB;
        const bool full = (n0 + RB <= N);

        float acc[RB][PL];
#pragma unroll
        for (int r = 0; r < RB; ++r)
#pragma unroll
            for (int j = 0; j < PL; ++j) acc[r][j] = 0.0f;

        const uint2* xp = (const uint2*)(in + (size_t)n0 * K);

        if (full) {
            uint2 xv[RB], xn[RB];
#pragma unroll
            for (int r = 0; r < RB; ++r) xv[r] = xp[r * K4];
#pragma unroll 2
            for (int k4 = 0; k4 < K4; ++k4) {
                if (k4 + 1 < K4) {
#pragma unroll
                    for (int r = 0; r < RB; ++r)
                        xn[r] = xp[r * K4 + k4 + 1];
                }
#pragma unroll
                for (int j = 0; j < PL; ++j) {
                    uint2 wv = wlds[k4 * CHUNK + lane + 64 * j];
#pragma unroll
                    for (int r = 0; r < RB; ++r) {
                        acc[r][j] = fdot2(as_h2(xv[r].x), as_h2(wv.x), acc[r][j]);
                        acc[r][j] = fdot2(as_h2(xv[r].y), as_h2(wv.y), acc[r][j]);
                    }
                }
                if (k4 + 1 < K4) {
#pragma unroll
                    for (int r = 0; r < RB; ++r) xv[r] = xn[r];
                }
            }
        } else {
#pragma unroll 1
            for (int k4 = 0; k4 < K4; ++k4) {
#pragma unroll 1
                for (int r = 0; r < RB; ++r) {
                    if (n0 + r >= N) break;
                    uint2 xr = xp[(size_t)r * K4 + k4];
#pragma unroll
                    for (int j = 0; j < PL; ++j) {
                        uint2 wv = wlds[k4 * CHUNK + lane + 64 * j];
                        acc[r][j] = fdot2(as_h2(xr.x), as_h2(wv.x), acc[r][j]);
                        acc[r][j] = fdot2(as_h2(xr.y), as_h2(wv.y), acc[r][j]);
                    }
                }
            }
        }

#pragma unroll
        for (int r = 0; r < RB; ++r) {
            if (!full && n0 + r >= N) break;
            const int n = n0 + r;
#pragma unroll
            for (int j = 0; j < PL; ++j)
                out[(size_t)n * M + lane + 64 * j] = (__half)acc[r][j];

            float ps[PL], pd[PL];
#pragma unroll
            for (int j = 0; j < PL; ++j) { ps[j] = acc[r][j] * aSv[j]; pd[j] = acc[r][j] * aDv[j]; }
            const int m0 = (ALPHA == 1) ? 16 : 32;
            for (int mm = m0; mm >= 1; mm >>= 1) {
#pragma unroll
                for (int j = 0; j < PL; ++j) {
                    ps[j] += __shfl_xor(ps[j], mm, 64);
                    pd[j] += __shfl_xor(pd[j], mm, 64);
                }
            }
            if (ALPHA == 1) {
                if ((lane & 31) == 0) {
                    int idx = n * 2 + (lane >> 5);
                    alpS[idx] = ps[0]; alpD[idx] = pd[0];
                }
            } else if (ALPHA == 2) {
                if (lane == 0) {
#pragma unroll
                    for (int j = 0; j < PL; ++j) {
                        alpS[n * 2 + j] = ps[j]; alpD[n * 2 + j] = pd[j];
                    }
                }
            } else {
                if (lane == 0) { alpS[n] = ps[0]; alpD[n] = pd[0]; }
            }
        }
    }
}

// ---------------------------------------------------------------------------
// FC GEMM, fp16 inputs / fp32 accumulate via fdot2. Column-paired: lane owns
// cols (2l, 2l+1) of the 128-chunk -> one uint4 LDS read + one float2 store
// per row (was 2x uint2 reads + 2x dword stores). Grid (512,4) proven.
// ---------------------------------------------------------------------------
template <int RB>
__global__ __launch_bounds__(256) void fc16_kernel(
        const __half* __restrict__ in,    // [N][64] fp16
        const __half* __restrict__ Wh,    // [64][512] fp16
        const float* __restrict__ bias,   // [512]
        float* __restrict__ out,          // [N][512]
        int N) {
    constexpr int K4 = 16, CHUNK = 128, M = 512;
    __shared__ uint2 wlds[K4 * CHUNK];    // 16 KB
    const int cb = blockIdx.y * CHUNK;
    const unsigned short* wsrc = (const unsigned short*)Wh;
    for (int idx = threadIdx.x; idx < K4 * CHUNK; idx += 256) {
        int k4 = idx / CHUNK, c = idx % CHUNK;
        const unsigned short* wp = wsrc + (size_t)(4 * k4) * M + cb + c;
        uint2 v;
        v.x = (unsigned int)wp[0]     | ((unsigned int)wp[M] << 16);
        v.y = (unsigned int)wp[2 * M] | ((unsigned int)wp[3 * M] << 16);
        wlds[idx] = v;
    }
    __syncthreads();

    const int wid  = threadIdx.x >> 6;
    const int lane = threadIdx.x & 63;
    const float b0 = bias[cb + 2 * lane];
    const float b1 = bias[cb + 2 * lane + 1];

    const int groups = (N + RB - 1) / RB;
    for (int g = blockIdx.x * 4 + wid; g < groups; g += gridDim.x * 4) {
        const int n0 = g * RB;
        const bool full = (n0 + RB <= N);

        float acc[RB][2];
#pragma unroll
        for (int r = 0; r < RB; ++r) { acc[r][0] = 0.0f; acc[r][1] = 0.0f; }

        const uint2* xp = (const uint2*)(in + (size_t)n0 * 64);

        if (full) {
            uint2 xv[RB], xn[RB];
#pragma unroll
            for (int r = 0; r < RB; ++r) xv[r] = xp[r * K4];
#pragma unroll 2
            for (int k4 = 0; k4 < K4; ++k4) {
                if (k4 + 1 < K4) {
#pragma unroll
                    for (int r = 0; r < RB; ++r)
                        xn[r] = xp[r * K4 + k4 + 1];
                }
                // cols 2*lane (wv4.x,.y) and 2*lane+1 (wv4.z,.w)
                uint4 wv4 = *((const uint4*)&wlds[k4 * CHUNK + 2 * lane]);
#pragma unroll
                for (int r = 0; r < RB; ++r) {
                    acc[r][0] = fdot2(as_h2(xv[r].x), as_h2(wv4.x), acc[r][0]);
                    acc[r][0] = fdot2(as_h2(xv[r].y), as_h2(wv4.y), acc[r][0]);
                    acc[r][1] = fdot2(as_h2(xv[r].x), as_h2(wv4.z), acc[r][1]);
                    acc[r][1] = fdot2(as_h2(xv[r].y), as_h2(wv4.w), acc[r][1]);
                }
                if (k4 + 1 < K4) {
#pragma unroll
                    for (int r = 0; r < RB; ++r) xv[r] = xn[r];
                }
            }
        } else {
#pragma unroll 1
            for (int k4 = 0; k4 < K4; ++k4) {
#pragma unroll 1
                for (int r = 0; r < RB; ++r) {
                    if (n0 + r >= N) break;
                    uint2 xr = xp[(size_t)r * K4 + k4];
                    uint4 wv4 = *((const uint4*)&wlds[k4 * CHUNK + 2 * lane]);
                    acc[r][0] = fdot2(as_h2(xr.x), as_h2(wv4.x), acc[r][0]);
                    acc[r][0] = fdot2(as_h2(xr.y), as_h2(wv4.y), acc[r][0]);
                    acc[r][1] = fdot2(as_h2(xr.x), as_h2(wv4.z), acc[r][1]);
                    acc[r][1] = fdot2(as_h2(xr.y), as_h2(wv4.w), acc[r][1]);
                }
            }
        }

#pragma unroll
        for (int r = 0; r < RB; ++r) {
            if (!full && n0 + r >= N) break;
            const int n = n0 + r;
            float2 o;
            o.x = fmaxf(acc[r][0] + b0, 0.0f);
            o.y = fmaxf(acc[r][1] + b1, 0.0f);
            *((float2*)&out[(size_t)n * M + cb + 2 * lane]) = o;
        }
    }
}

// ---------------------------------------------------------------------------
// Aggregate (PL1 variants, layers 1+3): one wave per dst node, 64-edge
// chunks, two-phase; h gathered as FP16; softmax/accumulate fp32; fp16 out.
// ---------------------------------------------------------------------------
template <int H, int C>
__global__ __launch_bounds__(256) void aggregate_kernel(
        const __half* __restrict__ h,
        const float* __restrict__ alpha_s,
        const float* __restrict__ alpha_d,
        const int* __restrict__ row_ptr,
        const int* __restrict__ csr_src,
        const float* __restrict__ bias,
        __half* __restrict__ out, int N) {
    constexpr int M = H * C;
    __shared__ int   ss[4][64];
    __shared__ float sp[4][128];
    const int wid  = threadIdx.x >> 6;
    const int lane = threadIdx.x & 63;
    const int n = blockIdx.x * 4 + wid;
    if (n >= N) return;

    const int lo = row_ptr[n], hi = row_ptr[n + 1];
    const int myhead = (H == 2) ? (lane / C) : 0;

    float adv[H];
#pragma unroll
    for (int t = 0; t < H; ++t) adv[t] = alpha_d[n * H + t];

    float m[H], den[H], acc = 0.0f;
#pragma unroll
    for (int t = 0; t < H; ++t) { m[t] = -INFINITY; den[t] = 0.0f; }

    for (int e0 = lo; e0 < hi; e0 += 64) {
        const int idx = e0 + lane;
        const bool valid = idx < hi;
        const int src_l = csr_src[valid ? idx : hi - 1];

        // ---- phase A: lane-parallel logits ----
        float lg[H];
        if (H == 2) {
            float2 as = ((const float2*)alpha_s)[src_l];
            lg[0] = as.x + adv[0];
            lg[1] = as.y + adv[1];
        } else {
            lg[0] = alpha_s[src_l] + adv[0];
        }
#pragma unroll
        for (int t = 0; t < H; ++t) {
            float v = lg[t];
            v = v > 0.0f ? v : 0.2f * v;
            lg[t] = valid ? v : -INFINITY;
        }
        float cm[H];
#pragma unroll
        for (int t = 0; t < H; ++t) cm[t] = lg[t];
        for (int mm = 32; mm >= 1; mm >>= 1) {
#pragma unroll
            for (int t = 0; t < H; ++t)
                cm[t] = fmaxf(cm[t], __shfl_xor(cm[t], mm, 64));
        }
        float sc[H];
#pragma unroll
        for (int t = 0; t < H; ++t) {
            float mnew = fmaxf(m[t], cm[t]);
            sc[t] = __expf(m[t] - mnew);
            den[t] *= sc[t];
            m[t] = mnew;
        }
        acc *= (H == 1) ? sc[0] : (myhead == 0 ? sc[0] : sc[1]);

        float p[H], dsum[H];
#pragma unroll
        for (int t = 0; t < H; ++t) { p[t] = __expf(lg[t] - m[t]); dsum[t] = p[t]; }
        for (int mm = 32; mm >= 1; mm >>= 1) {
#pragma unroll
            for (int t = 0; t < H; ++t)
                dsum[t] += __shfl_xor(dsum[t], mm, 64);
        }
#pragma unroll
        for (int t = 0; t < H; ++t) den[t] += dsum[t];

        ss[wid][lane] = src_l;
        if (H == 2) ((float2*)sp[wid])[lane] = make_float2(p[0], p[1]);
        else        sp[wid][lane] = p[0];

        // ---- phase B: per-edge broadcast accumulate, 8-wide batch ----
        int nu = hi - e0; if (nu > 64) nu = 64;
        int u = 0;
#pragma unroll 1
        for (; u + 8 <= nu; u += 8) {
            int su[8];
#pragma unroll
            for (int t = 0; t < 8; ++t)
                su[t] = __builtin_amdgcn_readfirstlane(ss[wid][u + t]);
            float hv[8];
#pragma unroll
            for (int t = 0; t < 8; ++t)
                hv[t] = __half2float(h[(size_t)su[t] * M + lane]);
            if (H == 2) {
                const float2* pb = (const float2*)sp[wid];
#pragma unroll
                for (int t = 0; t < 8; ++t) {
                    float2 q = pb[u + t];
                    acc += (myhead == 0 ? q.x : q.y) * hv[t];
                }
            } else {
#pragma unroll
                for (int t = 0; t < 8; ++t)
                    acc += sp[wid][u + t] * hv[t];
            }
        }
#pragma unroll 1
        for (; u < nu; ++u) {
            int su = __builtin_amdgcn_readfirstlane(ss[wid][u]);
            float hv = __half2float(h[(size_t)su * M + lane]);
            if (H == 2) {
                float2 q = ((const float2*)sp[wid])[u];
                acc += (myhead == 0 ? q.x : q.y) * hv;
            } else {
                acc += sp[wid][u] * hv;
            }
        }
    }

    float dv = (H == 1) ? den[0] : (myhead == 0 ? den[0] : den[1]);
    float v = acc / dv + bias[lane];
    out[(size_t)n * M + lane] = (__half)fmaxf(v, 0.0f);
}

// ---------------------------------------------------------------------------
// Layer-2 aggregate, HEAD-SPLIT: 2 waves per node; h fp16 in, fp16 out.
// ---------------------------------------------------------------------------
__global__ __launch_bounds__(256) void aggregate2_kernel(
        const __half* __restrict__ h,       // [N][128] fp16
        const float* __restrict__ alpha_s,  // [N][2]
        const float* __restrict__ alpha_d,  // [N][2]
        const int* __restrict__ row_ptr,
        const int* __restrict__ csr_src,
        const float* __restrict__ bias,     // [128]
        __half* __restrict__ out, int N) {
    __shared__ int   ss[4][64];
    __shared__ float sp[4][64];
    const int wid  = threadIdx.x >> 6;
    const int lane = threadIdx.x & 63;
    const int gw   = blockIdx.x * 4 + wid;
    const int n    = gw >> 1;
    const int hd   = gw & 1;
    if (n >= N) return;

    const int lo = row_ptr[n], hi = row_ptr[n + 1];
    const float adv = alpha_d[n * 2 + hd];

    float m = -INFINITY, den = 0.0f, acc = 0.0f;

    for (int e0 = lo; e0 < hi; e0 += 64) {
        const int idx = e0 + lane;
        const bool valid = idx < hi;
        const int src_l = csr_src[valid ? idx : hi - 1];

        float lg = alpha_s[src_l * 2 + hd] + adv;
        lg = lg > 0.0f ? lg : 0.2f * lg;
        if (!valid) lg = -INFINITY;

        float cm = lg;
        for (int mm = 32; mm >= 1; mm >>= 1)
            cm = fmaxf(cm, __shfl_xor(cm, mm, 64));

        float mnew = fmaxf(m, cm);
        float sc = __expf(m - mnew);
        den *= sc; acc *= sc; m = mnew;

        float p = __expf(lg - m), ds = p;
        for (int mm = 32; mm >= 1; mm >>= 1)
            ds += __shfl_xor(ds, mm, 64);
        den += ds;

        ss[wid][lane] = src_l;
        sp[wid][lane] = p;

        int nu = hi - e0; if (nu > 64) nu = 64;
        int u = 0;
#pragma unroll 1
        for (; u + 8 <= nu; u += 8) {
            int su[8];
#pragma unroll
            for (int t = 0; t < 8; ++t)
                su[t] = __builtin_amdgcn_readfirstlane(ss[wid][u + t]);
            float hv[8];
#pragma unroll
            for (int t = 0; t < 8; ++t)
                hv[t] = __half2float(h[(size_t)su[t] * 128 + hd * 64 + lane]);
#pragma unroll
            for (int t = 0; t < 8; ++t)
                acc += sp[wid][u + t] * hv[t];
        }
#pragma unroll 1
        for (; u < nu; ++u) {
            int su = __builtin_amdgcn_readfirstlane(ss[wid][u]);
            acc += sp[wid][u] * __half2float(h[(size_t)su * 128 + hd * 64 + lane]);
        }
    }

    float v = acc / den + bias[hd * 64 + lane];
    out[(size_t)n * 128 + hd * 64 + lane] = (__half)fmaxf(v, 0.0f);
}

// ---------------------------------------------------------------------------

extern "C" void kernel_launch(void* const* d_in, const int* in_sizes, int n_in,
                              void* d_out, int out_size, void* d_ws, size_t ws_size,
                              hipStream_t stream) {
    const float* x   = (const float*)d_in[0];
    const int*   ei  = (const int*)  d_in[1];
    const float* w1  = (const float*)d_in[2];
    const float* as1 = (const float*)d_in[3];
    const float* ad1 = (const float*)d_in[4];
    const float* b1  = (const float*)d_in[5];
    const float* w2  = (const float*)d_in[6];
    const float* as2 = (const float*)d_in[7];
    const float* ad2 = (const float*)d_in[8];
    const float* b2  = (const float*)d_in[9];
    const float* w3  = (const float*)d_in[10];
    const float* as3 = (const float*)d_in[11];
    const float* ad3 = (const float*)d_in[12];
    const float* b3  = (const float*)d_in[13];
    const float* fcw = (const float*)d_in[14];
    const float* fcb = (const float*)d_in[15];
    float* out = (float*)d_out;

    const int N = in_sizes[0] / 128;
    const int E = in_sizes[1] / 2;
    const int Etot = E + N;

    // workspace carve-up (256B aligned regions)
    char* p = (char*)d_ws;
    auto alloc = [&](size_t bytes) {
        char* r = p;
        p += (bytes + 255) & ~(size_t)255;
        return r;
    };
    int*    cnt     = (int*)   alloc((size_t)N * 4);
    int*    row_ptr = (int*)   alloc((size_t)(N + 1) * 4);
    int*    rank    = (int*)   alloc((size_t)Etot * 4);
    int*    csr_src = (int*)   alloc((size_t)Etot * 4);
    int*    bsum    = (int*)   alloc((size_t)SCAN_NB * 4);
    int*    bbase   = (int*)   alloc((size_t)SCAN_NB * 4);
    __half* x16     = (__half*)alloc((size_t)N * 128 * 2);   // fp16 input x
    __half* bufA    = (__half*)alloc((size_t)N * 128 * 2);   // fp16 gemm out h
    __half* bufB    = (__half*)alloc((size_t)N * 128 * 2);   // fp16 agg out
    __half* bufC    = (__half*)alloc((size_t)N * 64 * 2);    // fp16 agg3 out (FC in)
    __half* wh1     = (__half*)alloc((size_t)8192 * 2);
    __half* wh2     = (__half*)alloc((size_t)8192 * 2);
    __half* wh3     = (__half*)alloc((size_t)8192 * 2);
    __half* fcwh    = (__half*)alloc((size_t)32768 * 2);
    float*  alpS    = (float*) alloc((size_t)N * 2 * 4);
    float*  alpD    = (float*) alloc((size_t)N * 2 * 4);
    (void)ws_size; (void)n_in; (void)out_size;

    // ---- fused prologue: cvtx + cvtw + count_rank in one launch ----
    hipMemsetAsync(cnt, 0, (size_t)N * 4, stream);
    const int n4 = N * 32;                      // float4 units in x
    const int XB = (n4 + 255) / 256;            // cvtx blocks (6250)
    const int WB = 224;                         // cvtw blocks
    const int CB = (Etot / 4 + 255) / 256 + 1;  // count_rank blocks
    fused_pre_kernel<<<XB + WB + CB, 256, 0, stream>>>(
        x, x16, n4, w1, w2, w3, fcw, wh1, wh2, wh3, fcwh,
        ei, E, N, cnt, rank, XB, WB);
    // parallel 3-phase scan
    scanA_kernel<<<SCAN_NB, 256, 0, stream>>>(cnt, N, bsum);
    scanB_kernel<<<1, 256, 0, stream>>>(bsum, bbase);
    scanC_kernel<<<SCAN_NB, 256, 0, stream>>>(cnt, N, Etot, bbase, row_ptr);
    scatter_kernel<<<CB, 256, 0, stream>>>(ei, E, N, row_ptr, rank, csr_src);

    int gb  = (N + 3) / 4;        // aggregate (PL1): 4 waves/block, 1 node/wave
    int gb2 = (2 * N + 3) / 4;    // aggregate2: 2 waves/node
    const int GB16 = 2048;        // fp16 gemm grids: 8 blocks/CU (16KB LDS, VGPR<=64)

    // ---- layer 1: 128 -> H2 x C32, concat ----
    gemm16_kernel<128, 64, 8, 1><<<dim3(GB16, 1), 256, 0, stream>>>(
        x16, wh1, bufA, as1, ad1, alpS, alpD, N, 64);
    aggregate_kernel<2, 32><<<gb, 256, 0, stream>>>(bufA, alpS, alpD, row_ptr, csr_src, b1, bufB, N);

    // ---- layer 2: 64 -> H2 x C64, concat (head-split aggregate) ----
    gemm16_kernel<64, 128, 8, 2><<<dim3(GB16, 1), 256, 0, stream>>>(
        bufB, wh2, bufA, as2, ad2, alpS, alpD, N, 128);
    aggregate2_kernel<<<gb2, 256, 0, stream>>>(bufA, alpS, alpD, row_ptr, csr_src, b2, bufB, N);

    // ---- layer 3: 128 -> H1 x C64, mean; output fp16 for FC ----
    gemm16_kernel<128, 64, 8, 3><<<dim3(GB16, 1), 256, 0, stream>>>(
        bufB, wh3, bufA, as3, ad3, alpS, alpD, N, 64);
    aggregate_kernel<1, 64><<<gb, 256, 0, stream>>>(bufA, alpS, alpD, row_ptr, csr_src, b3, bufC, N);

    // ---- FC: 64 -> 512 + relu, fp16 inputs, grid (512,4) ----
    fc16_kernel<8><<<dim3(512, 4), 256, 0, stream>>>(
        bufC, fcwh, fcb, out, N);
}

// Round 14
// 606.020 us; speedup vs baseline: 1.4550x; 1.1356x over previous
//
#include <hip/hip_runtime.h>
#include <hip/hip_fp16.h>
#include <math.h>

// ---------------------------------------------------------------------------
// GAT pipeline: 3x (GEMM16+alpha fused -> CSR segment-softmax aggregate) + FC
// R21: FC moved to MFMA (v_mfma_f32_16x16x32_f16). Vector-path FC proved
//      immovable at ~113us across 4 rounds (issue/residency/balance/LDS all
//      neutral) vs a ~25us write floor. Per wave: 64 cols' B-fragments in
//      REGISTERS (loaded once from transposed fp16 W built in prologue),
//      16-row tiles: 2 x-loads + 8 MFMA + coalesced stores. No LDS/barriers.
//      Layout risk bounded: A/B k-mapping cancels when both use the same
//      convention; C/D mapping is the HW-verified col=lane&15,
//      row=(lane>>4)*4+reg. Everything else = R20 (688us proven).
// ---------------------------------------------------------------------------

typedef _Float16 h2_t __attribute__((ext_vector_type(2)));
typedef _Float16 f16x8 __attribute__((ext_vector_type(8)));
typedef float f32x4 __attribute__((ext_vector_type(4)));

__device__ __forceinline__ h2_t as_h2(unsigned int u) {
    union { unsigned int u; h2_t h; } x; x.u = u; return x.h;
}

__device__ __forceinline__ float fdot2(h2_t a, h2_t b, float c) {
#if __has_builtin(__builtin_amdgcn_fdot2)
    return __builtin_amdgcn_fdot2(a, b, c, false);
#else
    return c + (float)a[0] * (float)b[0] + (float)a[1] * (float)b[1];
#endif
}

// ---------------------------------------------------------------------------
// Fused prologue: blocks [0,XB) convert x fp32->fp16 (float4-wide);
// blocks [XB,XB+WB) convert the 3 layer weight mats + TRANSPOSED fc weight;
// blocks [XB+WB,..) run count_rank. All three independent.
// ---------------------------------------------------------------------------
__global__ void fused_pre_kernel(
        const float* __restrict__ x, __half* __restrict__ xh, int n4,
        const float* __restrict__ w1, const float* __restrict__ w2,
        const float* __restrict__ w3, const float* __restrict__ fcw,
        __half* __restrict__ o1, __half* __restrict__ o2,
        __half* __restrict__ o3, __half* __restrict__ o4T,
        const int* __restrict__ ei, int E, int N,
        int* __restrict__ cnt, int* __restrict__ rank,
        int XB, int WB) {
    const int b = blockIdx.x;
    if (b < XB) {
        int i = b * 256 + threadIdx.x;
        if (i < n4) {
            float4 v = ((const float4*)x)[i];
            __half2 a, c;
            a.x = (__half)v.x; a.y = (__half)v.y;
            c.x = (__half)v.z; c.y = (__half)v.w;
            ((__half2*)xh)[2 * i]     = a;
            ((__half2*)xh)[2 * i + 1] = c;
        }
    } else if (b < XB + WB) {
        int i = (b - XB) * 256 + threadIdx.x;
        if (i < 8192)       o1[i]         = (__half)w1[i];
        else if (i < 16384) o2[i - 8192]  = (__half)w2[i - 8192];
        else if (i < 24576) o3[i - 16384] = (__half)w3[i - 16384];
        else if (i < 57344) {
            int j = i - 24576;              // fcw is [64][512] row-major
            int k = j >> 9, c = j & 511;
            o4T[c * 64 + k] = (__half)fcw[j];   // -> [512][64] transposed
        }
    } else {
        const int base = XB + WB;
        const int Etot = E + N;
        const int T = (gridDim.x - base) * 256;
        int e = (b - base) * 256 + threadIdx.x;
#pragma unroll 4
        for (int u = 0; u < 4; ++u, e += T) {
            if (e < Etot) {
                int dst = (e < E) ? ei[E + e] : (e - E);   // self-loops appended
                rank[e] = atomicAdd(&cnt[dst], 1);
            }
        }
    }
}

// ---------------------------------------------------------------------------
// Parallel scan, 3 phases. NB=256 blocks, chunk = ceil(N/NB) <= 256.
// ---------------------------------------------------------------------------
#define SCAN_NB 256

__global__ __launch_bounds__(256) void scanA_kernel(const int* __restrict__ cnt,
                                                    int N, int* __restrict__ bsum) {
    __shared__ int red[256];
    const int chunk = (N + SCAN_NB - 1) / SCAN_NB;
    const int lo = blockIdx.x * chunk;
    const int len = min(N - lo, chunk);
    int s = 0;
    for (int i = threadIdx.x; i < len; i += 256) s += cnt[lo + i];
    red[threadIdx.x] = s;
    __syncthreads();
    for (int off = 128; off >= 1; off >>= 1) {
        if (threadIdx.x < off) red[threadIdx.x] += red[threadIdx.x + off];
        __syncthreads();
    }
    if (threadIdx.x == 0) bsum[blockIdx.x] = red[0];
}

__global__ __launch_bounds__(256) void scanB_kernel(int* __restrict__ bsum,
                                                    int* __restrict__ bbase) {
    __shared__ int s[256];
    int v = bsum[threadIdx.x];
    s[threadIdx.x] = v;
    __syncthreads();
    for (int off = 1; off < 256; off <<= 1) {
        int t = (threadIdx.x >= off) ? s[threadIdx.x - off] : 0;
        __syncthreads();
        s[threadIdx.x] += t;
        __syncthreads();
    }
    bbase[threadIdx.x] = s[threadIdx.x] - v;   // exclusive
}

__global__ __launch_bounds__(256) void scanC_kernel(const int* __restrict__ cnt,
                                                    int N, int Etot,
                                                    const int* __restrict__ bbase,
                                                    int* __restrict__ row_ptr) {
    __shared__ int s[256];
    const int chunk = (N + SCAN_NB - 1) / SCAN_NB;
    const int lo = blockIdx.x * chunk;
    const int len = min(N - lo, chunk);
    const int t = threadIdx.x;
    int v = (t < len) ? cnt[lo + t] : 0;
    s[t] = v;
    __syncthreads();
    for (int off = 1; off < 256; off <<= 1) {
        int u = (t >= off) ? s[t - off] : 0;
        __syncthreads();
        s[t] += u;
        __syncthreads();
    }
    if (t < len) row_ptr[lo + t] = bbase[blockIdx.x] + s[t] - v;
    if (blockIdx.x == 0 && t == 0) row_ptr[N] = Etot;
}

// pass 3: pos = row_ptr[dst] + rank[e]; atomic-free scattered store.
__global__ void scatter_kernel(const int* __restrict__ ei, int E, int N,
                               const int* __restrict__ row_ptr,
                               const int* __restrict__ rank,
                               int* __restrict__ csr_src) {
    const int Etot = E + N;
    const int T = gridDim.x * blockDim.x;
    int e = blockIdx.x * blockDim.x + threadIdx.x;
#pragma unroll 4
    for (int u = 0; u < 4; ++u, e += T) {
        if (e < Etot) {
            int src, dst;
            if (e < E) { src = ei[e]; dst = ei[E + e]; }
            else       { src = e - E; dst = e - E; }
            csr_src[row_ptr[dst] + rank[e]] = src;
        }
    }
}

// ---------------------------------------------------------------------------
// Layer GEMM, fp16 in/W, fp32 acc via fdot2, fp16 out, fused alpha from the
// fp32 acc (R18-proven). 256 thr / 4 waves, W tile 16KB LDS (uint2-packed),
// RB=8 rows/wave, distance-1 ping-pong, unroll 2, grid 2048 = 8 blocks/CU.
// ALPHA: 1=(H2,C32: segmented 32-lane)  2=(H2,C64,PL2)  3=(H1,C64)
// ---------------------------------------------------------------------------
template <int K, int CHUNK, int RB, int ALPHA>
__global__ __launch_bounds__(256) void gemm16_kernel(
        const __half* __restrict__ in,
        const __half* __restrict__ Wh,
        __half* __restrict__ out,
        const float* __restrict__ a_src,
        const float* __restrict__ a_dst,
        float* __restrict__ alpS,
        float* __restrict__ alpD,
        int N, int M) {
    constexpr int PL = CHUNK / 64;
    constexpr int K4 = K / 4;
    __shared__ uint2 wlds[K4 * CHUNK];   // = K*CHUNK*2 B = 16 KB
    const unsigned short* wsrc = (const unsigned short*)Wh;
    for (int idx = threadIdx.x; idx < K4 * CHUNK; idx += 256) {
        int k4 = idx / CHUNK, c = idx % CHUNK;
        const unsigned short* wp = wsrc + (size_t)(4 * k4) * M + c;
        uint2 v;
        v.x = (unsigned int)wp[0]     | ((unsigned int)wp[M] << 16);
        v.y = (unsigned int)wp[2 * M] | ((unsigned int)wp[3 * M] << 16);
        wlds[idx] = v;
    }
    __syncthreads();

    const int wid  = threadIdx.x >> 6;
    const int lane = threadIdx.x & 63;

    float aSv[PL], aDv[PL];
#pragma unroll
    for (int j = 0; j < PL; ++j) {
        aSv[j] = a_src[lane + 64 * j];
        aDv[j] = a_dst[lane + 64 * j];
    }

    const int groups = (N + RB - 1) / RB;
    for (int g = blockIdx.x * 4 + wid; g < groups; g += gridDim.x * 4) {
        const int n0 = g * RB;
        const bool full = (n0 + RB <= N);

        float acc[RB][PL];
#pragma unroll
        for (int r = 0; r < RB; ++r)
#pragma unroll
            for (int j = 0; j < PL; ++j) acc[r][j] = 0.0f;

        const uint2* xp = (const uint2*)(in + (size_t)n0 * K);

        if (full) {
            uint2 xv[RB], xn[RB];
#pragma unroll
            for (int r = 0; r < RB; ++r) xv[r] = xp[r * K4];
#pragma unroll 2
            for (int k4 = 0; k4 < K4; ++k4) {
                if (k4 + 1 < K4) {
#pragma unroll
                    for (int r = 0; r < RB; ++r)
                        xn[r] = xp[r * K4 + k4 + 1];
                }
#pragma unroll
                for (int j = 0; j < PL; ++j) {
                    uint2 wv = wlds[k4 * CHUNK + lane + 64 * j];
#pragma unroll
                    for (int r = 0; r < RB; ++r) {
                        acc[r][j] = fdot2(as_h2(xv[r].x), as_h2(wv.x), acc[r][j]);
                        acc[r][j] = fdot2(as_h2(xv[r].y), as_h2(wv.y), acc[r][j]);
                    }
                }
                if (k4 + 1 < K4) {
#pragma unroll
                    for (int r = 0; r < RB; ++r) xv[r] = xn[r];
                }
            }
        } else {
#pragma unroll 1
            for (int k4 = 0; k4 < K4; ++k4) {
#pragma unroll 1
                for (int r = 0; r < RB; ++r) {
                    if (n0 + r >= N) break;
                    uint2 xr = xp[(size_t)r * K4 + k4];
#pragma unroll
                    for (int j = 0; j < PL; ++j) {
                        uint2 wv = wlds[k4 * CHUNK + lane + 64 * j];
                        acc[r][j] = fdot2(as_h2(xr.x), as_h2(wv.x), acc[r][j]);
                        acc[r][j] = fdot2(as_h2(xr.y), as_h2(wv.y), acc[r][j]);
                    }
                }
            }
        }

#pragma unroll
        for (int r = 0; r < RB; ++r) {
            if (!full && n0 + r >= N) break;
            const int n = n0 + r;
#pragma unroll
            for (int j = 0; j < PL; ++j)
                out[(size_t)n * M + lane + 64 * j] = (__half)acc[r][j];

            float ps[PL], pd[PL];
#pragma unroll
            for (int j = 0; j < PL; ++j) { ps[j] = acc[r][j] * aSv[j]; pd[j] = acc[r][j] * aDv[j]; }
            const int m0 = (ALPHA == 1) ? 16 : 32;
            for (int mm = m0; mm >= 1; mm >>= 1) {
#pragma unroll
                for (int j = 0; j < PL; ++j) {
                    ps[j] += __shfl_xor(ps[j], mm, 64);
                    pd[j] += __shfl_xor(pd[j], mm, 64);
                }
            }
            if (ALPHA == 1) {
                if ((lane & 31) == 0) {
                    int idx = n * 2 + (lane >> 5);
                    alpS[idx] = ps[0]; alpD[idx] = pd[0];
                }
            } else if (ALPHA == 2) {
                if (lane == 0) {
#pragma unroll
                    for (int j = 0; j < PL; ++j) {
                        alpS[n * 2 + j] = ps[j]; alpD[n * 2 + j] = pd[j];
                    }
                }
            } else {
                if (lane == 0) { alpS[n] = ps[0]; alpD[n] = pd[0]; }
            }
        }
    }
}

// ---------------------------------------------------------------------------
// FC via MFMA: out[n][c] = relu(sum_k x[n][k] * W[k][c] + b[c]).
// Wave owns 64 cols (4 col-tiles x 16); B fragments in registers from
// WT[512][64] (transposed fp16 W). Per 16-row tile: 2 x-loads (f16x8),
// 8x mfma_f32_16x16x32_f16, bias+relu, stores. A/B both use the standard
// k=(lane>>4)*8+i convention (any HW k-permutation cancels); C/D layout
// col=lane&15, row=(lane>>4)*4+reg (HW-verified).
// Grid (ceil(NT/5), 2): 5 row-tiles/block; NT=3125 exact at N=50000.
// ---------------------------------------------------------------------------
__global__ __launch_bounds__(256) void fcmfma_kernel(
        const __half* __restrict__ in,    // [N][64] fp16
        const __half* __restrict__ WT,    // [512][64] fp16 (transposed)
        const float* __restrict__ bias,   // [512]
        float* __restrict__ out,          // [N][512]
        int N, int NT) {
    const int wid  = threadIdx.x >> 6;
    const int lane = threadIdx.x & 63;
    const int cb = blockIdx.y * 256 + wid * 64;
    const int r  = lane & 15;     // A-row / B-col / D-col within tile
    const int kg = lane >> 4;     // k-group

    // B fragments: 4 col-tiles x 2 k-frags, in registers (one-time load)
    f16x8 bfrag[4][2];
#pragma unroll
    for (int t = 0; t < 4; ++t)
#pragma unroll
        for (int kf = 0; kf < 2; ++kf)
            bfrag[t][kf] = *(const f16x8*)(WT + (size_t)(cb + t * 16 + r) * 64 + kf * 32 + kg * 8);
    float bs[4];
#pragma unroll
    for (int t = 0; t < 4; ++t) bs[t] = bias[cb + t * 16 + r];

    const int rt0 = blockIdx.x * 5;
#pragma unroll 1
    for (int q = 0; q < 5; ++q) {
        const int rt = rt0 + q;
        if (rt >= NT) break;
        const int n0 = rt * 16;
        // A fragments: row n0+r, k = kf*32 + kg*8 + i  (same convention as B)
        f16x8 a0 = *(const f16x8*)(in + (size_t)(n0 + r) * 64 + kg * 8);
        f16x8 a1 = *(const f16x8*)(in + (size_t)(n0 + r) * 64 + 32 + kg * 8);
#pragma unroll
        for (int t = 0; t < 4; ++t) {
            f32x4 acc = {0.0f, 0.0f, 0.0f, 0.0f};
            acc = __builtin_amdgcn_mfma_f32_16x16x32_f16(a0, bfrag[t][0], acc, 0, 0, 0);
            acc = __builtin_amdgcn_mfma_f32_16x16x32_f16(a1, bfrag[t][1], acc, 0, 0, 0);
#pragma unroll
            for (int i = 0; i < 4; ++i) {
                int grow = n0 + kg * 4 + i;
                if (grow < N)
                    out[(size_t)grow * 512 + cb + t * 16 + r] = fmaxf(acc[i] + bs[t], 0.0f);
            }
        }
    }
}

// ---------------------------------------------------------------------------
// Aggregate (PL1 variants, layers 1+3): one wave per dst node, 64-edge
// chunks, two-phase; h gathered as FP16; softmax/accumulate fp32; fp16 out.
// ---------------------------------------------------------------------------
template <int H, int C>
__global__ __launch_bounds__(256) void aggregate_kernel(
        const __half* __restrict__ h,
        const float* __restrict__ alpha_s,
        const float* __restrict__ alpha_d,
        const int* __restrict__ row_ptr,
        const int* __restrict__ csr_src,
        const float* __restrict__ bias,
        __half* __restrict__ out, int N) {
    constexpr int M = H * C;
    __shared__ int   ss[4][64];
    __shared__ float sp[4][128];
    const int wid  = threadIdx.x >> 6;
    const int lane = threadIdx.x & 63;
    const int n = blockIdx.x * 4 + wid;
    if (n >= N) return;

    const int lo = row_ptr[n], hi = row_ptr[n + 1];
    const int myhead = (H == 2) ? (lane / C) : 0;

    float adv[H];
#pragma unroll
    for (int t = 0; t < H; ++t) adv[t] = alpha_d[n * H + t];

    float m[H], den[H], acc = 0.0f;
#pragma unroll
    for (int t = 0; t < H; ++t) { m[t] = -INFINITY; den[t] = 0.0f; }

    for (int e0 = lo; e0 < hi; e0 += 64) {
        const int idx = e0 + lane;
        const bool valid = idx < hi;
        const int src_l = csr_src[valid ? idx : hi - 1];

        // ---- phase A: lane-parallel logits ----
        float lg[H];
        if (H == 2) {
            float2 as = ((const float2*)alpha_s)[src_l];
            lg[0] = as.x + adv[0];
            lg[1] = as.y + adv[1];
        } else {
            lg[0] = alpha_s[src_l] + adv[0];
        }
#pragma unroll
        for (int t = 0; t < H; ++t) {
            float v = lg[t];
            v = v > 0.0f ? v : 0.2f * v;
            lg[t] = valid ? v : -INFINITY;
        }
        float cm[H];
#pragma unroll
        for (int t = 0; t < H; ++t) cm[t] = lg[t];
        for (int mm = 32; mm >= 1; mm >>= 1) {
#pragma unroll
            for (int t = 0; t < H; ++t)
                cm[t] = fmaxf(cm[t], __shfl_xor(cm[t], mm, 64));
        }
        float sc[H];
#pragma unroll
        for (int t = 0; t < H; ++t) {
            float mnew = fmaxf(m[t], cm[t]);
            sc[t] = __expf(m[t] - mnew);
            den[t] *= sc[t];
            m[t] = mnew;
        }
        acc *= (H == 1) ? sc[0] : (myhead == 0 ? sc[0] : sc[1]);

        float p[H], dsum[H];
#pragma unroll
        for (int t = 0; t < H; ++t) { p[t] = __expf(lg[t] - m[t]); dsum[t] = p[t]; }
        for (int mm = 32; mm >= 1; mm >>= 1) {
#pragma unroll
            for (int t = 0; t < H; ++t)
                dsum[t] += __shfl_xor(dsum[t], mm, 64);
        }
#pragma unroll
        for (int t = 0; t < H; ++t) den[t] += dsum[t];

        ss[wid][lane] = src_l;
        if (H == 2) ((float2*)sp[wid])[lane] = make_float2(p[0], p[1]);
        else        sp[wid][lane] = p[0];

        // ---- phase B: per-edge broadcast accumulate, 8-wide batch ----
        int nu = hi - e0; if (nu > 64) nu = 64;
        int u = 0;
#pragma unroll 1
        for (; u + 8 <= nu; u += 8) {
            int su[8];
#pragma unroll
            for (int t = 0; t < 8; ++t)
                su[t] = __builtin_amdgcn_readfirstlane(ss[wid][u + t]);
            float hv[8];
#pragma unroll
            for (int t = 0; t < 8; ++t)
                hv[t] = __half2float(h[(size_t)su[t] * M + lane]);
            if (H == 2) {
                const float2* pb = (const float2*)sp[wid];
#pragma unroll
                for (int t = 0; t < 8; ++t) {
                    float2 q = pb[u + t];
                    acc += (myhead == 0 ? q.x : q.y) * hv[t];
                }
            } else {
#pragma unroll
                for (int t = 0; t < 8; ++t)
                    acc += sp[wid][u + t] * hv[t];
            }
        }
#pragma unroll 1
        for (; u < nu; ++u) {
            int su = __builtin_amdgcn_readfirstlane(ss[wid][u]);
            float hv = __half2float(h[(size_t)su * M + lane]);
            if (H == 2) {
                float2 q = ((const float2*)sp[wid])[u];
                acc += (myhead == 0 ? q.x : q.y) * hv;
            } else {
                acc += sp[wid][u] * hv;
            }
        }
    }

    float dv = (H == 1) ? den[0] : (myhead == 0 ? den[0] : den[1]);
    float v = acc / dv + bias[lane];
    out[(size_t)n * M + lane] = (__half)fmaxf(v, 0.0f);
}

// ---------------------------------------------------------------------------
// Layer-2 aggregate, HEAD-SPLIT: 2 waves per node; h fp16 in, fp16 out.
// ---------------------------------------------------------------------------
__global__ __launch_bounds__(256) void aggregate2_kernel(
        const __half* __restrict__ h,       // [N][128] fp16
        const float* __restrict__ alpha_s,  // [N][2]
        const float* __restrict__ alpha_d,  // [N][2]
        const int* __restrict__ row_ptr,
        const int* __restrict__ csr_src,
        const float* __restrict__ bias,     // [128]
        __half* __restrict__ out, int N) {
    __shared__ int   ss[4][64];
    __shared__ float sp[4][64];
    const int wid  = threadIdx.x >> 6;
    const int lane = threadIdx.x & 63;
    const int gw   = blockIdx.x * 4 + wid;
    const int n    = gw >> 1;
    const int hd   = gw & 1;
    if (n >= N) return;

    const int lo = row_ptr[n], hi = row_ptr[n + 1];
    const float adv = alpha_d[n * 2 + hd];

    float m = -INFINITY, den = 0.0f, acc = 0.0f;

    for (int e0 = lo; e0 < hi; e0 += 64) {
        const int idx = e0 + lane;
        const bool valid = idx < hi;
        const int src_l = csr_src[valid ? idx : hi - 1];

        float lg = alpha_s[src_l * 2 + hd] + adv;
        lg = lg > 0.0f ? lg : 0.2f * lg;
        if (!valid) lg = -INFINITY;

        float cm = lg;
        for (int mm = 32; mm >= 1; mm >>= 1)
            cm = fmaxf(cm, __shfl_xor(cm, mm, 64));

        float mnew = fmaxf(m, cm);
        float sc = __expf(m - mnew);
        den *= sc; acc *= sc; m = mnew;

        float p = __expf(lg - m), ds = p;
        for (int mm = 32; mm >= 1; mm >>= 1)
            ds += __shfl_xor(ds, mm, 64);
        den += ds;

        ss[wid][lane] = src_l;
        sp[wid][lane] = p;

        int nu = hi - e0; if (nu > 64) nu = 64;
        int u = 0;
#pragma unroll 1
        for (; u + 8 <= nu; u += 8) {
            int su[8];
#pragma unroll
            for (int t = 0; t < 8; ++t)
                su[t] = __builtin_amdgcn_readfirstlane(ss[wid][u + t]);
            float hv[8];
#pragma unroll
            for (int t = 0; t < 8; ++t)
                hv[t] = __half2float(h[(size_t)su[t] * 128 + hd * 64 + lane]);
#pragma unroll
            for (int t = 0; t < 8; ++t)
                acc += sp[wid][u + t] * hv[t];
        }
#pragma unroll 1
        for (; u < nu; ++u) {
            int su = __builtin_amdgcn_readfirstlane(ss[wid][u]);
            acc += sp[wid][u] * __half2float(h[(size_t)su * 128 + hd * 64 + lane]);
        }
    }

    float v = acc / den + bias[hd * 64 + lane];
    out[(size_t)n * 128 + hd * 64 + lane] = (__half)fmaxf(v, 0.0f);
}

// ---------------------------------------------------------------------------

extern "C" void kernel_launch(void* const* d_in, const int* in_sizes, int n_in,
                              void* d_out, int out_size, void* d_ws, size_t ws_size,
                              hipStream_t stream) {
    const float* x   = (const float*)d_in[0];
    const int*   ei  = (const int*)  d_in[1];
    const float* w1  = (const float*)d_in[2];
    const float* as1 = (const float*)d_in[3];
    const float* ad1 = (const float*)d_in[4];
    const float* b1  = (const float*)d_in[5];
    const float* w2  = (const float*)d_in[6];
    const float* as2 = (const float*)d_in[7];
    const float* ad2 = (const float*)d_in[8];
    const float* b2  = (const float*)d_in[9];
    const float* w3  = (const float*)d_in[10];
    const float* as3 = (const float*)d_in[11];
    const float* ad3 = (const float*)d_in[12];
    const float* b3  = (const float*)d_in[13];
    const float* fcw = (const float*)d_in[14];
    const float* fcb = (const float*)d_in[15];
    float* out = (float*)d_out;

    const int N = in_sizes[0] / 128;
    const int E = in_sizes[1] / 2;
    const int Etot = E + N;

    // workspace carve-up (256B aligned regions)
    char* p = (char*)d_ws;
    auto alloc = [&](size_t bytes) {
        char* r = p;
        p += (bytes + 255) & ~(size_t)255;
        return r;
    };
    int*    cnt     = (int*)   alloc((size_t)N * 4);
    int*    row_ptr = (int*)   alloc((size_t)(N + 1) * 4);
    int*    rank    = (int*)   alloc((size_t)Etot * 4);
    int*    csr_src = (int*)   alloc((size_t)Etot * 4);
    int*    bsum    = (int*)   alloc((size_t)SCAN_NB * 4);
    int*    bbase   = (int*)   alloc((size_t)SCAN_NB * 4);
    __half* x16     = (__half*)alloc((size_t)N * 128 * 2);   // fp16 input x
    __half* bufA    = (__half*)alloc((size_t)N * 128 * 2);   // fp16 gemm out h
    __half* bufB    = (__half*)alloc((size_t)N * 128 * 2);   // fp16 agg out
    __half* bufC    = (__half*)alloc((size_t)(N + 16) * 64 * 2); // fp16 agg3 out (FC in, +pad for OOB A-loads)
    __half* wh1     = (__half*)alloc((size_t)8192 * 2);
    __half* wh2     = (__half*)alloc((size_t)8192 * 2);
    __half* wh3     = (__half*)alloc((size_t)8192 * 2);
    __half* fcwT    = (__half*)alloc((size_t)32768 * 2);     // [512][64] transposed
    float*  alpS    = (float*) alloc((size_t)N * 2 * 4);
    float*  alpD    = (float*) alloc((size_t)N * 2 * 4);
    (void)ws_size; (void)n_in; (void)out_size;

    // ---- fused prologue: cvtx + cvtw(+transpose) + count_rank ----
    hipMemsetAsync(cnt, 0, (size_t)N * 4, stream);
    const int n4 = N * 32;                      // float4 units in x
    const int XB = (n4 + 255) / 256;            // cvtx blocks
    const int WB = 224;                         // cvtw blocks
    const int CB = (Etot / 4 + 255) / 256 + 1;  // count_rank blocks
    fused_pre_kernel<<<XB + WB + CB, 256, 0, stream>>>(
        x, x16, n4, w1, w2, w3, fcw, wh1, wh2, wh3, fcwT,
        ei, E, N, cnt, rank, XB, WB);
    // parallel 3-phase scan
    scanA_kernel<<<SCAN_NB, 256, 0, stream>>>(cnt, N, bsum);
    scanB_kernel<<<1, 256, 0, stream>>>(bsum, bbase);
    scanC_kernel<<<SCAN_NB, 256, 0, stream>>>(cnt, N, Etot, bbase, row_ptr);
    scatter_kernel<<<CB, 256, 0, stream>>>(ei, E, N, row_ptr, rank, csr_src);

    int gb  = (N + 3) / 4;        // aggregate (PL1): 4 waves/block, 1 node/wave
    int gb2 = (2 * N + 3) / 4;    // aggregate2: 2 waves/node
    const int GB16 = 2048;        // fp16 gemm grids: 8 blocks/CU (16KB LDS, VGPR<=64)

    // ---- layer 1: 128 -> H2 x C32, concat ----
    gemm16_kernel<128, 64, 8, 1><<<dim3(GB16, 1), 256, 0, stream>>>(
        x16, wh1, bufA, as1, ad1, alpS, alpD, N, 64);
    aggregate_kernel<2, 32><<<gb, 256, 0, stream>>>(bufA, alpS, alpD, row_ptr, csr_src, b1, bufB, N);

    // ---- layer 2: 64 -> H2 x C64, concat (head-split aggregate) ----
    gemm16_kernel<64, 128, 8, 2><<<dim3(GB16, 1), 256, 0, stream>>>(
        bufB, wh2, bufA, as2, ad2, alpS, alpD, N, 128);
    aggregate2_kernel<<<gb2, 256, 0, stream>>>(bufA, alpS, alpD, row_ptr, csr_src, b2, bufB, N);

    // ---- layer 3: 128 -> H1 x C64, mean; output fp16 for FC ----
    gemm16_kernel<128, 64, 8, 3><<<dim3(GB16, 1), 256, 0, stream>>>(
        bufB, wh3, bufA, as3, ad3, alpS, alpD, N, 64);
    aggregate_kernel<1, 64><<<gb, 256, 0, stream>>>(bufA, alpS, alpD, row_ptr, csr_src, b3, bufC, N);

    // ---- FC: 64 -> 512 + relu via MFMA, B-fragments in registers ----
    const int NT = (N + 15) / 16;               // 16-row tiles (3125 exact)
    const int GX = (NT + 4) / 5;                // 5 tiles/block (625)
    fcmfma_kernel<<<dim3(GX, 2), 256, 0, stream>>>(
        bufC, fcwT, fcb, out, N, NT);
}

// Round 15
// 584.662 us; speedup vs baseline: 1.5082x; 1.0365x over previous
//
#include <hip/hip_runtime.h>
#include <hip/hip_fp16.h>
#include <math.h>

// ---------------------------------------------------------------------------
// GAT pipeline: 3x (GEMM16+alpha fused -> CSR segment-softmax aggregate) + FC
// R22: hide the atomic wall. R21 counters: fused_pre 87us, VALUBusy 0.9%,
//      WRITE 69MB (=20MB payload + ~53MB of 32B atomic transactions) ->
//      count_rank is device-atomic-RATE-bound (1.65M cross-XCD atomics).
//      Can't cut E atomics; hide them instead: count_rank fused INTO gemm1's
//      dispatch (1024 gemm + 1024 count blocks = 2048 = exact residency cap,
//      ~4+4 per CU -> atomic stalls overlap fdot2 compute). cvt (x16+weights)
//      becomes its own small streaming launch. All else = R21 (606us proven).
// ---------------------------------------------------------------------------

typedef _Float16 h2_t __attribute__((ext_vector_type(2)));
typedef _Float16 f16x8 __attribute__((ext_vector_type(8)));
typedef float f32x4 __attribute__((ext_vector_type(4)));

__device__ __forceinline__ h2_t as_h2(unsigned int u) {
    union { unsigned int u; h2_t h; } x; x.u = u; return x.h;
}

__device__ __forceinline__ float fdot2(h2_t a, h2_t b, float c) {
#if __has_builtin(__builtin_amdgcn_fdot2)
    return __builtin_amdgcn_fdot2(a, b, c, false);
#else
    return c + (float)a[0] * (float)b[0] + (float)a[1] * (float)b[1];
#endif
}

// ---------------------------------------------------------------------------
// cvt: blocks [0,XB) convert x fp32->fp16; blocks [XB,XB+WB) convert the 3
// layer weights + transposed fc weight. Pure streaming, ~15us.
// ---------------------------------------------------------------------------
__global__ void cvt_kernel(
        const float* __restrict__ x, __half* __restrict__ xh, int n4,
        const float* __restrict__ w1, const float* __restrict__ w2,
        const float* __restrict__ w3, const float* __restrict__ fcw,
        __half* __restrict__ o1, __half* __restrict__ o2,
        __half* __restrict__ o3, __half* __restrict__ o4T,
        int XB) {
    const int b = blockIdx.x;
    if (b < XB) {
        int i = b * 256 + threadIdx.x;
        if (i < n4) {
            float4 v = ((const float4*)x)[i];
            __half2 a, c;
            a.x = (__half)v.x; a.y = (__half)v.y;
            c.x = (__half)v.z; c.y = (__half)v.w;
            ((__half2*)xh)[2 * i]     = a;
            ((__half2*)xh)[2 * i + 1] = c;
        }
    } else {
        int i = (b - XB) * 256 + threadIdx.x;
        if (i < 8192)       o1[i]         = (__half)w1[i];
        else if (i < 16384) o2[i - 8192]  = (__half)w2[i - 8192];
        else if (i < 24576) o3[i - 16384] = (__half)w3[i - 16384];
        else if (i < 57344) {
            int j = i - 24576;              // fcw is [64][512] row-major
            int k = j >> 9, c = j & 511;
            o4T[c * 64 + k] = (__half)fcw[j];   // -> [512][64] transposed
        }
    }
}

// ---------------------------------------------------------------------------
// Parallel scan, 3 phases. NB=256 blocks, chunk = ceil(N/NB) <= 256.
// ---------------------------------------------------------------------------
#define SCAN_NB 256

__global__ __launch_bounds__(256) void scanA_kernel(const int* __restrict__ cnt,
                                                    int N, int* __restrict__ bsum) {
    __shared__ int red[256];
    const int chunk = (N + SCAN_NB - 1) / SCAN_NB;
    const int lo = blockIdx.x * chunk;
    const int len = min(N - lo, chunk);
    int s = 0;
    for (int i = threadIdx.x; i < len; i += 256) s += cnt[lo + i];
    red[threadIdx.x] = s;
    __syncthreads();
    for (int off = 128; off >= 1; off >>= 1) {
        if (threadIdx.x < off) red[threadIdx.x] += red[threadIdx.x + off];
        __syncthreads();
    }
    if (threadIdx.x == 0) bsum[blockIdx.x] = red[0];
}

__global__ __launch_bounds__(256) void scanB_kernel(int* __restrict__ bsum,
                                                    int* __restrict__ bbase) {
    __shared__ int s[256];
    int v = bsum[threadIdx.x];
    s[threadIdx.x] = v;
    __syncthreads();
    for (int off = 1; off < 256; off <<= 1) {
        int t = (threadIdx.x >= off) ? s[threadIdx.x - off] : 0;
        __syncthreads();
        s[threadIdx.x] += t;
        __syncthreads();
    }
    bbase[threadIdx.x] = s[threadIdx.x] - v;   // exclusive
}

__global__ __launch_bounds__(256) void scanC_kernel(const int* __restrict__ cnt,
                                                    int N, int Etot,
                                                    const int* __restrict__ bbase,
                                                    int* __restrict__ row_ptr) {
    __shared__ int s[256];
    const int chunk = (N + SCAN_NB - 1) / SCAN_NB;
    const int lo = blockIdx.x * chunk;
    const int len = min(N - lo, chunk);
    const int t = threadIdx.x;
    int v = (t < len) ? cnt[lo + t] : 0;
    s[t] = v;
    __syncthreads();
    for (int off = 1; off < 256; off <<= 1) {
        int u = (t >= off) ? s[t - off] : 0;
        __syncthreads();
        s[t] += u;
        __syncthreads();
    }
    if (t < len) row_ptr[lo + t] = bbase[blockIdx.x] + s[t] - v;
    if (blockIdx.x == 0 && t == 0) row_ptr[N] = Etot;
}

// pass 3: pos = row_ptr[dst] + rank[e]; atomic-free scattered store.
__global__ void scatter_kernel(const int* __restrict__ ei, int E, int N,
                               const int* __restrict__ row_ptr,
                               const int* __restrict__ rank,
                               int* __restrict__ csr_src) {
    const int Etot = E + N;
    const int T = gridDim.x * blockDim.x;
    int e = blockIdx.x * blockDim.x + threadIdx.x;
#pragma unroll 4
    for (int u = 0; u < 4; ++u, e += T) {
        if (e < Etot) {
            int src, dst;
            if (e < E) { src = ei[e]; dst = ei[E + e]; }
            else       { src = e - E; dst = e - E; }
            csr_src[row_ptr[dst] + rank[e]] = src;
        }
    }
}

// ---------------------------------------------------------------------------
// Layer GEMM, fp16 in/W, fp32 acc via fdot2, fp16 out, fused alpha (R18).
// COUNT variant (layer 1): blocks [GGEMM, gridDim) run count_rank
// (grid-stride over all Etot edges) concurrently with the gemm blocks --
// atomic stalls hide under fdot2 compute on co-resident CUs.
// ALPHA: 1=(H2,C32: segmented 32-lane)  2=(H2,C64,PL2)  3=(H1,C64)
// ---------------------------------------------------------------------------
template <int K, int CHUNK, int RB, int ALPHA, bool COUNT>
__global__ __launch_bounds__(256) void gemm16_kernel(
        const __half* __restrict__ in,
        const __half* __restrict__ Wh,
        __half* __restrict__ out,
        const float* __restrict__ a_src,
        const float* __restrict__ a_dst,
        float* __restrict__ alpS,
        float* __restrict__ alpD,
        int N, int M,
        const int* __restrict__ ei, int E,
        int* __restrict__ cnt, int* __restrict__ rank,
        int GGEMM) {
    constexpr int PL = CHUNK / 64;
    constexpr int K4 = K / 4;
    __shared__ uint2 wlds[K4 * CHUNK];   // 16 KB

    if (COUNT && blockIdx.x >= GGEMM) {
        // ---- count_rank: cnt[dst]++ + per-edge arrival rank ----
        const int Etot = E + N;
        const int T = (gridDim.x - GGEMM) * 256;
        int e = (blockIdx.x - GGEMM) * 256 + threadIdx.x;
#pragma unroll 1
        for (; e < Etot; e += T) {
            int dst = (e < E) ? ei[E + e] : (e - E);   // self-loops appended
            rank[e] = atomicAdd(&cnt[dst], 1);
        }
        return;
    }
    const int GSTRIDE = COUNT ? GGEMM : gridDim.x;

    const unsigned short* wsrc = (const unsigned short*)Wh;
    for (int idx = threadIdx.x; idx < K4 * CHUNK; idx += 256) {
        int k4 = idx / CHUNK, c = idx % CHUNK;
        const unsigned short* wp = wsrc + (size_t)(4 * k4) * M + c;
        uint2 v;
        v.x = (unsigned int)wp[0]     | ((unsigned int)wp[M] << 16);
        v.y = (unsigned int)wp[2 * M] | ((unsigned int)wp[3 * M] << 16);
        wlds[idx] = v;
    }
    __syncthreads();

    const int wid  = threadIdx.x >> 6;
    const int lane = threadIdx.x & 63;

    float aSv[PL], aDv[PL];
#pragma unroll
    for (int j = 0; j < PL; ++j) {
        aSv[j] = a_src[lane + 64 * j];
        aDv[j] = a_dst[lane + 64 * j];
    }

    const int groups = (N + RB - 1) / RB;
    for (int g = blockIdx.x * 4 + wid; g < groups; g += GSTRIDE * 4) {
        const int n0 = g * RB;
        const bool full = (n0 + RB <= N);

        float acc[RB][PL];
#pragma unroll
        for (int r = 0; r < RB; ++r)
#pragma unroll
            for (int j = 0; j < PL; ++j) acc[r][j] = 0.0f;

        const uint2* xp = (const uint2*)(in + (size_t)n0 * K);

        if (full) {
            uint2 xv[RB], xn[RB];
#pragma unroll
            for (int r = 0; r < RB; ++r) xv[r] = xp[r * K4];
#pragma unroll 2
            for (int k4 = 0; k4 < K4; ++k4) {
                if (k4 + 1 < K4) {
#pragma unroll
                    for (int r = 0; r < RB; ++r)
                        xn[r] = xp[r * K4 + k4 + 1];
                }
#pragma unroll
                for (int j = 0; j < PL; ++j) {
                    uint2 wv = wlds[k4 * CHUNK + lane + 64 * j];
#pragma unroll
                    for (int r = 0; r < RB; ++r) {
                        acc[r][j] = fdot2(as_h2(xv[r].x), as_h2(wv.x), acc[r][j]);
                        acc[r][j] = fdot2(as_h2(xv[r].y), as_h2(wv.y), acc[r][j]);
                    }
                }
                if (k4 + 1 < K4) {
#pragma unroll
                    for (int r = 0; r < RB; ++r) xv[r] = xn[r];
                }
            }
        } else {
#pragma unroll 1
            for (int k4 = 0; k4 < K4; ++k4) {
#pragma unroll 1
                for (int r = 0; r < RB; ++r) {
                    if (n0 + r >= N) break;
                    uint2 xr = xp[(size_t)r * K4 + k4];
#pragma unroll
                    for (int j = 0; j < PL; ++j) {
                        uint2 wv = wlds[k4 * CHUNK + lane + 64 * j];
                        acc[r][j] = fdot2(as_h2(xr.x), as_h2(wv.x), acc[r][j]);
                        acc[r][j] = fdot2(as_h2(xr.y), as_h2(wv.y), acc[r][j]);
                    }
                }
            }
        }

#pragma unroll
        for (int r = 0; r < RB; ++r) {
            if (!full && n0 + r >= N) break;
            const int n = n0 + r;
#pragma unroll
            for (int j = 0; j < PL; ++j)
                out[(size_t)n * M + lane + 64 * j] = (__half)acc[r][j];

            float ps[PL], pd[PL];
#pragma unroll
            for (int j = 0; j < PL; ++j) { ps[j] = acc[r][j] * aSv[j]; pd[j] = acc[r][j] * aDv[j]; }
            const int m0 = (ALPHA == 1) ? 16 : 32;
            for (int mm = m0; mm >= 1; mm >>= 1) {
#pragma unroll
                for (int j = 0; j < PL; ++j) {
                    ps[j] += __shfl_xor(ps[j], mm, 64);
                    pd[j] += __shfl_xor(pd[j], mm, 64);
                }
            }
            if (ALPHA == 1) {
                if ((lane & 31) == 0) {
                    int idx = n * 2 + (lane >> 5);
                    alpS[idx] = ps[0]; alpD[idx] = pd[0];
                }
            } else if (ALPHA == 2) {
                if (lane == 0) {
#pragma unroll
                    for (int j = 0; j < PL; ++j) {
                        alpS[n * 2 + j] = ps[j]; alpD[n * 2 + j] = pd[j];
                    }
                }
            } else {
                if (lane == 0) { alpS[n] = ps[0]; alpD[n] = pd[0]; }
            }
        }
    }
}

// ---------------------------------------------------------------------------
// FC via MFMA (R21-proven): wave owns 64 cols, B fragments in registers from
// WT[512][64]; per 16-row tile: 2 x-loads + 8 MFMA + coalesced stores.
// ---------------------------------------------------------------------------
__global__ __launch_bounds__(256) void fcmfma_kernel(
        const __half* __restrict__ in,    // [N][64] fp16
        const __half* __restrict__ WT,    // [512][64] fp16 (transposed)
        const float* __restrict__ bias,   // [512]
        float* __restrict__ out,          // [N][512]
        int N, int NT) {
    const int wid  = threadIdx.x >> 6;
    const int lane = threadIdx.x & 63;
    const int cb = blockIdx.y * 256 + wid * 64;
    const int r  = lane & 15;     // A-row / B-col / D-col within tile
    const int kg = lane >> 4;     // k-group

    f16x8 bfrag[4][2];
#pragma unroll
    for (int t = 0; t < 4; ++t)
#pragma unroll
        for (int kf = 0; kf < 2; ++kf)
            bfrag[t][kf] = *(const f16x8*)(WT + (size_t)(cb + t * 16 + r) * 64 + kf * 32 + kg * 8);
    float bs[4];
#pragma unroll
    for (int t = 0; t < 4; ++t) bs[t] = bias[cb + t * 16 + r];

    const int rt0 = blockIdx.x * 5;
#pragma unroll 1
    for (int q = 0; q < 5; ++q) {
        const int rt = rt0 + q;
        if (rt >= NT) break;
        const int n0 = rt * 16;
        f16x8 a0 = *(const f16x8*)(in + (size_t)(n0 + r) * 64 + kg * 8);
        f16x8 a1 = *(const f16x8*)(in + (size_t)(n0 + r) * 64 + 32 + kg * 8);
#pragma unroll
        for (int t = 0; t < 4; ++t) {
            f32x4 acc = {0.0f, 0.0f, 0.0f, 0.0f};
            acc = __builtin_amdgcn_mfma_f32_16x16x32_f16(a0, bfrag[t][0], acc, 0, 0, 0);
            acc = __builtin_amdgcn_mfma_f32_16x16x32_f16(a1, bfrag[t][1], acc, 0, 0, 0);
#pragma unroll
            for (int i = 0; i < 4; ++i) {
                int grow = n0 + kg * 4 + i;
                if (grow < N)
                    out[(size_t)grow * 512 + cb + t * 16 + r] = fmaxf(acc[i] + bs[t], 0.0f);
            }
        }
    }
}

// ---------------------------------------------------------------------------
// Aggregate (PL1 variants, layers 1+3): one wave per dst node, 64-edge
// chunks, two-phase; h gathered as FP16; softmax/accumulate fp32; fp16 out.
// ---------------------------------------------------------------------------
template <int H, int C>
__global__ __launch_bounds__(256) void aggregate_kernel(
        const __half* __restrict__ h,
        const float* __restrict__ alpha_s,
        const float* __restrict__ alpha_d,
        const int* __restrict__ row_ptr,
        const int* __restrict__ csr_src,
        const float* __restrict__ bias,
        __half* __restrict__ out, int N) {
    constexpr int M = H * C;
    __shared__ int   ss[4][64];
    __shared__ float sp[4][128];
    const int wid  = threadIdx.x >> 6;
    const int lane = threadIdx.x & 63;
    const int n = blockIdx.x * 4 + wid;
    if (n >= N) return;

    const int lo = row_ptr[n], hi = row_ptr[n + 1];
    const int myhead = (H == 2) ? (lane / C) : 0;

    float adv[H];
#pragma unroll
    for (int t = 0; t < H; ++t) adv[t] = alpha_d[n * H + t];

    float m[H], den[H], acc = 0.0f;
#pragma unroll
    for (int t = 0; t < H; ++t) { m[t] = -INFINITY; den[t] = 0.0f; }

    for (int e0 = lo; e0 < hi; e0 += 64) {
        const int idx = e0 + lane;
        const bool valid = idx < hi;
        const int src_l = csr_src[valid ? idx : hi - 1];

        // ---- phase A: lane-parallel logits ----
        float lg[H];
        if (H == 2) {
            float2 as = ((const float2*)alpha_s)[src_l];
            lg[0] = as.x + adv[0];
            lg[1] = as.y + adv[1];
        } else {
            lg[0] = alpha_s[src_l] + adv[0];
        }
#pragma unroll
        for (int t = 0; t < H; ++t) {
            float v = lg[t];
            v = v > 0.0f ? v : 0.2f * v;
            lg[t] = valid ? v : -INFINITY;
        }
        float cm[H];
#pragma unroll
        for (int t = 0; t < H; ++t) cm[t] = lg[t];
        for (int mm = 32; mm >= 1; mm >>= 1) {
#pragma unroll
            for (int t = 0; t < H; ++t)
                cm[t] = fmaxf(cm[t], __shfl_xor(cm[t], mm, 64));
        }
        float sc[H];
#pragma unroll
        for (int t = 0; t < H; ++t) {
            float mnew = fmaxf(m[t], cm[t]);
            sc[t] = __expf(m[t] - mnew);
            den[t] *= sc[t];
            m[t] = mnew;
        }
        acc *= (H == 1) ? sc[0] : (myhead == 0 ? sc[0] : sc[1]);

        float p[H], dsum[H];
#pragma unroll
        for (int t = 0; t < H; ++t) { p[t] = __expf(lg[t] - m[t]); dsum[t] = p[t]; }
        for (int mm = 32; mm >= 1; mm >>= 1) {
#pragma unroll
            for (int t = 0; t < H; ++t)
                dsum[t] += __shfl_xor(dsum[t], mm, 64);
        }
#pragma unroll
        for (int t = 0; t < H; ++t) den[t] += dsum[t];

        ss[wid][lane] = src_l;
        if (H == 2) ((float2*)sp[wid])[lane] = make_float2(p[0], p[1]);
        else        sp[wid][lane] = p[0];

        // ---- phase B: per-edge broadcast accumulate, 8-wide batch ----
        int nu = hi - e0; if (nu > 64) nu = 64;
        int u = 0;
#pragma unroll 1
        for (; u + 8 <= nu; u += 8) {
            int su[8];
#pragma unroll
            for (int t = 0; t < 8; ++t)
                su[t] = __builtin_amdgcn_readfirstlane(ss[wid][u + t]);
            float hv[8];
#pragma unroll
            for (int t = 0; t < 8; ++t)
                hv[t] = __half2float(h[(size_t)su[t] * M + lane]);
            if (H == 2) {
                const float2* pb = (const float2*)sp[wid];
#pragma unroll
                for (int t = 0; t < 8; ++t) {
                    float2 q = pb[u + t];
                    acc += (myhead == 0 ? q.x : q.y) * hv[t];
                }
            } else {
#pragma unroll
                for (int t = 0; t < 8; ++t)
                    acc += sp[wid][u + t] * hv[t];
            }
        }
#pragma unroll 1
        for (; u < nu; ++u) {
            int su = __builtin_amdgcn_readfirstlane(ss[wid][u]);
            float hv = __half2float(h[(size_t)su * M + lane]);
            if (H == 2) {
                float2 q = ((const float2*)sp[wid])[u];
                acc += (myhead == 0 ? q.x : q.y) * hv;
            } else {
                acc += sp[wid][u] * hv;
            }
        }
    }

    float dv = (H == 1) ? den[0] : (myhead == 0 ? den[0] : den[1]);
    float v = acc / dv + bias[lane];
    out[(size_t)n * M + lane] = (__half)fmaxf(v, 0.0f);
}

// ---------------------------------------------------------------------------
// Layer-2 aggregate, HEAD-SPLIT: 2 waves per node; h fp16 in, fp16 out.
// ---------------------------------------------------------------------------
__global__ __launch_bounds__(256) void aggregate2_kernel(
        const __half* __restrict__ h,       // [N][128] fp16
        const float* __restrict__ alpha_s,  // [N][2]
        const float* __restrict__ alpha_d,  // [N][2]
        const int* __restrict__ row_ptr,
        const int* __restrict__ csr_src,
        const float* __restrict__ bias,     // [128]
        __half* __restrict__ out, int N) {
    __shared__ int   ss[4][64];
    __shared__ float sp[4][64];
    const int wid  = threadIdx.x >> 6;
    const int lane = threadIdx.x & 63;
    const int gw   = blockIdx.x * 4 + wid;
    const int n    = gw >> 1;
    const int hd   = gw & 1;
    if (n >= N) return;

    const int lo = row_ptr[n], hi = row_ptr[n + 1];
    const float adv = alpha_d[n * 2 + hd];

    float m = -INFINITY, den = 0.0f, acc = 0.0f;

    for (int e0 = lo; e0 < hi; e0 += 64) {
        const int idx = e0 + lane;
        const bool valid = idx < hi;
        const int src_l = csr_src[valid ? idx : hi - 1];

        float lg = alpha_s[src_l * 2 + hd] + adv;
        lg = lg > 0.0f ? lg : 0.2f * lg;
        if (!valid) lg = -INFINITY;

        float cm = lg;
        for (int mm = 32; mm >= 1; mm >>= 1)
            cm = fmaxf(cm, __shfl_xor(cm, mm, 64));

        float mnew = fmaxf(m, cm);
        float sc = __expf(m - mnew);
        den *= sc; acc *= sc; m = mnew;

        float p = __expf(lg - m), ds = p;
        for (int mm = 32; mm >= 1; mm >>= 1)
            ds += __shfl_xor(ds, mm, 64);
        den += ds;

        ss[wid][lane] = src_l;
        sp[wid][lane] = p;

        int nu = hi - e0; if (nu > 64) nu = 64;
        int u = 0;
#pragma unroll 1
        for (; u + 8 <= nu; u += 8) {
            int su[8];
#pragma unroll
            for (int t = 0; t < 8; ++t)
                su[t] = __builtin_amdgcn_readfirstlane(ss[wid][u + t]);
            float hv[8];
#pragma unroll
            for (int t = 0; t < 8; ++t)
                hv[t] = __half2float(h[(size_t)su[t] * 128 + hd * 64 + lane]);
#pragma unroll
            for (int t = 0; t < 8; ++t)
                acc += sp[wid][u + t] * hv[t];
        }
#pragma unroll 1
        for (; u < nu; ++u) {
            int su = __builtin_amdgcn_readfirstlane(ss[wid][u]);
            acc += sp[wid][u] * __half2float(h[(size_t)su * 128 + hd * 64 + lane]);
        }
    }

    float v = acc / den + bias[hd * 64 + lane];
    out[(size_t)n * 128 + hd * 64 + lane] = (__half)fmaxf(v, 0.0f);
}

// ---------------------------------------------------------------------------

extern "C" void kernel_launch(void* const* d_in, const int* in_sizes, int n_in,
                              void* d_out, int out_size, void* d_ws, size_t ws_size,
                              hipStream_t stream) {
    const float* x   = (const float*)d_in[0];
    const int*   ei  = (const int*)  d_in[1];
    const float* w1  = (const float*)d_in[2];
    const float* as1 = (const float*)d_in[3];
    const float* ad1 = (const float*)d_in[4];
    const float* b1  = (const float*)d_in[5];
    const float* w2  = (const float*)d_in[6];
    const float* as2 = (const float*)d_in[7];
    const float* ad2 = (const float*)d_in[8];
    const float* b2  = (const float*)d_in[9];
    const float* w3  = (const float*)d_in[10];
    const float* as3 = (const float*)d_in[11];
    const float* ad3 = (const float*)d_in[12];
    const float* b3  = (const float*)d_in[13];
    const float* fcw = (const float*)d_in[14];
    const float* fcb = (const float*)d_in[15];
    float* out = (float*)d_out;

    const int N = in_sizes[0] / 128;
    const int E = in_sizes[1] / 2;
    const int Etot = E + N;

    // workspace carve-up (256B aligned regions)
    char* p = (char*)d_ws;
    auto alloc = [&](size_t bytes) {
        char* r = p;
        p += (bytes + 255) & ~(size_t)255;
        return r;
    };
    int*    cnt     = (int*)   alloc((size_t)N * 4);
    int*    row_ptr = (int*)   alloc((size_t)(N + 1) * 4);
    int*    rank    = (int*)   alloc((size_t)Etot * 4);
    int*    csr_src = (int*)   alloc((size_t)Etot * 4);
    int*    bsum    = (int*)   alloc((size_t)SCAN_NB * 4);
    int*    bbase   = (int*)   alloc((size_t)SCAN_NB * 4);
    __half* x16     = (__half*)alloc((size_t)N * 128 * 2);   // fp16 input x
    __half* bufA    = (__half*)alloc((size_t)N * 128 * 2);   // fp16 gemm out h
    __half* bufB    = (__half*)alloc((size_t)N * 128 * 2);   // fp16 agg out
    __half* bufC    = (__half*)alloc((size_t)(N + 16) * 64 * 2); // fp16 agg3 out (FC in, +pad)
    __half* wh1     = (__half*)alloc((size_t)8192 * 2);
    __half* wh2     = (__half*)alloc((size_t)8192 * 2);
    __half* wh3     = (__half*)alloc((size_t)8192 * 2);
    __half* fcwT    = (__half*)alloc((size_t)32768 * 2);     // [512][64] transposed
    float*  alpS    = (float*) alloc((size_t)N * 2 * 4);
    float*  alpD    = (float*) alloc((size_t)N * 2 * 4);
    (void)ws_size; (void)n_in; (void)out_size;

    // ---- cvt: x fp32->fp16 + weights (streaming) ----
    hipMemsetAsync(cnt, 0, (size_t)N * 4, stream);
    const int n4 = N * 32;                      // float4 units in x
    const int XB = (n4 + 255) / 256;            // cvtx blocks
    const int WB = 224;                         // cvtw blocks
    cvt_kernel<<<XB + WB, 256, 0, stream>>>(
        x, x16, n4, w1, w2, w3, fcw, wh1, wh2, wh3, fcwT, XB);

    int gb  = (N + 3) / 4;        // aggregate (PL1): 4 waves/block, 1 node/wave
    int gb2 = (2 * N + 3) / 4;    // aggregate2: 2 waves/node
    const int GB16 = 2048;        // fp16 gemm grids (layers 2,3)
    const int GG1  = 1024;        // layer-1 gemm blocks (fused with count)
    const int GC1  = 1024;        // count blocks co-resident with gemm1

    // ---- layer 1 GEMM fused with count_rank (atomics hide under fdot2) ----
    gemm16_kernel<128, 64, 8, 1, true><<<dim3(GG1 + GC1, 1), 256, 0, stream>>>(
        x16, wh1, bufA, as1, ad1, alpS, alpD, N, 64, ei, E, cnt, rank, GG1);

    // ---- CSR: parallel scan + scatter ----
    scanA_kernel<<<SCAN_NB, 256, 0, stream>>>(cnt, N, bsum);
    scanB_kernel<<<1, 256, 0, stream>>>(bsum, bbase);
    scanC_kernel<<<SCAN_NB, 256, 0, stream>>>(cnt, N, Etot, bbase, row_ptr);
    const int CB = (Etot / 4 + 255) / 256 + 1;
    scatter_kernel<<<CB, 256, 0, stream>>>(ei, E, N, row_ptr, rank, csr_src);

    // ---- layer 1 aggregate ----
    aggregate_kernel<2, 32><<<gb, 256, 0, stream>>>(bufA, alpS, alpD, row_ptr, csr_src, b1, bufB, N);

    // ---- layer 2: 64 -> H2 x C64, concat (head-split aggregate) ----
    gemm16_kernel<64, 128, 8, 2, false><<<dim3(GB16, 1), 256, 0, stream>>>(
        bufB, wh2, bufA, as2, ad2, alpS, alpD, N, 128, nullptr, 0, nullptr, nullptr, GB16);
    aggregate2_kernel<<<gb2, 256, 0, stream>>>(bufA, alpS, alpD, row_ptr, csr_src, b2, bufB, N);

    // ---- layer 3: 128 -> H1 x C64, mean; output fp16 for FC ----
    gemm16_kernel<128, 64, 8, 3, false><<<dim3(GB16, 1), 256, 0, stream>>>(
        bufB, wh3, bufA, as3, ad3, alpS, alpD, N, 64, nullptr, 0, nullptr, nullptr, GB16);
    aggregate_kernel<1, 64><<<gb, 256, 0, stream>>>(bufA, alpS, alpD, row_ptr, csr_src, b3, bufC, N);

    // ---- FC: 64 -> 512 + relu via MFMA, B-fragments in registers ----
    const int NT = (N + 15) / 16;               // 16-row tiles (3125 exact)
    const int GX = (NT + 4) / 5;                // 5 tiles/block (625)
    fcmfma_kernel<<<dim3(GX, 2), 256, 0, stream>>>(
        bufC, fcwT, fcb, out, N, NT);
}